// Round 1
// baseline (577.093 us; speedup 1.0000x reference)
//
#include <hip/hip_runtime.h>
#include <math.h>

// ProbAttention: B=4, N=2048, C=512, H=8, D=64, sample_k=40, u=40
namespace {

constexpr int Bb = 4, Nn = 2048, Cc = 512, Hh = 8, Dd = 64, Ss = 40, Uu = 40;
constexpr int M_ROWS = Bb * Nn; // 8192

// ---------------- 128x128x8 fp32 tiled GEMM ----------------
// MODE 0: out = A @ W0 + b0, plain [M,512] output (final projection)
// MODE 1: fused QKV: gridDim.y=12, each 128-col tile belongs to one of Wq/Wk/Wv;
//         output written head-split into q/k/v [B,H,N,D]
template<int MODE>
__global__ __launch_bounds__(256) void gemm128(
    const float* __restrict__ A,
    const float* __restrict__ W0, const float* __restrict__ W1, const float* __restrict__ W2,
    const float* __restrict__ bias0p, const float* __restrict__ bias1p, const float* __restrict__ bias2p,
    float* __restrict__ o0, float* __restrict__ o1, float* __restrict__ o2)
{
  __shared__ float As[8][128];   // transposed A tile
  __shared__ float Bs[8][128];
  int tid = threadIdx.x;
  int bm = blockIdx.x * 128;
  const float* W; const float* bias; int cb;
  if (MODE == 0) {
    W = W0; bias = bias0p; cb = blockIdx.y * 128;
  } else {
    int which = blockIdx.y >> 2;
    W = which == 0 ? W0 : (which == 1 ? W1 : W2);
    bias = which == 0 ? bias0p : (which == 1 ? bias1p : bias2p);
    cb = (blockIdx.y & 3) * 128;
  }
  float acc[8][8];
  #pragma unroll
  for (int i = 0; i < 8; ++i)
    #pragma unroll
    for (int j = 0; j < 8; ++j) acc[i][j] = 0.f;

  int tm = tid >> 4, tn = tid & 15;          // 16x16 thread grid, 8x8 micro-tile
  int ar = tid >> 1, ak = (tid & 1) * 4;     // A tile load map (128 rows x 8 k)
  int br = tid >> 5, bc = (tid & 31) * 4;    // B tile load map (8 rows x 128 cols)
  const float* Aptr = A + (size_t)(bm + ar) * Cc + ak;
  const float* Wptr = W + (size_t)br * Cc + cb + bc;

  for (int k0 = 0; k0 < Cc; k0 += 8) {
    float4 a4 = *(const float4*)(Aptr + k0);
    float4 b4 = *(const float4*)(Wptr + (size_t)k0 * Cc);
    As[ak + 0][ar] = a4.x;
    As[ak + 1][ar] = a4.y;
    As[ak + 2][ar] = a4.z;
    As[ak + 3][ar] = a4.w;
    *(float4*)&Bs[br][bc] = b4;
    __syncthreads();
    #pragma unroll
    for (int kk = 0; kk < 8; ++kk) {
      float a[8], bb[8];
      *(float4*)&a[0]  = *(const float4*)&As[kk][tm * 4];
      *(float4*)&a[4]  = *(const float4*)&As[kk][64 + tm * 4];
      *(float4*)&bb[0] = *(const float4*)&Bs[kk][tn * 4];
      *(float4*)&bb[4] = *(const float4*)&Bs[kk][64 + tn * 4];
      #pragma unroll
      for (int i = 0; i < 8; ++i)
        #pragma unroll
        for (int j = 0; j < 8; ++j)
          acc[i][j] = fmaf(a[i], bb[j], acc[i][j]);
    }
    __syncthreads();
  }

  float4 bv0 = *(const float4*)(bias + cb + tn * 4);
  float4 bv1 = *(const float4*)(bias + cb + 64 + tn * 4);

  #pragma unroll
  for (int i = 0; i < 8; ++i) {
    int row = bm + (i < 4 ? tm * 4 + i : 64 + tm * 4 + (i - 4));
    float4 s0 = make_float4(acc[i][0] + bv0.x, acc[i][1] + bv0.y,
                            acc[i][2] + bv0.z, acc[i][3] + bv0.w);
    float4 s1 = make_float4(acc[i][4] + bv1.x, acc[i][5] + bv1.y,
                            acc[i][6] + bv1.z, acc[i][7] + bv1.w);
    if (MODE == 0) {
      *(float4*)(o0 + (size_t)row * Cc + cb + tn * 4) = s0;
      *(float4*)(o0 + (size_t)row * Cc + cb + 64 + tn * 4) = s1;
    } else {
      int which = blockIdx.y >> 2;
      float* op = which == 0 ? o0 : (which == 1 ? o1 : o2);
      int b = row >> 11, n = row & 2047;
      int c0 = cb + tn * 4, c1 = cb + 64 + tn * 4;
      int h0 = c0 >> 6, d0 = c0 & 63;
      int h1 = c1 >> 6, d1 = c1 & 63;
      *(float4*)(op + ((size_t)(b * Hh + h0) * Nn + n) * Dd + d0) = s0;
      *(float4*)(op + ((size_t)(b * Hh + h1) * Nn + n) * Dd + d1) = s1;
    }
  }
}

// ---------------- sampled QK^T -> M = max - mean ----------------
// One wave per (b,h,l); lane s<40 computes dot(q_l, k[idx[l,s]]) over D=64.
__global__ __launch_bounds__(256) void sampled_qk_kernel(
    const float* __restrict__ q, const float* __restrict__ k,
    const int* __restrict__ idx, float* __restrict__ Mout)
{
  int wave = blockIdx.x * 4 + (threadIdx.x >> 6);  // bh*2048 + l
  int lane = threadIdx.x & 63;
  int l = wave & (Nn - 1);
  int bh = wave >> 11;
  const float* qrow = q + (size_t)wave * Dd;
  float dot = 0.f;
  if (lane < Ss) {
    int kr = idx[l * Ss + lane];
    const float* krow = k + ((size_t)bh * Nn + kr) * Dd;
    #pragma unroll
    for (int i = 0; i < 16; ++i) {
      float4 k4 = *(const float4*)(krow + i * 4);
      float4 q4 = *(const float4*)(qrow + i * 4);
      dot += q4.x * k4.x + q4.y * k4.y + q4.z * k4.z + q4.w * k4.w;
    }
  }
  float mx = (lane < Ss) ? dot : -INFINITY;
  float sm = (lane < Ss) ? dot : 0.f;
  #pragma unroll
  for (int o = 32; o; o >>= 1) {
    mx = fmaxf(mx, __shfl_xor(mx, o));
    sm += __shfl_xor(sm, o);
  }
  if (lane == 0) Mout[wave] = mx - sm * (1.f / (float)Nn);
}

// ---------------- top-40 indices per (b,h) ----------------
__global__ __launch_bounds__(256) void topk_kernel(
    const float* __restrict__ Min, int* __restrict__ M_top)
{
  __shared__ float vals[Nn];
  __shared__ float bv[256];
  __shared__ int   bi[256];
  int bh = blockIdx.x, t = threadIdx.x;
  for (int i = t; i < Nn; i += 256) vals[i] = Min[(size_t)bh * Nn + i];
  __syncthreads();
  for (int it = 0; it < Uu; ++it) {
    float best = -INFINITY; int besti = Nn;
    for (int i = t; i < Nn; i += 256) {
      float vv = vals[i];
      if (vv > best || (vv == best && i < besti)) { best = vv; besti = i; }
    }
    bv[t] = best; bi[t] = besti;
    __syncthreads();
    for (int sft = 128; sft; sft >>= 1) {
      if (t < sft) {
        float ov = bv[t + sft]; int oi = bi[t + sft];
        if (ov > bv[t] || (ov == bv[t] && oi < bi[t])) { bv[t] = ov; bi[t] = oi; }
      }
      __syncthreads();
    }
    if (t == 0) { M_top[bh * Uu + it] = bi[0]; vals[bi[0]] = -INFINITY; }
    __syncthreads();
  }
}

// ---------------- mean of V over N per (b,h,d) ----------------
__global__ __launch_bounds__(256) void vmean_kernel(
    const float* __restrict__ v, float* __restrict__ vmean)
{
  int bh = blockIdx.x, t = threadIdx.x;
  int d = t & 63, chunk = t >> 6;
  const float* base = v + (size_t)bh * Nn * Dd;
  float s = 0.f;
  for (int n = chunk * 512; n < (chunk + 1) * 512; ++n) s += base[(size_t)n * Dd + d];
  __shared__ float part[4][64];
  part[chunk][d] = s;
  __syncthreads();
  if (t < 64)
    vmean[bh * Dd + t] = (part[0][t] + part[1][t] + part[2][t] + part[3][t]) * (1.f / (float)Nn);
}

// ---------------- ctx init: broadcast mean-V into [B,N,C] ----------------
__global__ __launch_bounds__(256) void ctxinit_kernel(
    const float* __restrict__ vmean, float* __restrict__ ctx)
{
  size_t i = (size_t)blockIdx.x * 256 + threadIdx.x;  // one float4 each
  int c4 = (int)(i & 127) * 4;
  size_t bn = i >> 7;
  int b = (int)(bn >> 11);
  float4 m4 = *(const float4*)(vmean + b * Cc + c4);
  *(float4*)(ctx + i * 4) = m4;
}

// ---------------- reduced attention for top-u rows + scatter ----------------
// One block per (b,h,u).
__global__ __launch_bounds__(256) void redattn_kernel(
    const float* __restrict__ q, const float* __restrict__ k, const float* __restrict__ v,
    const int* __restrict__ M_top, float* __restrict__ ctx)
{
  int blk = blockIdx.x;             // bh*40 + u
  int bh = blk / Uu;
  int b = bh >> 3, h = bh & 7;
  int r = M_top[blk];
  int t = threadIdx.x;

  __shared__ float qs[Dd];
  __shared__ float sc[Nn];
  __shared__ float red[256];
  __shared__ float part[4][64];

  const float* kbase = k + (size_t)bh * Nn * Dd;
  const float* vbase = v + (size_t)bh * Nn * Dd;
  if (t < Dd) qs[t] = q[((size_t)bh * Nn + r) * Dd + t];
  __syncthreads();

  const float scale = 0.125f;  // D^-0.5
  float lmax = -INFINITY;
  float myS[8];
  #pragma unroll
  for (int j = 0; j < 8; ++j) {
    int n = t + j * 256;
    const float* krow = kbase + (size_t)n * Dd;
    float dot = 0.f;
    #pragma unroll
    for (int i = 0; i < 16; ++i) {
      float4 k4 = *(const float4*)(krow + i * 4);
      float4 q4 = *(const float4*)(qs + i * 4);
      dot += q4.x * k4.x + q4.y * k4.y + q4.z * k4.z + q4.w * k4.w;
    }
    dot *= scale;
    myS[j] = dot;
    lmax = fmaxf(lmax, dot);
  }
  red[t] = lmax;
  __syncthreads();
  for (int sft = 128; sft; sft >>= 1) {
    if (t < sft) red[t] = fmaxf(red[t], red[t + sft]);
    __syncthreads();
  }
  float m = red[0];
  __syncthreads();
  float lsum = 0.f;
  #pragma unroll
  for (int j = 0; j < 8; ++j) {
    float p = expf(myS[j] - m);
    sc[t + j * 256] = p;
    lsum += p;
  }
  red[t] = lsum;
  __syncthreads();
  for (int sft = 128; sft; sft >>= 1) {
    if (t < sft) red[t] += red[t + sft];
    __syncthreads();
  }
  float Z = red[0];

  // PV: wave w handles n in [w*512,(w+1)*512), lane = d
  int lane = t & 63, w = t >> 6;
  float acc = 0.f;
  for (int n = w * 512; n < (w + 1) * 512; ++n)
    acc = fmaf(sc[n], vbase[(size_t)n * Dd + lane], acc);
  part[w][lane] = acc;
  __syncthreads();
  if (t < 64) {
    float upd = (part[0][t] + part[1][t] + part[2][t] + part[3][t]) / Z;
    ctx[((size_t)b * Nn + r) * Cc + h * Dd + t] = upd;
  }
}

} // namespace

extern "C" void kernel_launch(void* const* d_in, const int* in_sizes, int n_in,
                              void* d_out, int out_size, void* d_ws, size_t ws_size,
                              hipStream_t stream) {
  const float* x  = (const float*)d_in[0];
  const float* Wq = (const float*)d_in[1];
  const float* bq = (const float*)d_in[2];
  const float* Wk = (const float*)d_in[3];
  const float* bk = (const float*)d_in[4];
  const float* Wv = (const float*)d_in[5];
  const float* bv = (const float*)d_in[6];
  const float* Wo = (const float*)d_in[7];
  const float* bo = (const float*)d_in[8];
  const int* idx  = (const int*)d_in[9];
  float* out = (float*)d_out;

  float* ws = (float*)d_ws;
  float* q     = ws;                 // [B,H,N,D] 4.19M floats
  float* kbuf  = ws + 4194304;
  float* vbuf  = ws + 8388608;
  float* ctx   = ws + 12582912;      // [B,N,C]
  float* Mbuf  = ws + 16777216;      // [B,H,N]
  float* vmean = ws + 16842752;      // [B,H,D]
  int*   M_top = (int*)(ws + 16844800); // [B,H,40]

  // 1) fused QKV projection (head-split outputs)
  gemm128<1><<<dim3(M_ROWS / 128, 12), 256, 0, stream>>>(
      x, Wq, Wk, Wv, bq, bk, bv, q, kbuf, vbuf);

  // 2) sampled QK^T -> sparsity measure M
  sampled_qk_kernel<<<(Bb * Hh * Nn) / 4, 256, 0, stream>>>(q, kbuf, idx, Mbuf);

  // 3) top-40 dominant queries per (b,h)
  topk_kernel<<<Bb * Hh, 256, 0, stream>>>(Mbuf, M_top);

  // 4) mean of V, broadcast into ctx
  vmean_kernel<<<Bb * Hh, 256, 0, stream>>>(vbuf, vmean);
  ctxinit_kernel<<<(Bb * Nn * Cc / 4) / 256, 256, 0, stream>>>(vmean, ctx);

  // 5) full attention for dominant rows, scatter into ctx
  redattn_kernel<<<Bb * Hh * Uu, 256, 0, stream>>>(q, kbuf, vbuf, M_top, ctx);

  // 6) output projection
  gemm128<0><<<dim3(M_ROWS / 128, 4), 256, 0, stream>>>(
      ctx, Wo, nullptr, nullptr, bo, nullptr, nullptr, out, nullptr, nullptr);
}

// Round 2
// 429.777 us; speedup vs baseline: 1.3428x; 1.3428x over previous
//
#include <hip/hip_runtime.h>
#include <math.h>

namespace {

constexpr int Bb = 4, Nn = 2048, Cc = 512, Hh = 8, Dd = 64, Ss = 40, Uu = 40;
constexpr int M_ROWS = Bb * Nn; // 8192
constexpr int BH = Bb * Hh;     // 32

typedef __attribute__((ext_vector_type(8))) short short8;
typedef __attribute__((ext_vector_type(4))) float f32x4;

__device__ inline unsigned short f2bf(float f) {
  union { float f; unsigned u; } v; v.f = f;
  unsigned r = (v.u + 0x7fffu + ((v.u >> 16) & 1u)) >> 16;
  return (unsigned short)r;
}
__device__ inline float bf2f(unsigned short h) {
  union { unsigned u; float f; } v; v.u = ((unsigned)h) << 16;
  return v.f;
}

// ---------- split x into bf16 hi/lo ----------
__global__ __launch_bounds__(256) void convert_x(
    const float* __restrict__ x, unsigned short* __restrict__ xh, unsigned short* __restrict__ xl)
{
  size_t i = ((size_t)blockIdx.x * 256 + threadIdx.x) * 4;
  float4 v = *(const float4*)(x + i);
  ushort4 h, l;
  h.x = f2bf(v.x); l.x = f2bf(v.x - bf2f(h.x));
  h.y = f2bf(v.y); l.y = f2bf(v.y - bf2f(h.y));
  h.z = f2bf(v.z); l.z = f2bf(v.z - bf2f(h.z));
  h.w = f2bf(v.w); l.w = f2bf(v.w - bf2f(h.w));
  *(ushort4*)(xh + i) = h;
  *(ushort4*)(xl + i) = l;
}

// ---------- build transposed+split weights WT[1536][512] ----------
__global__ __launch_bounds__(256) void convert_w(
    const float* __restrict__ Wq, const float* __restrict__ Wk, const float* __restrict__ Wv,
    unsigned short* __restrict__ WTh, unsigned short* __restrict__ WTl)
{
  int nrow = blockIdx.x;
  int which = nrow >> 9, col = nrow & 511;
  const float* Wsrc = which == 0 ? Wq : (which == 1 ? Wk : Wv);
  for (int kk = threadIdx.x; kk < 512; kk += 256) {
    float v = Wsrc[(size_t)kk * 512 + col];
    unsigned short h = f2bf(v);
    WTh[(size_t)nrow * 512 + kk] = h;
    WTl[(size_t)nrow * 512 + kk] = f2bf(v - bf2f(h));
  }
}

// ---------- bf16 split-precision MFMA GEMM: QKV projection ----------
// C[8192][1536] = sum of 3 passes (xh*WTh + xl*WTh + xh*WTl), + bias,
// written head-split into q/k/v [B,H,N,D] fp32.
__global__ __launch_bounds__(256) void gemm_qkv(
    const unsigned short* __restrict__ xh, const unsigned short* __restrict__ xl,
    const unsigned short* __restrict__ WTh, const unsigned short* __restrict__ WTl,
    const float* __restrict__ bq, const float* __restrict__ bk, const float* __restrict__ bv,
    float* __restrict__ qf, float* __restrict__ kf, float* __restrict__ vf)
{
  __shared__ __align__(16) unsigned short As[128 * 64];
  __shared__ __align__(16) unsigned short Bs[128 * 64];
  int tid = threadIdx.x;
  int lane = tid & 63, w = tid >> 6;
  int bm = blockIdx.x * 128, bn = blockIdx.y * 128;

  f32x4 acc[4][4];
  #pragma unroll
  for (int i = 0; i < 4; ++i)
    #pragma unroll
    for (int j = 0; j < 4; ++j)
      #pragma unroll
      for (int r = 0; r < 4; ++r) acc[i][j][r] = 0.f;

  int rA = w * 8 + (lane >> 3);   // +i*32 per issue
  int cA = (lane & 7) * 8;
  int wm = (w >> 1) * 64, wn = (w & 1) * 64;
  int lm = lane & 15, lg = lane >> 4;

  for (int seg = 0; seg < 3; ++seg) {
    const unsigned short* Abase = (seg == 1) ? xl : xh;
    const unsigned short* Bbase = (seg == 2) ? WTl : WTh;
    for (int kt = 0; kt < 8; ++kt) {
      int k0 = kt * 64;
      #pragma unroll
      for (int i = 0; i < 4; ++i) {
        const unsigned short* ga = Abase + (size_t)(bm + i * 32 + rA) * 512 + k0 + cA;
        __builtin_amdgcn_global_load_lds(
            (const __attribute__((address_space(1))) void*)ga,
            (__attribute__((address_space(3))) void*)((char*)As + i * 4096 + w * 1024), 16, 0, 0);
        const unsigned short* gb = Bbase + (size_t)(bn + i * 32 + rA) * 512 + k0 + cA;
        __builtin_amdgcn_global_load_lds(
            (const __attribute__((address_space(1))) void*)gb,
            (__attribute__((address_space(3))) void*)((char*)Bs + i * 4096 + w * 1024), 16, 0, 0);
      }
      __syncthreads();
      #pragma unroll
      for (int ks = 0; ks < 2; ++ks) {
        short8 af[4], bg[4];
        #pragma unroll
        for (int i = 0; i < 4; ++i)
          af[i] = *(const short8*)(As + (wm + i * 16 + lm) * 64 + ks * 32 + lg * 8);
        #pragma unroll
        for (int j = 0; j < 4; ++j)
          bg[j] = *(const short8*)(Bs + (wn + j * 16 + lm) * 64 + ks * 32 + lg * 8);
        #pragma unroll
        for (int i = 0; i < 4; ++i)
          #pragma unroll
          for (int j = 0; j < 4; ++j)
            acc[i][j] = __builtin_amdgcn_mfma_f32_16x16x32_bf16(af[i], bg[j], acc[i][j], 0, 0, 0);
      }
      __syncthreads();
    }
  }

  #pragma unroll
  for (int j = 0; j < 4; ++j) {
    int n = bn + wn + j * 16 + lm;
    float bias = n < 512 ? bq[n] : (n < 1024 ? bk[n - 512] : bv[n - 1024]);
    int tensor = n >> 9, h = (n >> 6) & 7, d = n & 63;
    float* op = tensor == 0 ? qf : (tensor == 1 ? kf : vf);
    #pragma unroll
    for (int i = 0; i < 4; ++i) {
      #pragma unroll
      for (int r = 0; r < 4; ++r) {
        int m = bm + wm + i * 16 + lg * 4 + r;
        int b = m >> 11, nn = m & 2047;
        op[((size_t)(b * Hh + h) * Nn + nn) * Dd + d] = acc[i][j][r] + bias;
      }
    }
  }
}

// ---------- sampled QK^T -> M = max - mean ----------
__global__ __launch_bounds__(256) void sampled_qk_kernel(
    const float* __restrict__ q, const float* __restrict__ k,
    const int* __restrict__ idx, float* __restrict__ Mout)
{
  int wave = blockIdx.x * 4 + (threadIdx.x >> 6);
  int lane = threadIdx.x & 63;
  int l = wave & (Nn - 1);
  int bh = wave >> 11;
  const float* qrow = q + (size_t)wave * Dd;
  float dot = 0.f;
  if (lane < Ss) {
    int kr = idx[l * Ss + lane];
    const float* krow = k + ((size_t)bh * Nn + kr) * Dd;
    #pragma unroll
    for (int i = 0; i < 16; ++i) {
      float4 k4 = *(const float4*)(krow + i * 4);
      float4 q4 = *(const float4*)(qrow + i * 4);
      dot += q4.x * k4.x + q4.y * k4.y + q4.z * k4.z + q4.w * k4.w;
    }
  }
  float mx = (lane < Ss) ? dot : -INFINITY;
  float sm = (lane < Ss) ? dot : 0.f;
  #pragma unroll
  for (int o = 32; o; o >>= 1) {
    mx = fmaxf(mx, __shfl_xor(mx, o));
    sm += __shfl_xor(sm, o);
  }
  if (lane == 0) Mout[wave] = mx - sm * (1.f / (float)Nn);
}

// ---------- top-40 per (b,h): single wave, register-resident ----------
__global__ __launch_bounds__(64) void topk_kernel(
    const float* __restrict__ Min, int* __restrict__ M_top)
{
  int bh = blockIdx.x, lane = threadIdx.x;
  const float* row = Min + (size_t)bh * Nn;
  float v[32];
  #pragma unroll
  for (int j = 0; j < 32; ++j) v[j] = row[j * 64 + lane];
  unsigned mask = 0;
  for (int it = 0; it < Uu; ++it) {
    float best = -INFINITY; int bidx = 0x7FFFFFFF;
    #pragma unroll
    for (int j = 0; j < 32; ++j) {
      if (!((mask >> j) & 1u) && v[j] > best) { best = v[j]; bidx = j * 64 + lane; }
    }
    #pragma unroll
    for (int o = 32; o; o >>= 1) {
      float ov = __shfl_xor(best, o);
      int oi = __shfl_xor(bidx, o);
      if (ov > best || (ov == best && oi < bidx)) { best = ov; bidx = oi; }
    }
    if ((bidx & 63) == lane) mask |= 1u << (bidx >> 6);
    if (lane == 0) M_top[bh * Uu + it] = bidx;
  }
}

// ---------- mean of V over N per (b,h,d) ----------
__global__ __launch_bounds__(256) void vmean_kernel(
    const float* __restrict__ v, float* __restrict__ vmean)
{
  int bh = blockIdx.x, t = threadIdx.x;
  int d = t & 63, chunk = t >> 6;
  const float* base = v + (size_t)bh * Nn * Dd;
  float s = 0.f;
  for (int n = chunk * 512; n < (chunk + 1) * 512; ++n) s += base[(size_t)n * Dd + d];
  __shared__ float part[4][64];
  part[chunk][d] = s;
  __syncthreads();
  if (t < 64)
    vmean[bh * Dd + t] = (part[0][t] + part[1][t] + part[2][t] + part[3][t]) * (1.f / (float)Nn);
}

// ---------- scores: S[bh][u][n] = (Qr . K^T) * scale, chunked over n ----------
__global__ __launch_bounds__(256) void scores_kernel(
    const float* __restrict__ q, const float* __restrict__ k,
    const int* __restrict__ M_top, float* __restrict__ S)
{
  int chunk = blockIdx.x, bh = blockIdx.y, t = threadIdx.x;
  __shared__ float qs[40][64];
  if (t < 160) {
    int u = t >> 2, p = (t & 3) * 16;
    int r = M_top[bh * Uu + u];
    const float4* src = (const float4*)(q + ((size_t)bh * Nn + r) * Dd + p);
    *(float4*)&qs[u][p + 0]  = src[0];
    *(float4*)&qs[u][p + 4]  = src[1];
    *(float4*)&qs[u][p + 8]  = src[2];
    *(float4*)&qs[u][p + 12] = src[3];
  }
  __syncthreads();
  int n = chunk * 256 + t;
  const float4* krow = (const float4*)(k + ((size_t)bh * Nn + n) * Dd);
  float acc[40];
  #pragma unroll
  for (int u = 0; u < 40; ++u) acc[u] = 0.f;
  #pragma unroll
  for (int d4 = 0; d4 < 16; ++d4) {
    float4 kv = krow[d4];
    #pragma unroll
    for (int u = 0; u < 40; ++u) {
      float4 qv = *(const float4*)&qs[u][d4 * 4];
      acc[u] += qv.x * kv.x + qv.y * kv.y + qv.z * kv.z + qv.w * kv.w;
    }
  }
  #pragma unroll
  for (int u = 0; u < 40; ++u)
    S[((size_t)bh * Uu + u) * Nn + n] = acc[u] * 0.125f;
}

// ---------- softmax over rows of S (in place), Z = row sum ----------
__global__ __launch_bounds__(256) void softmax_kernel(
    float* __restrict__ S, float* __restrict__ Z)
{
  int row = blockIdx.x, t = threadIdx.x;
  float* p = S + (size_t)row * Nn + t * 8;
  float4 a = *(float4*)p, b = *(float4*)(p + 4);
  __shared__ float red[256];
  float m = fmaxf(fmaxf(fmaxf(a.x, a.y), fmaxf(a.z, a.w)),
                  fmaxf(fmaxf(b.x, b.y), fmaxf(b.z, b.w)));
  red[t] = m; __syncthreads();
  for (int s = 128; s; s >>= 1) { if (t < s) red[t] = fmaxf(red[t], red[t + s]); __syncthreads(); }
  m = red[0]; __syncthreads();
  a.x = expf(a.x - m); a.y = expf(a.y - m); a.z = expf(a.z - m); a.w = expf(a.w - m);
  b.x = expf(b.x - m); b.y = expf(b.y - m); b.z = expf(b.z - m); b.w = expf(b.w - m);
  float sm = a.x + a.y + a.z + a.w + b.x + b.y + b.z + b.w;
  red[t] = sm; __syncthreads();
  for (int s = 128; s; s >>= 1) { if (t < s) red[t] += red[t + s]; __syncthreads(); }
  if (t == 0) Z[row] = red[0];
  *(float4*)p = a; *(float4*)(p + 4) = b;
}

// ---------- PV partial: partial[bh][cw][u][d] over n-chunks ----------
__global__ __launch_bounds__(256) void pv_kernel(
    const float* __restrict__ P, const float* __restrict__ v, float* __restrict__ partial)
{
  int chunk = blockIdx.x, bh = blockIdx.y, t = threadIdx.x;
  __shared__ float Pl[40][256];
  for (int u = 0; u < 40; ++u)
    Pl[u][t] = P[((size_t)bh * Uu + u) * Nn + chunk * 256 + t];
  __syncthreads();
  int lane = t & 63, w = t >> 6;
  float acc[40];
  #pragma unroll
  for (int u = 0; u < 40; ++u) acc[u] = 0.f;
  const float* vb = v + ((size_t)bh * Nn + chunk * 256 + w * 64) * Dd + lane;
  for (int i = 0; i < 64; ++i) {
    float vv = vb[(size_t)i * Dd];
    #pragma unroll
    for (int u = 0; u < 40; ++u) acc[u] = fmaf(Pl[u][w * 64 + i], vv, acc[u]);
  }
  float* pp = partial + ((size_t)(bh * 32 + chunk * 4 + w) * Uu) * Dd + lane;
  #pragma unroll
  for (int u = 0; u < 40; ++u) pp[(size_t)u * Dd] = acc[u];
}

// ---------- reduce partials -> upd[bhu][d] ----------
__global__ __launch_bounds__(64) void upd_reduce_kernel(
    const float* __restrict__ partial, const float* __restrict__ Z, float* __restrict__ upd)
{
  int bhu = blockIdx.x, t = threadIdx.x;
  int bh = bhu / Uu, u = bhu % Uu;
  float s = 0.f;
  for (int c = 0; c < 32; ++c)
    s += partial[((size_t)(bh * 32 + c) * Uu + u) * Dd + t];
  upd[(size_t)bhu * Dd + t] = s / Z[bhu];
}

// ---------- scatter map[b][h][n] = bhu index ----------
__global__ __launch_bounds__(256) void scatter_map_kernel(
    const int* __restrict__ M_top, int* __restrict__ map)
{
  int i = blockIdx.x * 256 + threadIdx.x;
  if (i < BH * Uu) {
    int bh = i / Uu;
    int r = M_top[i];
    map[bh * Nn + r] = i;
  }
}

// ---------- dout[bhu][c] = (upd - vmean) @ Wo_h ----------
__global__ __launch_bounds__(256) void delta_dout_kernel(
    const float* __restrict__ upd, const float* __restrict__ vmean,
    const float* __restrict__ Wo, float* __restrict__ dout)
{
  int bhu = blockIdx.x, t = threadIdx.x;
  int bh = bhu / Uu, h = bh & 7;
  __shared__ float dv[64];
  if (t < 64) dv[t] = upd[(size_t)bhu * Dd + t] - vmean[bh * Dd + t];
  __syncthreads();
  for (int c = t; c < 512; c += 256) {
    float s = 0.f;
    #pragma unroll
    for (int d = 0; d < 64; ++d)
      s = fmaf(dv[d], Wo[(size_t)(h * 64 + d) * 512 + c], s);
    dout[(size_t)bhu * 512 + c] = s;
  }
}

// ---------- base[b][c] = vmean_b @ Wo + bo ----------
__global__ __launch_bounds__(256) void base_kernel(
    const float* __restrict__ vmean, const float* __restrict__ Wo,
    const float* __restrict__ bo, float* __restrict__ base)
{
  int b = blockIdx.x, t = threadIdx.x;
  __shared__ float vm[512];
  vm[t] = vmean[b * 512 + t];
  vm[t + 256] = vmean[b * 512 + t + 256];
  __syncthreads();
  for (int c = t; c < 512; c += 256) {
    float s = bo[c];
    for (int k2 = 0; k2 < 512; ++k2)
      s = fmaf(vm[k2], Wo[(size_t)k2 * 512 + c], s);
    base[b * 512 + c] = s;
  }
}

// ---------- assemble out rows ----------
__global__ __launch_bounds__(256) void assemble_kernel(
    const float* __restrict__ base, const int* __restrict__ map,
    const float* __restrict__ dout, float* __restrict__ out)
{
  int t = threadIdx.x;
  int row = blockIdx.x * 4 + (t >> 6);
  int lane = t & 63;
  int b = row >> 11, n = row & 2047;
  float4 a0 = *(const float4*)(base + b * 512 + lane * 4);
  float4 a1 = *(const float4*)(base + b * 512 + 256 + lane * 4);
  for (int h = 0; h < 8; ++h) {
    int mi = map[(b * Hh + h) * Nn + n];
    if (mi >= 0) {
      const float* dp = dout + (size_t)mi * 512;
      float4 d0 = *(const float4*)(dp + lane * 4);
      float4 d1 = *(const float4*)(dp + 256 + lane * 4);
      a0.x += d0.x; a0.y += d0.y; a0.z += d0.z; a0.w += d0.w;
      a1.x += d1.x; a1.y += d1.y; a1.z += d1.z; a1.w += d1.w;
    }
  }
  *(float4*)(out + (size_t)row * 512 + lane * 4) = a0;
  *(float4*)(out + (size_t)row * 512 + 256 + lane * 4) = a1;
}

} // namespace

extern "C" void kernel_launch(void* const* d_in, const int* in_sizes, int n_in,
                              void* d_out, int out_size, void* d_ws, size_t ws_size,
                              hipStream_t stream) {
  const float* x  = (const float*)d_in[0];
  const float* Wq = (const float*)d_in[1];
  const float* bq = (const float*)d_in[2];
  const float* Wk = (const float*)d_in[3];
  const float* bk = (const float*)d_in[4];
  const float* Wv = (const float*)d_in[5];
  const float* bv = (const float*)d_in[6];
  const float* Wo = (const float*)d_in[7];
  const float* bo = (const float*)d_in[8];
  const int* idx  = (const int*)d_in[9];
  float* out = (float*)d_out;

  float* ws = (float*)d_ws;
  float* q      = ws;                       // 4,194,304 f
  float* kbuf   = ws + 4194304;
  float* vbuf   = ws + 8388608;
  float* S      = ws + 12582912;            // 2,621,440 f  [32][40][2048]
  float* Mbuf   = ws + 15204352;            // 262,144 f
  float* vmean  = ws + 15466496;            // 2,048 f
  float* Z      = ws + 15468544;            // 1,280 f
  float* upd    = ws + 15469824;            // 81,920 f
  float* base   = ws + 15551744;            // 2,048 f
  float* dout   = ws + 15553792;            // 655,360 f
  int*   M_top  = (int*)(ws + 16209152);    // 1,280
  int*   map    = (int*)(ws + 16210432);    // 65,536
  unsigned short* xh  = (unsigned short*)(ws + 16275968); // 4,194,304 bf16
  unsigned short* xl  = (unsigned short*)(ws + 18373120);
  unsigned short* WTh = (unsigned short*)(ws + 20470272); // 786,432 bf16
  unsigned short* WTl = (unsigned short*)(ws + 20863488);
  float* partial = ws + 16275968;           // overlays xh/xl after gemm (2,621,440 f)

  convert_x<<<4096, 256, 0, stream>>>(x, xh, xl);
  convert_w<<<1536, 256, 0, stream>>>(Wq, Wk, Wv, WTh, WTl);

  gemm_qkv<<<dim3(64, 12), 256, 0, stream>>>(xh, xl, WTh, WTl, bq, bk, bv, q, kbuf, vbuf);

  sampled_qk_kernel<<<(BH * Nn) / 4, 256, 0, stream>>>(q, kbuf, idx, Mbuf);
  topk_kernel<<<BH, 64, 0, stream>>>(Mbuf, M_top);
  vmean_kernel<<<BH, 256, 0, stream>>>(vbuf, vmean);

  scores_kernel<<<dim3(8, BH), 256, 0, stream>>>(q, kbuf, M_top, S);
  softmax_kernel<<<BH * Uu, 256, 0, stream>>>(S, Z);
  pv_kernel<<<dim3(8, BH), 256, 0, stream>>>(S, vbuf, partial);
  upd_reduce_kernel<<<BH * Uu, 64, 0, stream>>>(partial, Z, upd);

  hipMemsetAsync(map, 0xFF, BH * Nn * sizeof(int), stream);
  scatter_map_kernel<<<5, 256, 0, stream>>>(M_top, map);
  delta_dout_kernel<<<BH * Uu, 256, 0, stream>>>(upd, vmean, Wo, dout);
  base_kernel<<<Bb, 256, 0, stream>>>(vmean, Wo, bo, base);
  assemble_kernel<<<M_ROWS / 4, 256, 0, stream>>>(base, map, dout, out);
}

// Round 3
// 341.428 us; speedup vs baseline: 1.6902x; 1.2588x over previous
//
#include <hip/hip_runtime.h>
#include <math.h>

namespace {

constexpr int Bb = 4, Nn = 2048, Cc = 512, Hh = 8, Dd = 64, Ss = 40, Uu = 40;
constexpr int M_ROWS = Bb * Nn; // 8192
constexpr int BH = Bb * Hh;     // 32

typedef __attribute__((ext_vector_type(8))) short short8;
typedef __attribute__((ext_vector_type(4))) float f32x4;

__device__ inline unsigned short f2bf(float f) {
  union { float f; unsigned u; } v; v.f = f;
  unsigned r = (v.u + 0x7fffu + ((v.u >> 16) & 1u)) >> 16;
  return (unsigned short)r;
}
__device__ inline float bf2f(unsigned short h) {
  union { unsigned u; float f; } v; v.u = ((unsigned)h) << 16;
  return v.f;
}

// ---------- split x into bf16 hi/lo ----------
__global__ __launch_bounds__(256) void convert_x(
    const float* __restrict__ x, unsigned short* __restrict__ xh, unsigned short* __restrict__ xl)
{
  size_t i = ((size_t)blockIdx.x * 256 + threadIdx.x) * 4;
  float4 v = *(const float4*)(x + i);
  ushort4 h, l;
  h.x = f2bf(v.x); l.x = f2bf(v.x - bf2f(h.x));
  h.y = f2bf(v.y); l.y = f2bf(v.y - bf2f(h.y));
  h.z = f2bf(v.z); l.z = f2bf(v.z - bf2f(h.z));
  h.w = f2bf(v.w); l.w = f2bf(v.w - bf2f(h.w));
  *(ushort4*)(xh + i) = h;
  *(ushort4*)(xl + i) = l;
}

// ---------- build transposed+split weights WT[1536][512] ----------
__global__ __launch_bounds__(256) void convert_w(
    const float* __restrict__ Wq, const float* __restrict__ Wk, const float* __restrict__ Wv,
    unsigned short* __restrict__ WTh, unsigned short* __restrict__ WTl)
{
  int nrow = blockIdx.x;
  int which = nrow >> 9, col = nrow & 511;
  const float* Wsrc = which == 0 ? Wq : (which == 1 ? Wk : Wv);
  for (int kk = threadIdx.x; kk < 512; kk += 256) {
    float v = Wsrc[(size_t)kk * 512 + col];
    unsigned short h = f2bf(v);
    WTh[(size_t)nrow * 512 + kk] = h;
    WTl[(size_t)nrow * 512 + kk] = f2bf(v - bf2f(h));
  }
}

// ---------- bf16 split-precision MFMA GEMM: QKV projection ----------
// 4-tile staging (Ah,Al,Bh,Bl) per K-step of 32; acc = Ah*Bh + Al*Bh + Ah*Bl.
// Chunk-XOR swizzle vs LDS bank conflicts: stored chunk p holds global chunk
// p ^ (row&3); read at p = want ^ (row&3). Source pre-swizzled (rule #21).
__global__ __launch_bounds__(256) void gemm_qkv(
    const unsigned short* __restrict__ xh, const unsigned short* __restrict__ xl,
    const unsigned short* __restrict__ WTh, const unsigned short* __restrict__ WTl,
    const float* __restrict__ bq, const float* __restrict__ bk, const float* __restrict__ bv,
    float* __restrict__ qf, float* __restrict__ kf, float* __restrict__ vf)
{
  __shared__ __align__(16) unsigned short Ah[128 * 32];
  __shared__ __align__(16) unsigned short Al[128 * 32];
  __shared__ __align__(16) unsigned short Bh[128 * 32];
  __shared__ __align__(16) unsigned short Bl[128 * 32];
  int tid = threadIdx.x;
  int lane = tid & 63, w = tid >> 6;
  int bm = blockIdx.x * 128, bn = blockIdx.y * 128;

  f32x4 acc[4][4];
  #pragma unroll
  for (int i = 0; i < 4; ++i)
    #pragma unroll
    for (int j = 0; j < 4; ++j)
      #pragma unroll
      for (int r = 0; r < 4; ++r) acc[i][j][r] = 0.f;

  int wm = (w >> 1) * 64, wn = (w & 1) * 64;
  int lm = lane & 15, lg = lane >> 4;

  // staging geometry: per call, wave w covers rows w*16+(lane>>2) (+call*64),
  // chunk c = lane&3; LDS dest = tile + call*4096 + w*1024 (+lane*16 by HW).
  int srow = (lane >> 2);
  int cs = (lane & 3) ^ (srow & 3);   // pre-swizzled source chunk

  for (int kt = 0; kt < 16; ++kt) {
    int k0 = kt * 32;
    #pragma unroll
    for (int call = 0; call < 2; ++call) {
      int row = w * 16 + srow + call * 64;
      size_t offA = (size_t)(bm + row) * 512 + k0 + cs * 8;
      size_t offB = (size_t)(bn + row) * 512 + k0 + cs * 8;
      unsigned dst = call * 4096 + w * 1024;
      __builtin_amdgcn_global_load_lds(
          (const __attribute__((address_space(1))) void*)(xh + offA),
          (__attribute__((address_space(3))) void*)((char*)Ah + dst), 16, 0, 0);
      __builtin_amdgcn_global_load_lds(
          (const __attribute__((address_space(1))) void*)(xl + offA),
          (__attribute__((address_space(3))) void*)((char*)Al + dst), 16, 0, 0);
      __builtin_amdgcn_global_load_lds(
          (const __attribute__((address_space(1))) void*)(WTh + offB),
          (__attribute__((address_space(3))) void*)((char*)Bh + dst), 16, 0, 0);
      __builtin_amdgcn_global_load_lds(
          (const __attribute__((address_space(1))) void*)(WTl + offB),
          (__attribute__((address_space(3))) void*)((char*)Bl + dst), 16, 0, 0);
    }
    __syncthreads();

    short8 afh[4], bgh[4], afl[4], bgl[4];
    #pragma unroll
    for (int i = 0; i < 4; ++i) {
      int R = wm + i * 16 + lm;
      afh[i] = *(const short8*)(Ah + R * 32 + ((lg ^ (R & 3)) * 8));
    }
    #pragma unroll
    for (int j = 0; j < 4; ++j) {
      int R = wn + j * 16 + lm;
      bgh[j] = *(const short8*)(Bh + R * 32 + ((lg ^ (R & 3)) * 8));
    }
    #pragma unroll
    for (int i = 0; i < 4; ++i)
      #pragma unroll
      for (int j = 0; j < 4; ++j)
        acc[i][j] = __builtin_amdgcn_mfma_f32_16x16x32_bf16(afh[i], bgh[j], acc[i][j], 0, 0, 0);

    #pragma unroll
    for (int i = 0; i < 4; ++i) {
      int R = wm + i * 16 + lm;
      afl[i] = *(const short8*)(Al + R * 32 + ((lg ^ (R & 3)) * 8));
    }
    #pragma unroll
    for (int i = 0; i < 4; ++i)
      #pragma unroll
      for (int j = 0; j < 4; ++j)
        acc[i][j] = __builtin_amdgcn_mfma_f32_16x16x32_bf16(afl[i], bgh[j], acc[i][j], 0, 0, 0);

    #pragma unroll
    for (int j = 0; j < 4; ++j) {
      int R = wn + j * 16 + lm;
      bgl[j] = *(const short8*)(Bl + R * 32 + ((lg ^ (R & 3)) * 8));
    }
    #pragma unroll
    for (int i = 0; i < 4; ++i)
      #pragma unroll
      for (int j = 0; j < 4; ++j)
        acc[i][j] = __builtin_amdgcn_mfma_f32_16x16x32_bf16(afh[i], bgl[j], acc[i][j], 0, 0, 0);

    __syncthreads();
  }

  #pragma unroll
  for (int j = 0; j < 4; ++j) {
    int n = bn + wn + j * 16 + lm;
    float bias = n < 512 ? bq[n] : (n < 1024 ? bk[n - 512] : bv[n - 1024]);
    int tensor = n >> 9, h = (n >> 6) & 7, d = n & 63;
    float* op = tensor == 0 ? qf : (tensor == 1 ? kf : vf);
    #pragma unroll
    for (int i = 0; i < 4; ++i) {
      #pragma unroll
      for (int r = 0; r < 4; ++r) {
        int m = bm + wm + i * 16 + lg * 4 + r;
        int b = m >> 11, nn = m & 2047;
        op[((size_t)(b * Hh + h) * Nn + nn) * Dd + d] = acc[i][j][r] + bias;
      }
    }
  }
}

// ---------- sampled QK^T -> M = max - mean ----------
// One block per l (indices shared across all 32 bh!). Per instruction,
// 4 consecutive lanes cover consecutive 16B of one K row -> minimal
// line-requests (1 per 64B line), 16 rows per instruction.
__global__ __launch_bounds__(256) void sampled_qk_kernel(
    const float* __restrict__ q, const float* __restrict__ k,
    const int* __restrict__ idx, float* __restrict__ Mout)
{
  int l = blockIdx.x;
  int t = threadIdx.x;
  __shared__ int ridx[40];
  __shared__ float dots[32][40];
  if (t < 40) ridx[t] = idx[(size_t)l * Ss + t];
  __syncthreads();

  int w = t >> 6, lane = t & 63;
  int g = lane >> 2, dq = lane & 3;
  int bh = (w & 1) * 16 + g;

  const float* qrow = q + ((size_t)bh * Nn + l) * Dd + dq * 4;
  float4 qv[4];
  #pragma unroll
  for (int i = 0; i < 4; ++i) qv[i] = *(const float4*)(qrow + i * 16);

  for (int s0 = 0; s0 < 40; s0 += 2) {
    int s = s0 + (w >> 1);
    const float* krow = k + ((size_t)bh * Nn + ridx[s]) * Dd + dq * 4;
    float dot = 0.f;
    #pragma unroll
    for (int i = 0; i < 4; ++i) {
      float4 kv = *(const float4*)(krow + i * 16);
      dot += kv.x * qv[i].x + kv.y * qv[i].y + kv.z * qv[i].z + kv.w * qv[i].w;
    }
    dot += __shfl_xor(dot, 1);
    dot += __shfl_xor(dot, 2);
    if (dq == 0) dots[bh][s] = dot;
  }
  __syncthreads();

  // M per bh: wave w handles bh2 = w*8 + (lane>>3); 8 lanes per bh
  int bh2 = w * 8 + (lane >> 3);
  int j = lane & 7;
  float mx = -INFINITY, sm = 0.f;
  for (int s = j; s < 40; s += 8) {
    float v = dots[bh2][s];
    mx = fmaxf(mx, v); sm += v;
  }
  #pragma unroll
  for (int o = 1; o < 8; o <<= 1) {
    mx = fmaxf(mx, __shfl_xor(mx, o));
    sm += __shfl_xor(sm, o);
  }
  if (j == 0) Mout[(size_t)bh2 * Nn + l] = mx - sm * (1.f / (float)Nn);
}

// ---------- top-40 per (b,h): single wave, register-resident ----------
__global__ __launch_bounds__(64) void topk_kernel(
    const float* __restrict__ Min, int* __restrict__ M_top)
{
  int bh = blockIdx.x, lane = threadIdx.x;
  const float* row = Min + (size_t)bh * Nn;
  float v[32];
  #pragma unroll
  for (int j = 0; j < 32; ++j) v[j] = row[j * 64 + lane];
  unsigned mask = 0;
  for (int it = 0; it < Uu; ++it) {
    float best = -INFINITY; int bidx = 0x7FFFFFFF;
    #pragma unroll
    for (int j = 0; j < 32; ++j) {
      if (!((mask >> j) & 1u) && v[j] > best) { best = v[j]; bidx = j * 64 + lane; }
    }
    #pragma unroll
    for (int o = 32; o; o >>= 1) {
      float ov = __shfl_xor(best, o);
      int oi = __shfl_xor(bidx, o);
      if (ov > best || (ov == best && oi < bidx)) { best = ov; bidx = oi; }
    }
    if ((bidx & 63) == lane) mask |= 1u << (bidx >> 6);
    if (lane == 0) M_top[bh * Uu + it] = bidx;
  }
}

// ---------- mean of V over N per (b,h,d) ----------
__global__ __launch_bounds__(256) void vmean_kernel(
    const float* __restrict__ v, float* __restrict__ vmean)
{
  int bh = blockIdx.x, t = threadIdx.x;
  int d = t & 63, chunk = t >> 6;
  const float* base = v + (size_t)bh * Nn * Dd;
  float s = 0.f;
  for (int n = chunk * 512; n < (chunk + 1) * 512; ++n) s += base[(size_t)n * Dd + d];
  __shared__ float part[4][64];
  part[chunk][d] = s;
  __syncthreads();
  if (t < 64)
    vmean[bh * Dd + t] = (part[0][t] + part[1][t] + part[2][t] + part[3][t]) * (1.f / (float)Nn);
}

// ---------- scores: S[bh][u][n] = (Qr . K^T) * scale, chunked over n ----------
__global__ __launch_bounds__(256) void scores_kernel(
    const float* __restrict__ q, const float* __restrict__ k,
    const int* __restrict__ M_top, float* __restrict__ S)
{
  int chunk = blockIdx.x, bh = blockIdx.y, t = threadIdx.x;
  __shared__ float qs[40][64];
  if (t < 160) {
    int u = t >> 2, p = (t & 3) * 16;
    int r = M_top[bh * Uu + u];
    const float4* src = (const float4*)(q + ((size_t)bh * Nn + r) * Dd + p);
    *(float4*)&qs[u][p + 0]  = src[0];
    *(float4*)&qs[u][p + 4]  = src[1];
    *(float4*)&qs[u][p + 8]  = src[2];
    *(float4*)&qs[u][p + 12] = src[3];
  }
  __syncthreads();
  int n = chunk * 256 + t;
  const float4* krow = (const float4*)(k + ((size_t)bh * Nn + n) * Dd);
  float acc[40];
  #pragma unroll
  for (int u = 0; u < 40; ++u) acc[u] = 0.f;
  #pragma unroll
  for (int d4 = 0; d4 < 16; ++d4) {
    float4 kv = krow[d4];
    #pragma unroll
    for (int u = 0; u < 40; ++u) {
      float4 qv = *(const float4*)&qs[u][d4 * 4];
      acc[u] += qv.x * kv.x + qv.y * kv.y + qv.z * kv.z + qv.w * kv.w;
    }
  }
  #pragma unroll
  for (int u = 0; u < 40; ++u)
    S[((size_t)bh * Uu + u) * Nn + n] = acc[u] * 0.125f;
}

// ---------- softmax over rows of S (in place), Z = row sum ----------
__global__ __launch_bounds__(256) void softmax_kernel(
    float* __restrict__ S, float* __restrict__ Z)
{
  int row = blockIdx.x, t = threadIdx.x;
  float* p = S + (size_t)row * Nn + t * 8;
  float4 a = *(float4*)p, b = *(float4*)(p + 4);
  __shared__ float red[256];
  float m = fmaxf(fmaxf(fmaxf(a.x, a.y), fmaxf(a.z, a.w)),
                  fmaxf(fmaxf(b.x, b.y), fmaxf(b.z, b.w)));
  red[t] = m; __syncthreads();
  for (int s = 128; s; s >>= 1) { if (t < s) red[t] = fmaxf(red[t], red[t + s]); __syncthreads(); }
  m = red[0]; __syncthreads();
  a.x = expf(a.x - m); a.y = expf(a.y - m); a.z = expf(a.z - m); a.w = expf(a.w - m);
  b.x = expf(b.x - m); b.y = expf(b.y - m); b.z = expf(b.z - m); b.w = expf(b.w - m);
  float sm = a.x + a.y + a.z + a.w + b.x + b.y + b.z + b.w;
  red[t] = sm; __syncthreads();
  for (int s = 128; s; s >>= 1) { if (t < s) red[t] += red[t + s]; __syncthreads(); }
  if (t == 0) Z[row] = red[0];
  *(float4*)p = a; *(float4*)(p + 4) = b;
}

// ---------- PV partial: partial[bh][cw][u][d] over n-chunks ----------
__global__ __launch_bounds__(256) void pv_kernel(
    const float* __restrict__ P, const float* __restrict__ v, float* __restrict__ partial)
{
  int chunk = blockIdx.x, bh = blockIdx.y, t = threadIdx.x;
  __shared__ float Pl[40][256];
  for (int u = 0; u < 40; ++u)
    Pl[u][t] = P[((size_t)bh * Uu + u) * Nn + chunk * 256 + t];
  __syncthreads();
  int lane = t & 63, w = t >> 6;
  float acc[40];
  #pragma unroll
  for (int u = 0; u < 40; ++u) acc[u] = 0.f;
  const float* vb = v + ((size_t)bh * Nn + chunk * 256 + w * 64) * Dd + lane;
  for (int i = 0; i < 64; ++i) {
    float vv = vb[(size_t)i * Dd];
    #pragma unroll
    for (int u = 0; u < 40; ++u) acc[u] = fmaf(Pl[u][w * 64 + i], vv, acc[u]);
  }
  float* pp = partial + ((size_t)(bh * 32 + chunk * 4 + w) * Uu) * Dd + lane;
  #pragma unroll
  for (int u = 0; u < 40; ++u) pp[(size_t)u * Dd] = acc[u];
}

// ---------- reduce partials -> upd[bhu][d] ----------
__global__ __launch_bounds__(64) void upd_reduce_kernel(
    const float* __restrict__ partial, const float* __restrict__ Z, float* __restrict__ upd)
{
  int bhu = blockIdx.x, t = threadIdx.x;
  int bh = bhu / Uu, u = bhu % Uu;
  float s = 0.f;
  for (int c = 0; c < 32; ++c)
    s += partial[((size_t)(bh * 32 + c) * Uu + u) * Dd + t];
  upd[(size_t)bhu * Dd + t] = s / Z[bhu];
}

// ---------- scatter map[b][h][n] = bhu index ----------
__global__ __launch_bounds__(256) void scatter_map_kernel(
    const int* __restrict__ M_top, int* __restrict__ map)
{
  int i = blockIdx.x * 256 + threadIdx.x;
  if (i < BH * Uu) {
    int bh = i / Uu;
    int r = M_top[i];
    map[bh * Nn + r] = i;
  }
}

// ---------- dout[bhu][c] = (upd - vmean) @ Wo_h ----------
__global__ __launch_bounds__(256) void delta_dout_kernel(
    const float* __restrict__ upd, const float* __restrict__ vmean,
    const float* __restrict__ Wo, float* __restrict__ dout)
{
  int bhu = blockIdx.x, t = threadIdx.x;
  int bh = bhu / Uu, h = bh & 7;
  __shared__ float dv[64];
  if (t < 64) dv[t] = upd[(size_t)bhu * Dd + t] - vmean[bh * Dd + t];
  __syncthreads();
  for (int c = t; c < 512; c += 256) {
    float s = 0.f;
    #pragma unroll
    for (int d = 0; d < 64; ++d)
      s = fmaf(dv[d], Wo[(size_t)(h * 64 + d) * 512 + c], s);
    dout[(size_t)bhu * 512 + c] = s;
  }
}

// ---------- base[b][c] = vmean_b @ Wo + bo ----------
__global__ __launch_bounds__(256) void base_kernel(
    const float* __restrict__ vmean, const float* __restrict__ Wo,
    const float* __restrict__ bo, float* __restrict__ base)
{
  int b = blockIdx.x, t = threadIdx.x;
  __shared__ float vm[512];
  vm[t] = vmean[b * 512 + t];
  vm[t + 256] = vmean[b * 512 + t + 256];
  __syncthreads();
  for (int c = t; c < 512; c += 256) {
    float s = bo[c];
    for (int k2 = 0; k2 < 512; ++k2)
      s = fmaf(vm[k2], Wo[(size_t)k2 * 512 + c], s);
    base[b * 512 + c] = s;
  }
}

// ---------- assemble out rows ----------
__global__ __launch_bounds__(256) void assemble_kernel(
    const float* __restrict__ base, const int* __restrict__ map,
    const float* __restrict__ dout, float* __restrict__ out)
{
  int t = threadIdx.x;
  int row = blockIdx.x * 4 + (t >> 6);
  int lane = t & 63;
  int b = row >> 11, n = row & 2047;
  float4 a0 = *(const float4*)(base + b * 512 + lane * 4);
  float4 a1 = *(const float4*)(base + b * 512 + 256 + lane * 4);
  for (int h = 0; h < 8; ++h) {
    int mi = map[(b * Hh + h) * Nn + n];
    if (mi >= 0) {
      const float* dp = dout + (size_t)mi * 512;
      float4 d0 = *(const float4*)(dp + lane * 4);
      float4 d1 = *(const float4*)(dp + 256 + lane * 4);
      a0.x += d0.x; a0.y += d0.y; a0.z += d0.z; a0.w += d0.w;
      a1.x += d1.x; a1.y += d1.y; a1.z += d1.z; a1.w += d1.w;
    }
  }
  *(float4*)(out + (size_t)row * 512 + lane * 4) = a0;
  *(float4*)(out + (size_t)row * 512 + 256 + lane * 4) = a1;
}

} // namespace

extern "C" void kernel_launch(void* const* d_in, const int* in_sizes, int n_in,
                              void* d_out, int out_size, void* d_ws, size_t ws_size,
                              hipStream_t stream) {
  const float* x  = (const float*)d_in[0];
  const float* Wq = (const float*)d_in[1];
  const float* bq = (const float*)d_in[2];
  const float* Wk = (const float*)d_in[3];
  const float* bk = (const float*)d_in[4];
  const float* Wv = (const float*)d_in[5];
  const float* bv = (const float*)d_in[6];
  const float* Wo = (const float*)d_in[7];
  const float* bo = (const float*)d_in[8];
  const int* idx  = (const int*)d_in[9];
  float* out = (float*)d_out;

  float* ws = (float*)d_ws;
  float* q      = ws;                       // 4,194,304 f
  float* kbuf   = ws + 4194304;
  float* vbuf   = ws + 8388608;
  float* S      = ws + 12582912;            // 2,621,440 f  [32][40][2048]
  float* Mbuf   = ws + 15204352;            // 262,144 f
  float* vmean  = ws + 15466496;            // 2,048 f
  float* Z      = ws + 15468544;            // 1,280 f
  float* upd    = ws + 15469824;            // 81,920 f
  float* base   = ws + 15551744;            // 2,048 f
  float* dout   = ws + 15553792;            // 655,360 f
  int*   M_top  = (int*)(ws + 16209152);    // 1,280
  int*   map    = (int*)(ws + 16210432);    // 65,536
  unsigned short* xh  = (unsigned short*)(ws + 16275968); // 4,194,304 bf16
  unsigned short* xl  = (unsigned short*)(ws + 18373120);
  unsigned short* WTh = (unsigned short*)(ws + 20470272); // 786,432 bf16
  unsigned short* WTl = (unsigned short*)(ws + 20863488);
  float* partial = ws + 16275968;           // overlays xh/xl after gemm

  convert_x<<<4096, 256, 0, stream>>>(x, xh, xl);
  convert_w<<<1536, 256, 0, stream>>>(Wq, Wk, Wv, WTh, WTl);

  gemm_qkv<<<dim3(64, 12), 256, 0, stream>>>(xh, xl, WTh, WTl, bq, bk, bv, q, kbuf, vbuf);

  sampled_qk_kernel<<<Nn, 256, 0, stream>>>(q, kbuf, idx, Mbuf);
  topk_kernel<<<BH, 64, 0, stream>>>(Mbuf, M_top);
  vmean_kernel<<<BH, 256, 0, stream>>>(vbuf, vmean);

  scores_kernel<<<dim3(8, BH), 256, 0, stream>>>(q, kbuf, M_top, S);
  softmax_kernel<<<BH * Uu, 256, 0, stream>>>(S, Z);
  pv_kernel<<<dim3(8, BH), 256, 0, stream>>>(S, vbuf, partial);
  upd_reduce_kernel<<<BH * Uu, 64, 0, stream>>>(partial, Z, upd);

  hipMemsetAsync(map, 0xFF, BH * Nn * sizeof(int), stream);
  scatter_map_kernel<<<5, 256, 0, stream>>>(M_top, map);
  delta_dout_kernel<<<BH * Uu, 256, 0, stream>>>(upd, vmean, Wo, dout);
  base_kernel<<<Bb, 256, 0, stream>>>(vmean, Wo, bo, base);
  assemble_kernel<<<M_ROWS / 4, 256, 0, stream>>>(base, map, dout, out);
}

// Round 4
// 299.652 us; speedup vs baseline: 1.9259x; 1.1394x over previous
//
#include <hip/hip_runtime.h>
#include <math.h>

namespace {

constexpr int Bb = 4, Nn = 2048, Cc = 512, Hh = 8, Dd = 64, Ss = 40, Uu = 40;
constexpr int M_ROWS = Bb * Nn; // 8192
constexpr int BH = Bb * Hh;     // 32

typedef __attribute__((ext_vector_type(8))) short short8;
typedef __attribute__((ext_vector_type(4))) float f32x4;

__device__ inline unsigned short f2bf(float f) {
  union { float f; unsigned u; } v; v.f = f;
  unsigned r = (v.u + 0x7fffu + ((v.u >> 16) & 1u)) >> 16;
  return (unsigned short)r;
}
__device__ inline float bf2f(unsigned short h) {
  union { unsigned u; float f; } v; v.u = ((unsigned)h) << 16;
  return v.f;
}

// ---------- split x into bf16 hi/lo AND build transposed split weights ----------
__global__ __launch_bounds__(256) void convert_all(
    const float* __restrict__ x, const float* __restrict__ Wq,
    const float* __restrict__ Wk, const float* __restrict__ Wv,
    unsigned short* __restrict__ xh, unsigned short* __restrict__ xl,
    unsigned short* __restrict__ WTh, unsigned short* __restrict__ WTl)
{
  if (blockIdx.x < 4096) {
    size_t i = ((size_t)blockIdx.x * 256 + threadIdx.x) * 4;
    float4 v = *(const float4*)(x + i);
    ushort4 h, l;
    h.x = f2bf(v.x); l.x = f2bf(v.x - bf2f(h.x));
    h.y = f2bf(v.y); l.y = f2bf(v.y - bf2f(h.y));
    h.z = f2bf(v.z); l.z = f2bf(v.z - bf2f(h.z));
    h.w = f2bf(v.w); l.w = f2bf(v.w - bf2f(h.w));
    *(ushort4*)(xh + i) = h;
    *(ushort4*)(xl + i) = l;
  } else {
    int nrow = blockIdx.x - 4096;
    int which = nrow >> 9, col = nrow & 511;
    const float* Wsrc = which == 0 ? Wq : (which == 1 ? Wk : Wv);
    for (int kk = threadIdx.x; kk < 512; kk += 256) {
      float v = Wsrc[(size_t)kk * 512 + col];
      unsigned short h = f2bf(v);
      WTh[(size_t)nrow * 512 + kk] = h;
      WTl[(size_t)nrow * 512 + kk] = f2bf(v - bf2f(h));
    }
  }
}

// ---------- bf16 split-precision MFMA GEMM: QKV projection ----------
__global__ __launch_bounds__(256) void gemm_qkv(
    const unsigned short* __restrict__ xh, const unsigned short* __restrict__ xl,
    const unsigned short* __restrict__ WTh, const unsigned short* __restrict__ WTl,
    const float* __restrict__ bq, const float* __restrict__ bk, const float* __restrict__ bv,
    float* __restrict__ qf, float* __restrict__ kf, float* __restrict__ vf)
{
  __shared__ __align__(16) unsigned short Ah[128 * 32];
  __shared__ __align__(16) unsigned short Al[128 * 32];
  __shared__ __align__(16) unsigned short Bh[128 * 32];
  __shared__ __align__(16) unsigned short Bl[128 * 32];
  int tid = threadIdx.x;
  int lane = tid & 63, w = tid >> 6;
  int bm = blockIdx.x * 128, bn = blockIdx.y * 128;

  f32x4 acc[4][4];
  #pragma unroll
  for (int i = 0; i < 4; ++i)
    #pragma unroll
    for (int j = 0; j < 4; ++j)
      #pragma unroll
      for (int r = 0; r < 4; ++r) acc[i][j][r] = 0.f;

  int wm = (w >> 1) * 64, wn = (w & 1) * 64;
  int lm = lane & 15, lg = lane >> 4;

  int srow = (lane >> 2);
  int cs = (lane & 3) ^ (srow & 3);   // pre-swizzled source chunk

  for (int kt = 0; kt < 16; ++kt) {
    int k0 = kt * 32;
    #pragma unroll
    for (int call = 0; call < 2; ++call) {
      int row = w * 16 + srow + call * 64;
      size_t offA = (size_t)(bm + row) * 512 + k0 + cs * 8;
      size_t offB = (size_t)(bn + row) * 512 + k0 + cs * 8;
      unsigned dst = call * 4096 + w * 1024;
      __builtin_amdgcn_global_load_lds(
          (const __attribute__((address_space(1))) void*)(xh + offA),
          (__attribute__((address_space(3))) void*)((char*)Ah + dst), 16, 0, 0);
      __builtin_amdgcn_global_load_lds(
          (const __attribute__((address_space(1))) void*)(xl + offA),
          (__attribute__((address_space(3))) void*)((char*)Al + dst), 16, 0, 0);
      __builtin_amdgcn_global_load_lds(
          (const __attribute__((address_space(1))) void*)(WTh + offB),
          (__attribute__((address_space(3))) void*)((char*)Bh + dst), 16, 0, 0);
      __builtin_amdgcn_global_load_lds(
          (const __attribute__((address_space(1))) void*)(WTl + offB),
          (__attribute__((address_space(3))) void*)((char*)Bl + dst), 16, 0, 0);
    }
    __syncthreads();

    short8 afh[4], bgh[4], afl[4], bgl[4];
    #pragma unroll
    for (int i = 0; i < 4; ++i) {
      int R = wm + i * 16 + lm;
      afh[i] = *(const short8*)(Ah + R * 32 + ((lg ^ (R & 3)) * 8));
    }
    #pragma unroll
    for (int j = 0; j < 4; ++j) {
      int R = wn + j * 16 + lm;
      bgh[j] = *(const short8*)(Bh + R * 32 + ((lg ^ (R & 3)) * 8));
    }
    #pragma unroll
    for (int i = 0; i < 4; ++i)
      #pragma unroll
      for (int j = 0; j < 4; ++j)
        acc[i][j] = __builtin_amdgcn_mfma_f32_16x16x32_bf16(afh[i], bgh[j], acc[i][j], 0, 0, 0);

    #pragma unroll
    for (int i = 0; i < 4; ++i) {
      int R = wm + i * 16 + lm;
      afl[i] = *(const short8*)(Al + R * 32 + ((lg ^ (R & 3)) * 8));
    }
    #pragma unroll
    for (int i = 0; i < 4; ++i)
      #pragma unroll
      for (int j = 0; j < 4; ++j)
        acc[i][j] = __builtin_amdgcn_mfma_f32_16x16x32_bf16(afl[i], bgh[j], acc[i][j], 0, 0, 0);

    #pragma unroll
    for (int j = 0; j < 4; ++j) {
      int R = wn + j * 16 + lm;
      bgl[j] = *(const short8*)(Bl + R * 32 + ((lg ^ (R & 3)) * 8));
    }
    #pragma unroll
    for (int i = 0; i < 4; ++i)
      #pragma unroll
      for (int j = 0; j < 4; ++j)
        acc[i][j] = __builtin_amdgcn_mfma_f32_16x16x32_bf16(afh[i], bgl[j], acc[i][j], 0, 0, 0);

    __syncthreads();
  }

  #pragma unroll
  for (int j = 0; j < 4; ++j) {
    int n = bn + wn + j * 16 + lm;
    float bias = n < 512 ? bq[n] : (n < 1024 ? bk[n - 512] : bv[n - 1024]);
    int tensor = n >> 9, h = (n >> 6) & 7, d = n & 63;
    float* op = tensor == 0 ? qf : (tensor == 1 ? kf : vf);
    #pragma unroll
    for (int i = 0; i < 4; ++i) {
      #pragma unroll
      for (int r = 0; r < 4; ++r) {
        int m = bm + wm + i * 16 + lg * 4 + r;
        int b = m >> 11, nn = m & 2047;
        op[((size_t)(b * Hh + h) * Nn + nn) * Dd + d] = acc[i][j][r] + bias;
      }
    }
  }
}

// ---------- sampled QK^T -> M, bh-pinned to XCDs for L2 locality ----------
// Block p: xcd = p&7; bh = (p>>3>>4)*8 + xcd; chunk = (p>>3)&15 (128 l's).
// Each XCD touches only 4 bh's K (2 MB) -> L2-resident.
__global__ __launch_bounds__(256) void sampled_qk_kernel(
    const float* __restrict__ q, const float* __restrict__ k,
    const int* __restrict__ idx, float* __restrict__ Mout)
{
  int p = blockIdx.x;
  int xcd = p & 7, j = p >> 3;
  int chunk = j & 15;
  int bh = (j >> 4) * 8 + xcd;
  int t = threadIdx.x;
  int w = t >> 6, lane = t & 63;
  int g = lane >> 2, dq = lane & 3;

  const float* kb = k + (size_t)bh * Nn * Dd;

  for (int li = 0; li < 32; ++li) {
    int l = chunk * 128 + w * 32 + li;
    const float* qrow = q + ((size_t)bh * Nn + l) * Dd + dq * 4;
    float4 qv[4];
    #pragma unroll
    for (int i = 0; i < 4; ++i) qv[i] = *(const float4*)(qrow + i * 16);
    float mx = -INFINITY, sm = 0.f;
    #pragma unroll
    for (int pass = 0; pass < 3; ++pass) {
      int s = pass * 16 + g;
      bool valid = (s < Ss);
      float dot = 0.f;
      if (valid) {
        int kr = idx[l * Ss + s];
        const float* krow = kb + (size_t)kr * Dd + dq * 4;
        #pragma unroll
        for (int i = 0; i < 4; ++i) {
          float4 kv = *(const float4*)(krow + i * 16);
          dot += kv.x * qv[i].x + kv.y * qv[i].y + kv.z * qv[i].z + kv.w * qv[i].w;
        }
      }
      dot += __shfl_xor(dot, 1);
      dot += __shfl_xor(dot, 2);
      if (valid) { mx = fmaxf(mx, dot); sm += dot; }
    }
    #pragma unroll
    for (int o = 4; o < 64; o <<= 1) {
      mx = fmaxf(mx, __shfl_xor(mx, o));
      sm += __shfl_xor(sm, o);
    }
    if (lane == 0) Mout[(size_t)bh * Nn + l] = mx - sm * (1.f / (float)Nn);
  }
}

// ---------- top-40 per (b,h): single wave, register-resident ----------
__global__ __launch_bounds__(64) void topk_kernel(
    const float* __restrict__ Min, int* __restrict__ M_top)
{
  int bh = blockIdx.x, lane = threadIdx.x;
  const float* row = Min + (size_t)bh * Nn;
  float v[32];
  #pragma unroll
  for (int j = 0; j < 32; ++j) v[j] = row[j * 64 + lane];
  unsigned mask = 0;
  for (int it = 0; it < Uu; ++it) {
    float best = -INFINITY; int bidx = 0x7FFFFFFF;
    #pragma unroll
    for (int j = 0; j < 32; ++j) {
      if (!((mask >> j) & 1u) && v[j] > best) { best = v[j]; bidx = j * 64 + lane; }
    }
    #pragma unroll
    for (int o = 32; o; o >>= 1) {
      float ov = __shfl_xor(best, o);
      int oi = __shfl_xor(bidx, o);
      if (ov > best || (ov == best && oi < bidx)) { best = ov; bidx = oi; }
    }
    if ((bidx & 63) == lane) mask |= 1u << (bidx >> 6);
    if (lane == 0) M_top[bh * Uu + it] = bidx;
  }
}

// ---------- mean of V over N per (b,h,d) ----------
__global__ __launch_bounds__(256) void vmean_kernel(
    const float* __restrict__ v, float* __restrict__ vmean)
{
  int bh = blockIdx.x, t = threadIdx.x;
  int d = t & 63, chunk = t >> 6;
  const float* base = v + (size_t)bh * Nn * Dd;
  float s = 0.f;
  for (int n = chunk * 512; n < (chunk + 1) * 512; ++n) s += base[(size_t)n * Dd + d];
  __shared__ float part[4][64];
  part[chunk][d] = s;
  __syncthreads();
  if (t < 64)
    vmean[bh * Dd + t] = (part[0][t] + part[1][t] + part[2][t] + part[3][t]) * (1.f / (float)Nn);
}

// ---------- fused scores+softmax+PV partials, per (n-chunk, bh) ----------
// Outputs per (bh,chunk): pm[40], ps[40] (chunk max & expsum),
// partial[(bh*32 + chunk*4 + w)][40][64] unnormalized PV.
__global__ __launch_bounds__(256) void fused_attn_kernel(
    const float* __restrict__ q, const float* __restrict__ k, const float* __restrict__ v,
    const int* __restrict__ M_top, float* __restrict__ pm, float* __restrict__ ps,
    float* __restrict__ partial)
{
  int chunk = blockIdx.x, bh = blockIdx.y, t = threadIdx.x;
  __shared__ float qs[40][64];
  __shared__ float S[40][256];
  if (t < 160) {
    int u = t >> 2, p = (t & 3) * 16;
    int r = M_top[bh * Uu + u];
    const float4* src = (const float4*)(q + ((size_t)bh * Nn + r) * Dd + p);
    *(float4*)&qs[u][p + 0]  = src[0];
    *(float4*)&qs[u][p + 4]  = src[1];
    *(float4*)&qs[u][p + 8]  = src[2];
    *(float4*)&qs[u][p + 12] = src[3];
  }
  __syncthreads();

  // QK^T for this thread's n-column
  {
    int n = chunk * 256 + t;
    const float4* krow = (const float4*)(k + ((size_t)bh * Nn + n) * Dd);
    float acc[40];
    #pragma unroll
    for (int u = 0; u < 40; ++u) acc[u] = 0.f;
    #pragma unroll
    for (int d4 = 0; d4 < 16; ++d4) {
      float4 kv = krow[d4];
      #pragma unroll
      for (int u = 0; u < 40; ++u) {
        float4 qv = *(const float4*)&qs[u][d4 * 4];
        acc[u] += qv.x * kv.x + qv.y * kv.y + qv.z * kv.z + qv.w * kv.w;
      }
    }
    #pragma unroll
    for (int u = 0; u < 40; ++u) S[u][t] = acc[u] * 0.125f;
  }
  __syncthreads();

  // per-u chunk softmax: wave w handles u = w*10 .. w*10+9
  int w = t >> 6, lane = t & 63;
  #pragma unroll
  for (int r = 0; r < 10; ++r) {
    int u = w * 10 + r;
    float v0 = S[u][lane], v1 = S[u][lane + 64], v2 = S[u][lane + 128], v3 = S[u][lane + 192];
    float m = fmaxf(fmaxf(v0, v1), fmaxf(v2, v3));
    #pragma unroll
    for (int o = 1; o < 64; o <<= 1) m = fmaxf(m, __shfl_xor(m, o));
    float e0 = expf(v0 - m), e1 = expf(v1 - m), e2 = expf(v2 - m), e3 = expf(v3 - m);
    S[u][lane] = e0; S[u][lane + 64] = e1; S[u][lane + 128] = e2; S[u][lane + 192] = e3;
    float sum = e0 + e1 + e2 + e3;
    #pragma unroll
    for (int o = 1; o < 64; o <<= 1) sum += __shfl_xor(sum, o);
    if (lane == 0) {
      pm[(bh * 8 + chunk) * Uu + u] = m;
      ps[(bh * 8 + chunk) * Uu + u] = sum;
    }
  }
  __syncthreads();

  // PV: wave w handles n in [w*64, w*64+64), lane = d
  float acc2[40];
  #pragma unroll
  for (int u = 0; u < 40; ++u) acc2[u] = 0.f;
  const float* vb = v + ((size_t)bh * Nn + chunk * 256 + w * 64) * Dd + lane;
  for (int i = 0; i < 64; ++i) {
    float vv = vb[(size_t)i * Dd];
    #pragma unroll
    for (int u = 0; u < 40; ++u) acc2[u] = fmaf(S[u][w * 64 + i], vv, acc2[u]);
  }
  float* pp = partial + ((size_t)(bh * 32 + chunk * 4 + w) * Uu) * Dd + lane;
  #pragma unroll
  for (int u = 0; u < 40; ++u) pp[(size_t)u * Dd] = acc2[u];
}

// ---------- combine partials -> upd, dout = (upd - vmean) @ Wo_h, map ----------
__global__ __launch_bounds__(256) void attn_reduce_kernel(
    const float* __restrict__ pm, const float* __restrict__ ps,
    const float* __restrict__ partial, const float* __restrict__ vmean,
    const float* __restrict__ Wo, const int* __restrict__ M_top,
    float* __restrict__ dout, int* __restrict__ map)
{
  int bhu = blockIdx.x;
  int bh = bhu / Uu, u = bhu % Uu, h = bh & 7;
  int t = threadIdx.x;
  __shared__ float dv[64];
  __shared__ float w8[8];
  __shared__ float Zs;
  if (t == 0) {
    float m = -INFINITY;
    #pragma unroll
    for (int c = 0; c < 8; ++c) m = fmaxf(m, pm[(bh * 8 + c) * Uu + u]);
    float Z = 0.f;
    #pragma unroll
    for (int c = 0; c < 8; ++c) {
      float e = expf(pm[(bh * 8 + c) * Uu + u] - m);
      w8[c] = e;
      Z += e * ps[(bh * 8 + c) * Uu + u];
    }
    Zs = Z;
    map[bh * Nn + M_top[bhu]] = bhu;
  }
  __syncthreads();
  if (t < 64) {
    float s = 0.f;
    for (int c2 = 0; c2 < 32; ++c2)
      s += partial[((size_t)(bh * 32 + c2) * Uu + u) * Dd + t] * w8[c2 >> 2];
    dv[t] = s / Zs - vmean[bh * Dd + t];
  }
  __syncthreads();
  for (int c = t; c < 512; c += 256) {
    float s = 0.f;
    #pragma unroll
    for (int d = 0; d < 64; ++d)
      s = fmaf(dv[d], Wo[(size_t)(h * 64 + d) * 512 + c], s);
    dout[(size_t)bhu * 512 + c] = s;
  }
}

// ---------- base[b][c] = vmean_b @ Wo + bo ----------
__global__ __launch_bounds__(256) void base_kernel(
    const float* __restrict__ vmean, const float* __restrict__ Wo,
    const float* __restrict__ bo, float* __restrict__ base)
{
  int b = blockIdx.x, t = threadIdx.x;
  __shared__ float vm[512];
  vm[t] = vmean[b * 512 + t];
  vm[t + 256] = vmean[b * 512 + t + 256];
  __syncthreads();
  for (int c = t; c < 512; c += 256) {
    float s = bo[c];
    for (int k2 = 0; k2 < 512; ++k2)
      s = fmaf(vm[k2], Wo[(size_t)k2 * 512 + c], s);
    base[b * 512 + c] = s;
  }
}

// ---------- assemble out rows ----------
__global__ __launch_bounds__(256) void assemble_kernel(
    const float* __restrict__ base, const int* __restrict__ map,
    const float* __restrict__ dout, float* __restrict__ out)
{
  int t = threadIdx.x;
  int row = blockIdx.x * 4 + (t >> 6);
  int lane = t & 63;
  int b = row >> 11, n = row & 2047;
  float4 a0 = *(const float4*)(base + b * 512 + lane * 4);
  float4 a1 = *(const float4*)(base + b * 512 + 256 + lane * 4);
  for (int h = 0; h < 8; ++h) {
    int mi = map[(b * Hh + h) * Nn + n];
    if (mi >= 0) {
      const float* dp = dout + (size_t)mi * 512;
      float4 d0 = *(const float4*)(dp + lane * 4);
      float4 d1 = *(const float4*)(dp + 256 + lane * 4);
      a0.x += d0.x; a0.y += d0.y; a0.z += d0.z; a0.w += d0.w;
      a1.x += d1.x; a1.y += d1.y; a1.z += d1.z; a1.w += d1.w;
    }
  }
  *(float4*)(out + (size_t)row * 512 + lane * 4) = a0;
  *(float4*)(out + (size_t)row * 512 + 256 + lane * 4) = a1;
}

} // namespace

extern "C" void kernel_launch(void* const* d_in, const int* in_sizes, int n_in,
                              void* d_out, int out_size, void* d_ws, size_t ws_size,
                              hipStream_t stream) {
  const float* x  = (const float*)d_in[0];
  const float* Wq = (const float*)d_in[1];
  const float* bq = (const float*)d_in[2];
  const float* Wk = (const float*)d_in[3];
  const float* bk = (const float*)d_in[4];
  const float* Wv = (const float*)d_in[5];
  const float* bv = (const float*)d_in[6];
  const float* Wo = (const float*)d_in[7];
  const float* bo = (const float*)d_in[8];
  const int* idx  = (const int*)d_in[9];
  float* out = (float*)d_out;

  float* ws = (float*)d_ws;
  float* q      = ws;                       // 4,194,304 f
  float* kbuf   = ws + 4194304;
  float* vbuf   = ws + 8388608;
  float* Mbuf   = ws + 12582912;            // 65,536 f [32][2048]
  float* vmean  = ws + 12648448;            // 2,048 f
  float* pm     = ws + 12650496;            // 10,240 f [32][8][40]
  float* ps     = ws + 12660736;            // 10,240 f
  float* dout   = ws + 12670976;            // 655,360 f [1280][512]
  float* base   = ws + 13326336;            // 2,048 f
  int*   M_top  = (int*)(ws + 13328384);    // 1,280
  int*   map    = (int*)(ws + 13329664);    // 65,536
  unsigned short* xh  = (unsigned short*)(ws + 13395200); // 4,194,304 bf16
  unsigned short* xl  = (unsigned short*)(ws + 15492352);
  unsigned short* WTh = (unsigned short*)(ws + 17589504); // 786,432 bf16
  unsigned short* WTl = (unsigned short*)(ws + 17982720); // ends 18,375,936 f
  float* partial = ws + 13395200;           // overlays xh/xl after gemm (2,621,440 f)

  convert_all<<<4096 + 1536, 256, 0, stream>>>(x, Wq, Wk, Wv, xh, xl, WTh, WTl);

  gemm_qkv<<<dim3(64, 12), 256, 0, stream>>>(xh, xl, WTh, WTl, bq, bk, bv, q, kbuf, vbuf);

  sampled_qk_kernel<<<512, 256, 0, stream>>>(q, kbuf, idx, Mbuf);
  topk_kernel<<<BH, 64, 0, stream>>>(Mbuf, M_top);
  vmean_kernel<<<BH, 256, 0, stream>>>(vbuf, vmean);

  fused_attn_kernel<<<dim3(8, BH), 256, 0, stream>>>(q, kbuf, vbuf, M_top, pm, ps, partial);

  hipMemsetAsync(map, 0xFF, BH * Nn * sizeof(int), stream);
  attn_reduce_kernel<<<BH * Uu, 256, 0, stream>>>(pm, ps, partial, vmean, Wo, M_top, dout, map);

  base_kernel<<<Bb, 256, 0, stream>>>(vmean, Wo, bo, base);
  assemble_kernel<<<M_ROWS / 4, 256, 0, stream>>>(base, map, dout, out);
}

// Round 5
// 299.440 us; speedup vs baseline: 1.9272x; 1.0007x over previous
//
#include <hip/hip_runtime.h>
#include <math.h>

namespace {

constexpr int Bb = 4, Nn = 2048, Cc = 512, Hh = 8, Dd = 64, Ss = 40, Uu = 40;
constexpr int M_ROWS = Bb * Nn; // 8192
constexpr int BH = Bb * Hh;     // 32

typedef __attribute__((ext_vector_type(8))) short short8;
typedef __attribute__((ext_vector_type(4))) float f32x4;

__device__ inline unsigned short f2bf(float f) {
  union { float f; unsigned u; } v; v.f = f;
  unsigned r = (v.u + 0x7fffu + ((v.u >> 16) & 1u)) >> 16;
  return (unsigned short)r;
}
__device__ inline float bf2f(unsigned short h) {
  union { unsigned u; float f; } v; v.u = ((unsigned)h) << 16;
  return v.f;
}

// ---------- split x into bf16 hi/lo AND build transposed split weights ----------
__global__ __launch_bounds__(256) void convert_all(
    const float* __restrict__ x, const float* __restrict__ Wq,
    const float* __restrict__ Wk, const float* __restrict__ Wv,
    unsigned short* __restrict__ xh, unsigned short* __restrict__ xl,
    unsigned short* __restrict__ WTh, unsigned short* __restrict__ WTl)
{
  if (blockIdx.x < 4096) {
    size_t i = ((size_t)blockIdx.x * 256 + threadIdx.x) * 4;
    float4 v = *(const float4*)(x + i);
    ushort4 h, l;
    h.x = f2bf(v.x); l.x = f2bf(v.x - bf2f(h.x));
    h.y = f2bf(v.y); l.y = f2bf(v.y - bf2f(h.y));
    h.z = f2bf(v.z); l.z = f2bf(v.z - bf2f(h.z));
    h.w = f2bf(v.w); l.w = f2bf(v.w - bf2f(h.w));
    *(ushort4*)(xh + i) = h;
    *(ushort4*)(xl + i) = l;
  } else {
    int nrow = blockIdx.x - 4096;
    int which = nrow >> 9, col = nrow & 511;
    const float* Wsrc = which == 0 ? Wq : (which == 1 ? Wk : Wv);
    for (int kk = threadIdx.x; kk < 512; kk += 256) {
      float v = Wsrc[(size_t)kk * 512 + col];
      unsigned short h = f2bf(v);
      WTh[(size_t)nrow * 512 + kk] = h;
      WTl[(size_t)nrow * 512 + kk] = f2bf(v - bf2f(h));
    }
  }
}

// ---------- bf16 split-precision MFMA GEMM: QKV projection ----------
__global__ __launch_bounds__(256) void gemm_qkv(
    const unsigned short* __restrict__ xh, const unsigned short* __restrict__ xl,
    const unsigned short* __restrict__ WTh, const unsigned short* __restrict__ WTl,
    const float* __restrict__ bq, const float* __restrict__ bk, const float* __restrict__ bv,
    float* __restrict__ qf, float* __restrict__ kf, float* __restrict__ vf)
{
  __shared__ __align__(16) unsigned short Ah[128 * 32];
  __shared__ __align__(16) unsigned short Al[128 * 32];
  __shared__ __align__(16) unsigned short Bh[128 * 32];
  __shared__ __align__(16) unsigned short Bl[128 * 32];
  int tid = threadIdx.x;
  int lane = tid & 63, w = tid >> 6;
  int bm = blockIdx.x * 128, bn = blockIdx.y * 128;

  f32x4 acc[4][4];
  #pragma unroll
  for (int i = 0; i < 4; ++i)
    #pragma unroll
    for (int j = 0; j < 4; ++j)
      #pragma unroll
      for (int r = 0; r < 4; ++r) acc[i][j][r] = 0.f;

  int wm = (w >> 1) * 64, wn = (w & 1) * 64;
  int lm = lane & 15, lg = lane >> 4;

  int srow = (lane >> 2);
  int cs = (lane & 3) ^ (srow & 3);   // pre-swizzled source chunk

  for (int kt = 0; kt < 16; ++kt) {
    int k0 = kt * 32;
    #pragma unroll
    for (int call = 0; call < 2; ++call) {
      int row = w * 16 + srow + call * 64;
      size_t offA = (size_t)(bm + row) * 512 + k0 + cs * 8;
      size_t offB = (size_t)(bn + row) * 512 + k0 + cs * 8;
      unsigned dst = call * 4096 + w * 1024;
      __builtin_amdgcn_global_load_lds(
          (const __attribute__((address_space(1))) void*)(xh + offA),
          (__attribute__((address_space(3))) void*)((char*)Ah + dst), 16, 0, 0);
      __builtin_amdgcn_global_load_lds(
          (const __attribute__((address_space(1))) void*)(xl + offA),
          (__attribute__((address_space(3))) void*)((char*)Al + dst), 16, 0, 0);
      __builtin_amdgcn_global_load_lds(
          (const __attribute__((address_space(1))) void*)(WTh + offB),
          (__attribute__((address_space(3))) void*)((char*)Bh + dst), 16, 0, 0);
      __builtin_amdgcn_global_load_lds(
          (const __attribute__((address_space(1))) void*)(WTl + offB),
          (__attribute__((address_space(3))) void*)((char*)Bl + dst), 16, 0, 0);
    }
    __syncthreads();

    short8 afh[4], bgh[4], afl[4], bgl[4];
    #pragma unroll
    for (int i = 0; i < 4; ++i) {
      int R = wm + i * 16 + lm;
      afh[i] = *(const short8*)(Ah + R * 32 + ((lg ^ (R & 3)) * 8));
    }
    #pragma unroll
    for (int j = 0; j < 4; ++j) {
      int R = wn + j * 16 + lm;
      bgh[j] = *(const short8*)(Bh + R * 32 + ((lg ^ (R & 3)) * 8));
    }
    #pragma unroll
    for (int i = 0; i < 4; ++i)
      #pragma unroll
      for (int j = 0; j < 4; ++j)
        acc[i][j] = __builtin_amdgcn_mfma_f32_16x16x32_bf16(afh[i], bgh[j], acc[i][j], 0, 0, 0);

    #pragma unroll
    for (int i = 0; i < 4; ++i) {
      int R = wm + i * 16 + lm;
      afl[i] = *(const short8*)(Al + R * 32 + ((lg ^ (R & 3)) * 8));
    }
    #pragma unroll
    for (int i = 0; i < 4; ++i)
      #pragma unroll
      for (int j = 0; j < 4; ++j)
        acc[i][j] = __builtin_amdgcn_mfma_f32_16x16x32_bf16(afl[i], bgh[j], acc[i][j], 0, 0, 0);

    #pragma unroll
    for (int j = 0; j < 4; ++j) {
      int R = wn + j * 16 + lm;
      bgl[j] = *(const short8*)(Bl + R * 32 + ((lg ^ (R & 3)) * 8));
    }
    #pragma unroll
    for (int i = 0; i < 4; ++i)
      #pragma unroll
      for (int j = 0; j < 4; ++j)
        acc[i][j] = __builtin_amdgcn_mfma_f32_16x16x32_bf16(afh[i], bgl[j], acc[i][j], 0, 0, 0);

    __syncthreads();
  }

  #pragma unroll
  for (int j = 0; j < 4; ++j) {
    int n = bn + wn + j * 16 + lm;
    float bias = n < 512 ? bq[n] : (n < 1024 ? bk[n - 512] : bv[n - 1024]);
    int tensor = n >> 9, h = (n >> 6) & 7, d = n & 63;
    float* op = tensor == 0 ? qf : (tensor == 1 ? kf : vf);
    #pragma unroll
    for (int i = 0; i < 4; ++i) {
      #pragma unroll
      for (int r = 0; r < 4; ++r) {
        int m = bm + wm + i * 16 + lg * 4 + r;
        int b = m >> 11, nn = m & 2047;
        op[((size_t)(b * Hh + h) * Nn + nn) * Dd + d] = acc[i][j][r] + bias;
      }
    }
  }
}

// ---------- sampled QK^T -> M, bh-pinned to XCDs for L2 locality ----------
__global__ __launch_bounds__(256) void sampled_qk_kernel(
    const float* __restrict__ q, const float* __restrict__ k,
    const int* __restrict__ idx, float* __restrict__ Mout)
{
  int p = blockIdx.x;
  int xcd = p & 7, j = p >> 3;
  int chunk = j & 15;
  int bh = (j >> 4) * 8 + xcd;
  int t = threadIdx.x;
  int w = t >> 6, lane = t & 63;
  int g = lane >> 2, dq = lane & 3;

  const float* kb = k + (size_t)bh * Nn * Dd;

  for (int li = 0; li < 32; ++li) {
    int l = chunk * 128 + w * 32 + li;
    const float* qrow = q + ((size_t)bh * Nn + l) * Dd + dq * 4;
    float4 qv[4];
    #pragma unroll
    for (int i = 0; i < 4; ++i) qv[i] = *(const float4*)(qrow + i * 16);
    float mx = -INFINITY, sm = 0.f;
    #pragma unroll
    for (int pass = 0; pass < 3; ++pass) {
      int s = pass * 16 + g;
      bool valid = (s < Ss);
      float dot = 0.f;
      if (valid) {
        int kr = idx[l * Ss + s];
        const float* krow = kb + (size_t)kr * Dd + dq * 4;
        #pragma unroll
        for (int i = 0; i < 4; ++i) {
          float4 kv = *(const float4*)(krow + i * 16);
          dot += kv.x * qv[i].x + kv.y * qv[i].y + kv.z * qv[i].z + kv.w * qv[i].w;
        }
      }
      dot += __shfl_xor(dot, 1);
      dot += __shfl_xor(dot, 2);
      if (valid) { mx = fmaxf(mx, dot); sm += dot; }
    }
    #pragma unroll
    for (int o = 4; o < 64; o <<= 1) {
      mx = fmaxf(mx, __shfl_xor(mx, o));
      sm += __shfl_xor(sm, o);
    }
    if (lane == 0) Mout[(size_t)bh * Nn + l] = mx - sm * (1.f / (float)Nn);
  }
}

// ---------- top-40 per (b,h): single wave, register-resident ----------
__global__ __launch_bounds__(64) void topk_kernel(
    const float* __restrict__ Min, int* __restrict__ M_top)
{
  int bh = blockIdx.x, lane = threadIdx.x;
  const float* row = Min + (size_t)bh * Nn;
  float v[32];
  #pragma unroll
  for (int j = 0; j < 32; ++j) v[j] = row[j * 64 + lane];
  unsigned mask = 0;
  for (int it = 0; it < Uu; ++it) {
    float best = -INFINITY; int bidx = 0x7FFFFFFF;
    #pragma unroll
    for (int j = 0; j < 32; ++j) {
      if (!((mask >> j) & 1u) && v[j] > best) { best = v[j]; bidx = j * 64 + lane; }
    }
    #pragma unroll
    for (int o = 32; o; o >>= 1) {
      float ov = __shfl_xor(best, o);
      int oi = __shfl_xor(bidx, o);
      if (ov > best || (ov == best && oi < bidx)) { best = ov; bidx = oi; }
    }
    if ((bidx & 63) == lane) mask |= 1u << (bidx >> 6);
    if (lane == 0) M_top[bh * Uu + it] = bidx;
  }
}

// ---------- mean of V over N per (b,h,d) ----------
__global__ __launch_bounds__(256) void vmean_kernel(
    const float* __restrict__ v, float* __restrict__ vmean)
{
  int bh = blockIdx.x, t = threadIdx.x;
  int d = t & 63, chunk = t >> 6;
  const float* base = v + (size_t)bh * Nn * Dd;
  float s = 0.f;
  for (int n = chunk * 512; n < (chunk + 1) * 512; ++n) s += base[(size_t)n * Dd + d];
  __shared__ float part[4][64];
  part[chunk][d] = s;
  __syncthreads();
  if (t < 64)
    vmean[bh * Dd + t] = (part[0][t] + part[1][t] + part[2][t] + part[3][t]) * (1.f / (float)Nn);
}

// ---------- fused scores+softmax+PV partials, per (n-chunk, bh) ----------
// partial layout: [bhu][32][64] so the combine kernel reads 8KB contiguous.
__global__ __launch_bounds__(256) void fused_attn_kernel(
    const float* __restrict__ q, const float* __restrict__ k, const float* __restrict__ v,
    const int* __restrict__ M_top, float* __restrict__ pm, float* __restrict__ ps,
    float* __restrict__ partial)
{
  int chunk = blockIdx.x, bh = blockIdx.y, t = threadIdx.x;
  __shared__ float qs[40][64];
  __shared__ float S[40][256];
  if (t < 160) {
    int u = t >> 2, p = (t & 3) * 16;
    int r = M_top[bh * Uu + u];
    const float4* src = (const float4*)(q + ((size_t)bh * Nn + r) * Dd + p);
    *(float4*)&qs[u][p + 0]  = src[0];
    *(float4*)&qs[u][p + 4]  = src[1];
    *(float4*)&qs[u][p + 8]  = src[2];
    *(float4*)&qs[u][p + 12] = src[3];
  }
  __syncthreads();

  {
    int n = chunk * 256 + t;
    const float4* krow = (const float4*)(k + ((size_t)bh * Nn + n) * Dd);
    float acc[40];
    #pragma unroll
    for (int u = 0; u < 40; ++u) acc[u] = 0.f;
    #pragma unroll
    for (int d4 = 0; d4 < 16; ++d4) {
      float4 kv = krow[d4];
      #pragma unroll
      for (int u = 0; u < 40; ++u) {
        float4 qv = *(const float4*)&qs[u][d4 * 4];
        acc[u] += qv.x * kv.x + qv.y * kv.y + qv.z * kv.z + qv.w * kv.w;
      }
    }
    #pragma unroll
    for (int u = 0; u < 40; ++u) S[u][t] = acc[u] * 0.125f;
  }
  __syncthreads();

  int w = t >> 6, lane = t & 63;
  #pragma unroll
  for (int r = 0; r < 10; ++r) {
    int u = w * 10 + r;
    float v0 = S[u][lane], v1 = S[u][lane + 64], v2 = S[u][lane + 128], v3 = S[u][lane + 192];
    float m = fmaxf(fmaxf(v0, v1), fmaxf(v2, v3));
    #pragma unroll
    for (int o = 1; o < 64; o <<= 1) m = fmaxf(m, __shfl_xor(m, o));
    float e0 = expf(v0 - m), e1 = expf(v1 - m), e2 = expf(v2 - m), e3 = expf(v3 - m);
    S[u][lane] = e0; S[u][lane + 64] = e1; S[u][lane + 128] = e2; S[u][lane + 192] = e3;
    float sum = e0 + e1 + e2 + e3;
    #pragma unroll
    for (int o = 1; o < 64; o <<= 1) sum += __shfl_xor(sum, o);
    if (lane == 0) {
      pm[(bh * 8 + chunk) * Uu + u] = m;
      ps[(bh * 8 + chunk) * Uu + u] = sum;
    }
  }
  __syncthreads();

  // PV: wave w handles n in [w*64, w*64+64), lane = d
  float acc2[40];
  #pragma unroll
  for (int u = 0; u < 40; ++u) acc2[u] = 0.f;
  const float* vb = v + ((size_t)bh * Nn + chunk * 256 + w * 64) * Dd + lane;
  for (int i = 0; i < 64; ++i) {
    float vv = vb[(size_t)i * Dd];
    #pragma unroll
    for (int u = 0; u < 40; ++u) acc2[u] = fmaf(S[u][w * 64 + i], vv, acc2[u]);
  }
  // partial[bhu][chunk*4+w][lane]
  float* pp = partial + ((size_t)bh * Uu * 32 + chunk * 4 + w) * Dd + lane;
  #pragma unroll
  for (int u = 0; u < 40; ++u) pp[(size_t)u * 2048] = acc2[u];
}

// ---------- combine partials -> dv, dout = (upd - vmean) @ Wo_h, map ----------
// All-wave-parallel: wave 0 computes w8/Z via shfl over 8 lanes; each wave
// sums 8 contiguous chunks of partial; fused dout GEMM at the end.
__global__ __launch_bounds__(256) void attn_combine_kernel(
    const float* __restrict__ pm, const float* __restrict__ ps,
    const float* __restrict__ partial, const float* __restrict__ vmean,
    const float* __restrict__ Wo, const int* __restrict__ M_top,
    float* __restrict__ dout, int* __restrict__ map)
{
  int bhu = blockIdx.x;
  int bh = bhu / Uu, u = bhu % Uu, h = bh & 7;
  int t = threadIdx.x, lane = t & 63, w = t >> 6;
  __shared__ float w8[8];
  __shared__ float dv[64];
  __shared__ float pacc[4][64];
  __shared__ float Zsh;

  if (w == 0) {
    float pmv = (lane < 8) ? pm[(bh * 8 + lane) * Uu + u] : -INFINITY;
    float psv = (lane < 8) ? ps[(bh * 8 + lane) * Uu + u] : 0.f;
    float m = pmv;
    #pragma unroll
    for (int o = 1; o < 8; o <<= 1) m = fmaxf(m, __shfl_xor(m, o));
    float e = (lane < 8) ? expf(pmv - m) : 0.f;
    float z = e * psv;
    #pragma unroll
    for (int o = 1; o < 8; o <<= 1) z += __shfl_xor(z, o);
    if (lane < 8) w8[lane] = e;
    if (lane == 0) {
      Zsh = z;
      map[bh * Nn + M_top[bhu]] = bhu;
    }
  }
  __syncthreads();

  const float* pb = partial + (size_t)bhu * 2048;
  float s = 0.f;
  #pragma unroll
  for (int c = 0; c < 8; ++c) {
    int cw = w * 8 + c;
    s = fmaf(pb[cw * 64 + lane], w8[cw >> 2], s);
  }
  pacc[w][lane] = s;
  __syncthreads();
  if (t < 64)
    dv[t] = (pacc[0][t] + pacc[1][t] + pacc[2][t] + pacc[3][t]) / Zsh - vmean[bh * Dd + t];
  __syncthreads();

  for (int c = t; c < 512; c += 256) {
    float s2 = 0.f;
    #pragma unroll
    for (int d = 0; d < 64; ++d)
      s2 = fmaf(dv[d], Wo[(size_t)(h * 64 + d) * 512 + c], s2);
    dout[(size_t)bhu * 512 + c] = s2;
  }
}

// ---------- base[b][c] = vmean_b @ Wo + bo ----------
__global__ __launch_bounds__(256) void base_kernel(
    const float* __restrict__ vmean, const float* __restrict__ Wo,
    const float* __restrict__ bo, float* __restrict__ base)
{
  int b = blockIdx.x, t = threadIdx.x;
  __shared__ float vm[512];
  vm[t] = vmean[b * 512 + t];
  vm[t + 256] = vmean[b * 512 + t + 256];
  __syncthreads();
  for (int c = t; c < 512; c += 256) {
    float s = bo[c];
    for (int k2 = 0; k2 < 512; ++k2)
      s = fmaf(vm[k2], Wo[(size_t)k2 * 512 + c], s);
    base[b * 512 + c] = s;
  }
}

// ---------- assemble out rows ----------
__global__ __launch_bounds__(256) void assemble_kernel(
    const float* __restrict__ base, const int* __restrict__ map,
    const float* __restrict__ dout, float* __restrict__ out)
{
  int t = threadIdx.x;
  int row = blockIdx.x * 4 + (t >> 6);
  int lane = t & 63;
  int b = row >> 11, n = row & 2047;
  float4 a0 = *(const float4*)(base + b * 512 + lane * 4);
  float4 a1 = *(const float4*)(base + b * 512 + 256 + lane * 4);
  for (int h = 0; h < 8; ++h) {
    int mi = map[(b * Hh + h) * Nn + n];
    if (mi >= 0) {
      const float* dp = dout + (size_t)mi * 512;
      float4 d0 = *(const float4*)(dp + lane * 4);
      float4 d1 = *(const float4*)(dp + 256 + lane * 4);
      a0.x += d0.x; a0.y += d0.y; a0.z += d0.z; a0.w += d0.w;
      a1.x += d1.x; a1.y += d1.y; a1.z += d1.z; a1.w += d1.w;
    }
  }
  *(float4*)(out + (size_t)row * 512 + lane * 4) = a0;
  *(float4*)(out + (size_t)row * 512 + 256 + lane * 4) = a1;
}

} // namespace

extern "C" void kernel_launch(void* const* d_in, const int* in_sizes, int n_in,
                              void* d_out, int out_size, void* d_ws, size_t ws_size,
                              hipStream_t stream) {
  const float* x  = (const float*)d_in[0];
  const float* Wq = (const float*)d_in[1];
  const float* bq = (const float*)d_in[2];
  const float* Wk = (const float*)d_in[3];
  const float* bk = (const float*)d_in[4];
  const float* Wv = (const float*)d_in[5];
  const float* bv = (const float*)d_in[6];
  const float* Wo = (const float*)d_in[7];
  const float* bo = (const float*)d_in[8];
  const int* idx  = (const int*)d_in[9];
  float* out = (float*)d_out;

  float* ws = (float*)d_ws;
  float* q      = ws;                       // 4,194,304 f
  float* kbuf   = ws + 4194304;
  float* vbuf   = ws + 8388608;
  float* Mbuf   = ws + 12582912;            // 65,536 f [32][2048]
  float* vmean  = ws + 12648448;            // 2,048 f
  float* pm     = ws + 12650496;            // 10,240 f [32][8][40]
  float* ps     = ws + 12660736;            // 10,240 f
  float* dout   = ws + 12670976;            // 655,360 f [1280][512]
  float* base   = ws + 13326336;            // 2,048 f
  int*   M_top  = (int*)(ws + 13328384);    // 1,280
  int*   map    = (int*)(ws + 13329664);    // 65,536
  unsigned short* xh  = (unsigned short*)(ws + 13395200); // 4,194,304 bf16
  unsigned short* xl  = (unsigned short*)(ws + 15492352);
  unsigned short* WTh = (unsigned short*)(ws + 17589504); // 786,432 bf16
  unsigned short* WTl = (unsigned short*)(ws + 17982720); // ends 18,375,936 f
  float* partial = ws + 13395200;           // overlays xh/xl after gemm (2,621,440 f)

  convert_all<<<4096 + 1536, 256, 0, stream>>>(x, Wq, Wk, Wv, xh, xl, WTh, WTl);

  gemm_qkv<<<dim3(64, 12), 256, 0, stream>>>(xh, xl, WTh, WTl, bq, bk, bv, q, kbuf, vbuf);

  sampled_qk_kernel<<<512, 256, 0, stream>>>(q, kbuf, idx, Mbuf);
  topk_kernel<<<BH, 64, 0, stream>>>(Mbuf, M_top);
  vmean_kernel<<<BH, 256, 0, stream>>>(vbuf, vmean);

  fused_attn_kernel<<<dim3(8, BH), 256, 0, stream>>>(q, kbuf, vbuf, M_top, pm, ps, partial);

  hipMemsetAsync(map, 0xFF, BH * Nn * sizeof(int), stream);
  attn_combine_kernel<<<BH * Uu, 256, 0, stream>>>(pm, ps, partial, vmean, Wo, M_top, dout, map);

  base_kernel<<<Bb, 256, 0, stream>>>(vmean, Wo, bo, base);
  assemble_kernel<<<M_ROWS / 4, 256, 0, stream>>>(base, map, dout, out);
}

// Round 6
// 282.282 us; speedup vs baseline: 2.0444x; 1.0608x over previous
//
#include <hip/hip_runtime.h>
#include <math.h>

namespace {

constexpr int Bb = 4, Nn = 2048, Cc = 512, Hh = 8, Dd = 64, Ss = 40, Uu = 40;
constexpr int M_ROWS = Bb * Nn; // 8192
constexpr int BH = Bb * Hh;     // 32

typedef __attribute__((ext_vector_type(8))) short short8;
typedef __attribute__((ext_vector_type(4))) float f32x4;

__device__ inline unsigned short f2bf(float f) {
  union { float f; unsigned u; } v; v.f = f;
  unsigned r = (v.u + 0x7fffu + ((v.u >> 16) & 1u)) >> 16;
  return (unsigned short)r;
}
__device__ inline float bf2f(unsigned short h) {
  union { unsigned u; float f; } v; v.u = ((unsigned)h) << 16;
  return v.f;
}

// ---------- split x into bf16 hi/lo AND build transposed split weights ----------
// W rows 0..511: Wq^T, 512..1023: Wk^T, 1024..1535: Wv^T, 1536..2047: Wo^T
__global__ __launch_bounds__(256) void convert_all(
    const float* __restrict__ x, const float* __restrict__ Wq,
    const float* __restrict__ Wk, const float* __restrict__ Wv,
    const float* __restrict__ Wo,
    unsigned short* __restrict__ xh, unsigned short* __restrict__ xl,
    unsigned short* __restrict__ WTh, unsigned short* __restrict__ WTl)
{
  if (blockIdx.x < 4096) {
    size_t i = ((size_t)blockIdx.x * 256 + threadIdx.x) * 4;
    float4 v = *(const float4*)(x + i);
    ushort4 h, l;
    h.x = f2bf(v.x); l.x = f2bf(v.x - bf2f(h.x));
    h.y = f2bf(v.y); l.y = f2bf(v.y - bf2f(h.y));
    h.z = f2bf(v.z); l.z = f2bf(v.z - bf2f(h.z));
    h.w = f2bf(v.w); l.w = f2bf(v.w - bf2f(h.w));
    *(ushort4*)(xh + i) = h;
    *(ushort4*)(xl + i) = l;
  } else {
    int nrow = blockIdx.x - 4096;
    int which = nrow >> 9, col = nrow & 511;
    const float* Wsrc = which == 0 ? Wq : (which == 1 ? Wk : (which == 2 ? Wv : Wo));
    for (int kk = threadIdx.x; kk < 512; kk += 256) {
      float v = Wsrc[(size_t)kk * 512 + col];
      unsigned short h = f2bf(v);
      WTh[(size_t)nrow * 512 + kk] = h;
      WTl[(size_t)nrow * 512 + kk] = f2bf(v - bf2f(h));
    }
  }
}

// ---------- bf16 split-precision MFMA GEMM ----------
// MODE 0: QKV projection, grid (64,12), head-split fp32 outputs + bias
// MODE 1: plain C[M][512] = A @ B (no bias), grid (M/128, 4)
template<int MODE>
__global__ __launch_bounds__(256) void gemm_split(
    const unsigned short* __restrict__ xh, const unsigned short* __restrict__ xl,
    const unsigned short* __restrict__ WThp, const unsigned short* __restrict__ WTlp,
    const float* __restrict__ bq, const float* __restrict__ bk, const float* __restrict__ bv,
    float* __restrict__ o0, float* __restrict__ o1, float* __restrict__ o2)
{
  __shared__ __align__(16) unsigned short Ah[128 * 32];
  __shared__ __align__(16) unsigned short Al[128 * 32];
  __shared__ __align__(16) unsigned short Bh[128 * 32];
  __shared__ __align__(16) unsigned short Bl[128 * 32];
  int tid = threadIdx.x;
  int lane = tid & 63, w = tid >> 6;
  int bm = blockIdx.x * 128, bn = blockIdx.y * 128;

  f32x4 acc[4][4];
  #pragma unroll
  for (int i = 0; i < 4; ++i)
    #pragma unroll
    for (int j = 0; j < 4; ++j)
      #pragma unroll
      for (int r = 0; r < 4; ++r) acc[i][j][r] = 0.f;

  int wm = (w >> 1) * 64, wn = (w & 1) * 64;
  int lm = lane & 15, lg = lane >> 4;

  int srow = (lane >> 2);
  int cs = (lane & 3) ^ (srow & 3);   // pre-swizzled source chunk

  for (int kt = 0; kt < 16; ++kt) {
    int k0 = kt * 32;
    #pragma unroll
    for (int call = 0; call < 2; ++call) {
      int row = w * 16 + srow + call * 64;
      size_t offA = (size_t)(bm + row) * 512 + k0 + cs * 8;
      size_t offB = (size_t)(bn + row) * 512 + k0 + cs * 8;
      unsigned dst = call * 4096 + w * 1024;
      __builtin_amdgcn_global_load_lds(
          (const __attribute__((address_space(1))) void*)(xh + offA),
          (__attribute__((address_space(3))) void*)((char*)Ah + dst), 16, 0, 0);
      __builtin_amdgcn_global_load_lds(
          (const __attribute__((address_space(1))) void*)(xl + offA),
          (__attribute__((address_space(3))) void*)((char*)Al + dst), 16, 0, 0);
      __builtin_amdgcn_global_load_lds(
          (const __attribute__((address_space(1))) void*)(WThp + offB),
          (__attribute__((address_space(3))) void*)((char*)Bh + dst), 16, 0, 0);
      __builtin_amdgcn_global_load_lds(
          (const __attribute__((address_space(1))) void*)(WTlp + offB),
          (__attribute__((address_space(3))) void*)((char*)Bl + dst), 16, 0, 0);
    }
    __syncthreads();

    short8 afh[4], bgh[4], afl[4], bgl[4];
    #pragma unroll
    for (int i = 0; i < 4; ++i) {
      int R = wm + i * 16 + lm;
      afh[i] = *(const short8*)(Ah + R * 32 + ((lg ^ (R & 3)) * 8));
    }
    #pragma unroll
    for (int j = 0; j < 4; ++j) {
      int R = wn + j * 16 + lm;
      bgh[j] = *(const short8*)(Bh + R * 32 + ((lg ^ (R & 3)) * 8));
    }
    #pragma unroll
    for (int i = 0; i < 4; ++i)
      #pragma unroll
      for (int j = 0; j < 4; ++j)
        acc[i][j] = __builtin_amdgcn_mfma_f32_16x16x32_bf16(afh[i], bgh[j], acc[i][j], 0, 0, 0);

    #pragma unroll
    for (int i = 0; i < 4; ++i) {
      int R = wm + i * 16 + lm;
      afl[i] = *(const short8*)(Al + R * 32 + ((lg ^ (R & 3)) * 8));
    }
    #pragma unroll
    for (int i = 0; i < 4; ++i)
      #pragma unroll
      for (int j = 0; j < 4; ++j)
        acc[i][j] = __builtin_amdgcn_mfma_f32_16x16x32_bf16(afl[i], bgh[j], acc[i][j], 0, 0, 0);

    #pragma unroll
    for (int j = 0; j < 4; ++j) {
      int R = wn + j * 16 + lm;
      bgl[j] = *(const short8*)(Bl + R * 32 + ((lg ^ (R & 3)) * 8));
    }
    #pragma unroll
    for (int i = 0; i < 4; ++i)
      #pragma unroll
      for (int j = 0; j < 4; ++j)
        acc[i][j] = __builtin_amdgcn_mfma_f32_16x16x32_bf16(afh[i], bgl[j], acc[i][j], 0, 0, 0);

    __syncthreads();
  }

  if (MODE == 0) {
    #pragma unroll
    for (int j = 0; j < 4; ++j) {
      int n = bn + wn + j * 16 + lm;
      float bias = n < 512 ? bq[n] : (n < 1024 ? bk[n - 512] : bv[n - 1024]);
      int tensor = n >> 9, h = (n >> 6) & 7, d = n & 63;
      float* op = tensor == 0 ? o0 : (tensor == 1 ? o1 : o2);
      #pragma unroll
      for (int i = 0; i < 4; ++i) {
        #pragma unroll
        for (int r = 0; r < 4; ++r) {
          int m = bm + wm + i * 16 + lg * 4 + r;
          int b = m >> 11, nn = m & 2047;
          op[((size_t)(b * Hh + h) * Nn + nn) * Dd + d] = acc[i][j][r] + bias;
        }
      }
    }
  } else {
    #pragma unroll
    for (int j = 0; j < 4; ++j) {
      int n = bn + wn + j * 16 + lm;
      #pragma unroll
      for (int i = 0; i < 4; ++i) {
        #pragma unroll
        for (int r = 0; r < 4; ++r) {
          int m = bm + wm + i * 16 + lg * 4 + r;
          o0[(size_t)m * 512 + n] = acc[i][j][r];
        }
      }
    }
  }
}

// ---------- sampled QK^T -> M, bh-pinned to XCDs for L2 locality ----------
__global__ __launch_bounds__(256) void sampled_qk_kernel(
    const float* __restrict__ q, const float* __restrict__ k,
    const int* __restrict__ idx, float* __restrict__ Mout)
{
  int p = blockIdx.x;
  int xcd = p & 7, j = p >> 3;
  int chunk = j & 15;
  int bh = (j >> 4) * 8 + xcd;
  int t = threadIdx.x;
  int w = t >> 6, lane = t & 63;
  int g = lane >> 2, dq = lane & 3;

  const float* kb = k + (size_t)bh * Nn * Dd;

  for (int li = 0; li < 32; ++li) {
    int l = chunk * 128 + w * 32 + li;
    const float* qrow = q + ((size_t)bh * Nn + l) * Dd + dq * 4;
    float4 qv[4];
    #pragma unroll
    for (int i = 0; i < 4; ++i) qv[i] = *(const float4*)(qrow + i * 16);
    float mx = -INFINITY, sm = 0.f;
    #pragma unroll
    for (int pass = 0; pass < 3; ++pass) {
      int s = pass * 16 + g;
      bool valid = (s < Ss);
      float dot = 0.f;
      if (valid) {
        int kr = idx[l * Ss + s];
        const float* krow = kb + (size_t)kr * Dd + dq * 4;
        #pragma unroll
        for (int i = 0; i < 4; ++i) {
          float4 kv = *(const float4*)(krow + i * 16);
          dot += kv.x * qv[i].x + kv.y * qv[i].y + kv.z * qv[i].z + kv.w * qv[i].w;
        }
      }
      dot += __shfl_xor(dot, 1);
      dot += __shfl_xor(dot, 2);
      if (valid) { mx = fmaxf(mx, dot); sm += dot; }
    }
    #pragma unroll
    for (int o = 4; o < 64; o <<= 1) {
      mx = fmaxf(mx, __shfl_xor(mx, o));
      sm += __shfl_xor(sm, o);
    }
    if (lane == 0) Mout[(size_t)bh * Nn + l] = mx - sm * (1.f / (float)Nn);
  }
}

// ---------- top-40 per (b,h): single wave, register-resident ----------
__global__ __launch_bounds__(64) void topk_kernel(
    const float* __restrict__ Min, int* __restrict__ M_top)
{
  int bh = blockIdx.x, lane = threadIdx.x;
  const float* row = Min + (size_t)bh * Nn;
  float v[32];
  #pragma unroll
  for (int j = 0; j < 32; ++j) v[j] = row[j * 64 + lane];
  unsigned mask = 0;
  for (int it = 0; it < Uu; ++it) {
    float best = -INFINITY; int bidx = 0x7FFFFFFF;
    #pragma unroll
    for (int j = 0; j < 32; ++j) {
      if (!((mask >> j) & 1u) && v[j] > best) { best = v[j]; bidx = j * 64 + lane; }
    }
    #pragma unroll
    for (int o = 32; o; o >>= 1) {
      float ov = __shfl_xor(best, o);
      int oi = __shfl_xor(bidx, o);
      if (ov > best || (ov == best && oi < bidx)) { best = ov; bidx = oi; }
    }
    if ((bidx & 63) == lane) mask |= 1u << (bidx >> 6);
    if (lane == 0) M_top[bh * Uu + it] = bidx;
  }
}

// ---------- mean of V over N per (b,h,d) ----------
__global__ __launch_bounds__(256) void vmean_kernel(
    const float* __restrict__ v, float* __restrict__ vmean)
{
  int bh = blockIdx.x, t = threadIdx.x;
  int d = t & 63, chunk = t >> 6;
  const float* base = v + (size_t)bh * Nn * Dd;
  float s = 0.f;
  for (int n = chunk * 512; n < (chunk + 1) * 512; ++n) s += base[(size_t)n * Dd + d];
  __shared__ float part[4][64];
  part[chunk][d] = s;
  __syncthreads();
  if (t < 64)
    vmean[bh * Dd + t] = (part[0][t] + part[1][t] + part[2][t] + part[3][t]) * (1.f / (float)Nn);
}

// ---------- fused scores+softmax+PV partials, per (n-chunk, bh) ----------
// partial layout: [bhu][32][64] so the combine kernel reads 8KB contiguous.
__global__ __launch_bounds__(256) void fused_attn_kernel(
    const float* __restrict__ q, const float* __restrict__ k, const float* __restrict__ v,
    const int* __restrict__ M_top, float* __restrict__ pm, float* __restrict__ ps,
    float* __restrict__ partial)
{
  int chunk = blockIdx.x, bh = blockIdx.y, t = threadIdx.x;
  __shared__ float qs[40][64];
  __shared__ float S[40][256];
  if (t < 160) {
    int u = t >> 2, p = (t & 3) * 16;
    int r = M_top[bh * Uu + u];
    const float4* src = (const float4*)(q + ((size_t)bh * Nn + r) * Dd + p);
    *(float4*)&qs[u][p + 0]  = src[0];
    *(float4*)&qs[u][p + 4]  = src[1];
    *(float4*)&qs[u][p + 8]  = src[2];
    *(float4*)&qs[u][p + 12] = src[3];
  }
  __syncthreads();

  {
    int n = chunk * 256 + t;
    const float4* krow = (const float4*)(k + ((size_t)bh * Nn + n) * Dd);
    float acc[40];
    #pragma unroll
    for (int u = 0; u < 40; ++u) acc[u] = 0.f;
    #pragma unroll
    for (int d4 = 0; d4 < 16; ++d4) {
      float4 kv = krow[d4];
      #pragma unroll
      for (int u = 0; u < 40; ++u) {
        float4 qv = *(const float4*)&qs[u][d4 * 4];
        acc[u] += qv.x * kv.x + qv.y * kv.y + qv.z * kv.z + qv.w * kv.w;
      }
    }
    #pragma unroll
    for (int u = 0; u < 40; ++u) S[u][t] = acc[u] * 0.125f;
  }
  __syncthreads();

  int w = t >> 6, lane = t & 63;
  #pragma unroll
  for (int r = 0; r < 10; ++r) {
    int u = w * 10 + r;
    float v0 = S[u][lane], v1 = S[u][lane + 64], v2 = S[u][lane + 128], v3 = S[u][lane + 192];
    float m = fmaxf(fmaxf(v0, v1), fmaxf(v2, v3));
    #pragma unroll
    for (int o = 1; o < 64; o <<= 1) m = fmaxf(m, __shfl_xor(m, o));
    float e0 = expf(v0 - m), e1 = expf(v1 - m), e2 = expf(v2 - m), e3 = expf(v3 - m);
    S[u][lane] = e0; S[u][lane + 64] = e1; S[u][lane + 128] = e2; S[u][lane + 192] = e3;
    float sum = e0 + e1 + e2 + e3;
    #pragma unroll
    for (int o = 1; o < 64; o <<= 1) sum += __shfl_xor(sum, o);
    if (lane == 0) {
      pm[(bh * 8 + chunk) * Uu + u] = m;
      ps[(bh * 8 + chunk) * Uu + u] = sum;
    }
  }
  __syncthreads();

  float acc2[40];
  #pragma unroll
  for (int u = 0; u < 40; ++u) acc2[u] = 0.f;
  const float* vb = v + ((size_t)bh * Nn + chunk * 256 + w * 64) * Dd + lane;
  for (int i = 0; i < 64; ++i) {
    float vv = vb[(size_t)i * Dd];
    #pragma unroll
    for (int u = 0; u < 40; ++u) acc2[u] = fmaf(S[u][w * 64 + i], vv, acc2[u]);
  }
  float* pp = partial + ((size_t)bh * Uu * 32 + chunk * 4 + w) * Dd + lane;
  #pragma unroll
  for (int u = 0; u < 40; ++u) pp[(size_t)u * 2048] = acc2[u];
}

// ---------- combine partials -> dvF (zero-padded bf16 hi/lo) + map ----------
// 1 wave per bhu. lane = d.
__global__ __launch_bounds__(64) void combine_lite(
    const float* __restrict__ pm, const float* __restrict__ ps,
    const float* __restrict__ partial, const float* __restrict__ vmean,
    const int* __restrict__ M_top,
    unsigned short* __restrict__ dvh, unsigned short* __restrict__ dvl,
    int* __restrict__ map)
{
  int bhu = blockIdx.x;
  int bh = bhu / Uu, u = bhu % Uu, h = bh & 7;
  int lane = threadIdx.x;

  // all lanes compute w8/Z redundantly from broadcast loads
  float pmv[8], psv[8];
  #pragma unroll
  for (int c = 0; c < 8; ++c) {
    pmv[c] = pm[(bh * 8 + c) * Uu + u];
    psv[c] = ps[(bh * 8 + c) * Uu + u];
  }
  float m = pmv[0];
  #pragma unroll
  for (int c = 1; c < 8; ++c) m = fmaxf(m, pmv[c]);
  float w8[8], Z = 0.f;
  #pragma unroll
  for (int c = 0; c < 8; ++c) { w8[c] = expf(pmv[c] - m); Z += w8[c] * psv[c]; }

  const float* pb = partial + (size_t)bhu * 2048;
  float s = 0.f;
  #pragma unroll
  for (int cw = 0; cw < 32; ++cw)
    s = fmaf(pb[cw * 64 + lane], w8[cw >> 2], s);

  float dv = s / Z - vmean[bh * Dd + lane];
  unsigned short hbits = f2bf(dv);
  unsigned short lbits = f2bf(dv - bf2f(hbits));

  // write zero-padded row [512]: head slot h gets dv, rest zeros
  #pragma unroll
  for (int cc = 0; cc < 8; ++cc) {
    int c = cc * 64 + lane;
    bool mine = (cc == h);
    dvh[(size_t)bhu * 512 + c] = mine ? hbits : (unsigned short)0;
    dvl[(size_t)bhu * 512 + c] = mine ? lbits : (unsigned short)0;
  }
  if (lane == 0) map[bh * Nn + M_top[bhu]] = bhu;
}

// ---------- base[b][c] = vmean_b @ Wo + bo ----------
__global__ __launch_bounds__(256) void base_kernel(
    const float* __restrict__ vmean, const float* __restrict__ Wo,
    const float* __restrict__ bo, float* __restrict__ base)
{
  int b = blockIdx.x, t = threadIdx.x;
  __shared__ float vm[512];
  vm[t] = vmean[b * 512 + t];
  vm[t + 256] = vmean[b * 512 + t + 256];
  __syncthreads();
  for (int c = t; c < 512; c += 256) {
    float s = bo[c];
    for (int k2 = 0; k2 < 512; ++k2)
      s = fmaf(vm[k2], Wo[(size_t)k2 * 512 + c], s);
    base[b * 512 + c] = s;
  }
}

// ---------- assemble out rows ----------
__global__ __launch_bounds__(256) void assemble_kernel(
    const float* __restrict__ base, const int* __restrict__ map,
    const float* __restrict__ dout, float* __restrict__ out)
{
  int t = threadIdx.x;
  int row = blockIdx.x * 4 + (t >> 6);
  int lane = t & 63;
  int b = row >> 11, n = row & 2047;
  float4 a0 = *(const float4*)(base + b * 512 + lane * 4);
  float4 a1 = *(const float4*)(base + b * 512 + 256 + lane * 4);
  for (int h = 0; h < 8; ++h) {
    int mi = map[(b * Hh + h) * Nn + n];
    if (mi >= 0) {
      const float* dp = dout + (size_t)mi * 512;
      float4 d0 = *(const float4*)(dp + lane * 4);
      float4 d1 = *(const float4*)(dp + 256 + lane * 4);
      a0.x += d0.x; a0.y += d0.y; a0.z += d0.z; a0.w += d0.w;
      a1.x += d1.x; a1.y += d1.y; a1.z += d1.z; a1.w += d1.w;
    }
  }
  *(float4*)(out + (size_t)row * 512 + lane * 4) = a0;
  *(float4*)(out + (size_t)row * 512 + 256 + lane * 4) = a1;
}

} // namespace

extern "C" void kernel_launch(void* const* d_in, const int* in_sizes, int n_in,
                              void* d_out, int out_size, void* d_ws, size_t ws_size,
                              hipStream_t stream) {
  const float* x  = (const float*)d_in[0];
  const float* Wq = (const float*)d_in[1];
  const float* bq = (const float*)d_in[2];
  const float* Wk = (const float*)d_in[3];
  const float* bk = (const float*)d_in[4];
  const float* Wv = (const float*)d_in[5];
  const float* bv = (const float*)d_in[6];
  const float* Wo = (const float*)d_in[7];
  const float* bo = (const float*)d_in[8];
  const int* idx  = (const int*)d_in[9];
  float* out = (float*)d_out;

  float* ws = (float*)d_ws;
  float* q      = ws;                       // 4,194,304 f
  float* kbuf   = ws + 4194304;
  float* vbuf   = ws + 8388608;
  float* Mbuf   = ws + 12582912;            // 65,536 f
  float* vmean  = ws + 12648448;            // 2,048 f
  float* pm     = ws + 12650496;            // 10,240 f
  float* ps     = ws + 12660736;            // 10,240 f
  float* dout   = ws + 12670976;            // 655,360 f [1280][512]
  float* base   = ws + 13326336;            // 2,048 f
  int*   M_top  = (int*)(ws + 13328384);    // 1,280
  int*   map    = (int*)(ws + 13329664);    // 65,536
  unsigned short* dvh = (unsigned short*)(ws + 13395200); // 655,360 u16 (327,680 f)
  unsigned short* dvl = (unsigned short*)(ws + 13722880); // -> ends 14,050,560
  unsigned short* xh  = (unsigned short*)(ws + 14050560); // 4,194,304 u16
  unsigned short* xl  = (unsigned short*)(ws + 16147712);
  unsigned short* WTh = (unsigned short*)(ws + 18244864); // 2048*512 u16
  unsigned short* WTl = (unsigned short*)(ws + 18769152); // ends 19,293,440 f
  float* partial = ws + 14050560;           // overlays xh/xl after gemm_qkv (2,621,440 f)

  convert_all<<<4096 + 2048, 256, 0, stream>>>(x, Wq, Wk, Wv, Wo, xh, xl, WTh, WTl);

  gemm_split<0><<<dim3(64, 12), 256, 0, stream>>>(
      xh, xl, WTh, WTl, bq, bk, bv, q, kbuf, vbuf);

  sampled_qk_kernel<<<512, 256, 0, stream>>>(q, kbuf, idx, Mbuf);
  topk_kernel<<<BH, 64, 0, stream>>>(Mbuf, M_top);
  vmean_kernel<<<BH, 256, 0, stream>>>(vbuf, vmean);

  fused_attn_kernel<<<dim3(8, BH), 256, 0, stream>>>(q, kbuf, vbuf, M_top, pm, ps, partial);

  hipMemsetAsync(map, 0xFF, BH * Nn * sizeof(int), stream);
  combine_lite<<<BH * Uu, 64, 0, stream>>>(pm, ps, partial, vmean, M_top, dvh, dvl, map);

  // dout[1280][512] = dvF @ Wo^T (zero-padded head slots)
  gemm_split<1><<<dim3(10, 4), 256, 0, stream>>>(
      dvh, dvl, WTh + (size_t)1536 * 512, WTl + (size_t)1536 * 512,
      nullptr, nullptr, nullptr, dout, nullptr, nullptr);

  base_kernel<<<Bb, 256, 0, stream>>>(vmean, Wo, bo, base);
  assemble_kernel<<<M_ROWS / 4, 256, 0, stream>>>(base, map, dout, out);
}

// Round 7
// 265.335 us; speedup vs baseline: 2.1750x; 1.0639x over previous
//
#include <hip/hip_runtime.h>
#include <math.h>

namespace {

constexpr int Bb = 4, Nn = 2048, Cc = 512, Hh = 8, Dd = 64, Ss = 40, Uu = 40;
constexpr int M_ROWS = Bb * Nn; // 8192
constexpr int BH = Bb * Hh;     // 32

typedef __attribute__((ext_vector_type(8))) short short8;
typedef __attribute__((ext_vector_type(4))) float f32x4;

__device__ inline unsigned short f2bf(float f) {
  union { float f; unsigned u; } v; v.f = f;
  unsigned r = (v.u + 0x7fffu + ((v.u >> 16) & 1u)) >> 16;
  return (unsigned short)r;
}
__device__ inline float bf2f(unsigned short h) {
  union { unsigned u; float f; } v; v.u = ((unsigned)h) << 16;
  return v.f;
}

// ---------- split x into bf16 hi/lo AND build transposed split weights ----------
// W rows 0..511: Wq^T, 512..1023: Wk^T, 1024..1535: Wv^T, 1536..2047: Wo^T
__global__ __launch_bounds__(256) void convert_all(
    const float* __restrict__ x, const float* __restrict__ Wq,
    const float* __restrict__ Wk, const float* __restrict__ Wv,
    const float* __restrict__ Wo,
    unsigned short* __restrict__ xh, unsigned short* __restrict__ xl,
    unsigned short* __restrict__ WTh, unsigned short* __restrict__ WTl)
{
  if (blockIdx.x < 4096) {
    size_t i = ((size_t)blockIdx.x * 256 + threadIdx.x) * 4;
    float4 v = *(const float4*)(x + i);
    ushort4 h, l;
    h.x = f2bf(v.x); l.x = f2bf(v.x - bf2f(h.x));
    h.y = f2bf(v.y); l.y = f2bf(v.y - bf2f(h.y));
    h.z = f2bf(v.z); l.z = f2bf(v.z - bf2f(h.z));
    h.w = f2bf(v.w); l.w = f2bf(v.w - bf2f(h.w));
    *(ushort4*)(xh + i) = h;
    *(ushort4*)(xl + i) = l;
  } else {
    int nrow = blockIdx.x - 4096;
    int which = nrow >> 9, col = nrow & 511;
    const float* Wsrc = which == 0 ? Wq : (which == 1 ? Wk : (which == 2 ? Wv : Wo));
    for (int kk = threadIdx.x; kk < 512; kk += 256) {
      float v = Wsrc[(size_t)kk * 512 + col];
      unsigned short h = f2bf(v);
      WTh[(size_t)nrow * 512 + kk] = h;
      WTl[(size_t)nrow * 512 + kk] = f2bf(v - bf2f(h));
    }
  }
}

// ---------- bf16 split-precision MFMA GEMM ----------
// MODE 0: QKV projection, grid (64,12), head-split fp32 outputs + bias
// MODE 1: plain C[M][512] = A @ B (no bias), grid (M/128, 4)
template<int MODE>
__global__ __launch_bounds__(256) void gemm_split(
    const unsigned short* __restrict__ xh, const unsigned short* __restrict__ xl,
    const unsigned short* __restrict__ WThp, const unsigned short* __restrict__ WTlp,
    const float* __restrict__ bq, const float* __restrict__ bk, const float* __restrict__ bv,
    float* __restrict__ o0, float* __restrict__ o1, float* __restrict__ o2)
{
  __shared__ __align__(16) unsigned short Ah[128 * 32];
  __shared__ __align__(16) unsigned short Al[128 * 32];
  __shared__ __align__(16) unsigned short Bh[128 * 32];
  __shared__ __align__(16) unsigned short Bl[128 * 32];
  int tid = threadIdx.x;
  int lane = tid & 63, w = tid >> 6;
  int bm = blockIdx.x * 128, bn = blockIdx.y * 128;

  f32x4 acc[4][4];
  #pragma unroll
  for (int i = 0; i < 4; ++i)
    #pragma unroll
    for (int j = 0; j < 4; ++j)
      #pragma unroll
      for (int r = 0; r < 4; ++r) acc[i][j][r] = 0.f;

  int wm = (w >> 1) * 64, wn = (w & 1) * 64;
  int lm = lane & 15, lg = lane >> 4;

  int srow = (lane >> 2);
  int cs = (lane & 3) ^ (srow & 3);   // pre-swizzled source chunk

  for (int kt = 0; kt < 16; ++kt) {
    int k0 = kt * 32;
    #pragma unroll
    for (int call = 0; call < 2; ++call) {
      int row = w * 16 + srow + call * 64;
      size_t offA = (size_t)(bm + row) * 512 + k0 + cs * 8;
      size_t offB = (size_t)(bn + row) * 512 + k0 + cs * 8;
      unsigned dst = call * 4096 + w * 1024;
      __builtin_amdgcn_global_load_lds(
          (const __attribute__((address_space(1))) void*)(xh + offA),
          (__attribute__((address_space(3))) void*)((char*)Ah + dst), 16, 0, 0);
      __builtin_amdgcn_global_load_lds(
          (const __attribute__((address_space(1))) void*)(xl + offA),
          (__attribute__((address_space(3))) void*)((char*)Al + dst), 16, 0, 0);
      __builtin_amdgcn_global_load_lds(
          (const __attribute__((address_space(1))) void*)(WThp + offB),
          (__attribute__((address_space(3))) void*)((char*)Bh + dst), 16, 0, 0);
      __builtin_amdgcn_global_load_lds(
          (const __attribute__((address_space(1))) void*)(WTlp + offB),
          (__attribute__((address_space(3))) void*)((char*)Bl + dst), 16, 0, 0);
    }
    __syncthreads();

    short8 afh[4], bgh[4], afl[4], bgl[4];
    #pragma unroll
    for (int i = 0; i < 4; ++i) {
      int R = wm + i * 16 + lm;
      afh[i] = *(const short8*)(Ah + R * 32 + ((lg ^ (R & 3)) * 8));
    }
    #pragma unroll
    for (int j = 0; j < 4; ++j) {
      int R = wn + j * 16 + lm;
      bgh[j] = *(const short8*)(Bh + R * 32 + ((lg ^ (R & 3)) * 8));
    }
    #pragma unroll
    for (int i = 0; i < 4; ++i)
      #pragma unroll
      for (int j = 0; j < 4; ++j)
        acc[i][j] = __builtin_amdgcn_mfma_f32_16x16x32_bf16(afh[i], bgh[j], acc[i][j], 0, 0, 0);

    #pragma unroll
    for (int i = 0; i < 4; ++i) {
      int R = wm + i * 16 + lm;
      afl[i] = *(const short8*)(Al + R * 32 + ((lg ^ (R & 3)) * 8));
    }
    #pragma unroll
    for (int i = 0; i < 4; ++i)
      #pragma unroll
      for (int j = 0; j < 4; ++j)
        acc[i][j] = __builtin_amdgcn_mfma_f32_16x16x32_bf16(afl[i], bgh[j], acc[i][j], 0, 0, 0);

    #pragma unroll
    for (int j = 0; j < 4; ++j) {
      int R = wn + j * 16 + lm;
      bgl[j] = *(const short8*)(Bl + R * 32 + ((lg ^ (R & 3)) * 8));
    }
    #pragma unroll
    for (int i = 0; i < 4; ++i)
      #pragma unroll
      for (int j = 0; j < 4; ++j)
        acc[i][j] = __builtin_amdgcn_mfma_f32_16x16x32_bf16(afh[i], bgl[j], acc[i][j], 0, 0, 0);

    __syncthreads();
  }

  if (MODE == 0) {
    #pragma unroll
    for (int j = 0; j < 4; ++j) {
      int n = bn + wn + j * 16 + lm;
      float bias = n < 512 ? bq[n] : (n < 1024 ? bk[n - 512] : bv[n - 1024]);
      int tensor = n >> 9, h = (n >> 6) & 7, d = n & 63;
      float* op = tensor == 0 ? o0 : (tensor == 1 ? o1 : o2);
      #pragma unroll
      for (int i = 0; i < 4; ++i) {
        #pragma unroll
        for (int r = 0; r < 4; ++r) {
          int m = bm + wm + i * 16 + lg * 4 + r;
          int b = m >> 11, nn = m & 2047;
          op[((size_t)(b * Hh + h) * Nn + nn) * Dd + d] = acc[i][j][r] + bias;
        }
      }
    }
  } else {
    #pragma unroll
    for (int j = 0; j < 4; ++j) {
      int n = bn + wn + j * 16 + lm;
      #pragma unroll
      for (int i = 0; i < 4; ++i) {
        #pragma unroll
        for (int r = 0; r < 4; ++r) {
          int m = bm + wm + i * 16 + lg * 4 + r;
          o0[(size_t)m * 512 + n] = acc[i][j][r];
        }
      }
    }
  }
}

// ---------- sampled QK^T -> M, bh-pinned to XCDs, high occupancy ----------
// 2048 blocks: xcd = p&7, j = p>>3; bh = (j>>6)*8 + xcd; chunk = j&63 (32 l's).
// Each XCD touches only 4 bh's K (2 MB) -> L2-resident. 8 blocks/CU.
__global__ __launch_bounds__(256) void sampled_qk_kernel(
    const float* __restrict__ q, const float* __restrict__ k,
    const int* __restrict__ idx, float* __restrict__ Mout)
{
  int p = blockIdx.x;
  int xcd = p & 7, j = p >> 3;
  int chunk = j & 63;
  int bh = (j >> 6) * 8 + xcd;
  int t = threadIdx.x;
  int w = t >> 6, lane = t & 63;
  int g = lane >> 2, dq = lane & 3;

  const float* kb = k + (size_t)bh * Nn * Dd;

  for (int li = 0; li < 8; ++li) {
    int l = chunk * 32 + w * 8 + li;
    const float* qrow = q + ((size_t)bh * Nn + l) * Dd + dq * 4;
    float4 qv[4];
    #pragma unroll
    for (int i = 0; i < 4; ++i) qv[i] = *(const float4*)(qrow + i * 16);
    float mx = -INFINITY, sm = 0.f;
    #pragma unroll
    for (int pass = 0; pass < 3; ++pass) {
      int s = pass * 16 + g;
      bool valid = (s < Ss);
      float dot = 0.f;
      if (valid) {
        int kr = idx[l * Ss + s];
        const float* krow = kb + (size_t)kr * Dd + dq * 4;
        #pragma unroll
        for (int i = 0; i < 4; ++i) {
          float4 kv = *(const float4*)(krow + i * 16);
          dot += kv.x * qv[i].x + kv.y * qv[i].y + kv.z * qv[i].z + kv.w * qv[i].w;
        }
      }
      dot += __shfl_xor(dot, 1);
      dot += __shfl_xor(dot, 2);
      if (valid) { mx = fmaxf(mx, dot); sm += dot; }
    }
    #pragma unroll
    for (int o = 4; o < 64; o <<= 1) {
      mx = fmaxf(mx, __shfl_xor(mx, o));
      sm += __shfl_xor(sm, o);
    }
    if (lane == 0) Mout[(size_t)bh * Nn + l] = mx - sm * (1.f / (float)Nn);
  }
}

// ---------- top-40 per (b,h): single wave, register-resident ----------
__global__ __launch_bounds__(64) void topk_kernel(
    const float* __restrict__ Min, int* __restrict__ M_top)
{
  int bh = blockIdx.x, lane = threadIdx.x;
  const float* row = Min + (size_t)bh * Nn;
  float v[32];
  #pragma unroll
  for (int j = 0; j < 32; ++j) v[j] = row[j * 64 + lane];
  unsigned mask = 0;
  for (int it = 0; it < Uu; ++it) {
    float best = -INFINITY; int bidx = 0x7FFFFFFF;
    #pragma unroll
    for (int j = 0; j < 32; ++j) {
      if (!((mask >> j) & 1u) && v[j] > best) { best = v[j]; bidx = j * 64 + lane; }
    }
    #pragma unroll
    for (int o = 32; o; o >>= 1) {
      float ov = __shfl_xor(best, o);
      int oi = __shfl_xor(bidx, o);
      if (ov > best || (ov == best && oi < bidx)) { best = ov; bidx = oi; }
    }
    if ((bidx & 63) == lane) mask |= 1u << (bidx >> 6);
    if (lane == 0) M_top[bh * Uu + it] = bidx;
  }
}

// ---------- mean of V over N per (b,h,d) ----------
__global__ __launch_bounds__(256) void vmean_kernel(
    const float* __restrict__ v, float* __restrict__ vmean)
{
  int bh = blockIdx.x, t = threadIdx.x;
  int d = t & 63, chunk = t >> 6;
  const float* base = v + (size_t)bh * Nn * Dd;
  float s = 0.f;
  for (int n = chunk * 512; n < (chunk + 1) * 512; ++n) s += base[(size_t)n * Dd + d];
  __shared__ float part[4][64];
  part[chunk][d] = s;
  __syncthreads();
  if (t < 64)
    vmean[bh * Dd + t] = (part[0][t] + part[1][t] + part[2][t] + part[3][t]) * (1.f / (float)Nn);
}

// ---------- fused scores+softmax+PV partials, per (n-chunk, bh) ----------
// partial layout: [bhu][32][64] so the combine kernel reads 8KB contiguous.
__global__ __launch_bounds__(256) void fused_attn_kernel(
    const float* __restrict__ q, const float* __restrict__ k, const float* __restrict__ v,
    const int* __restrict__ M_top, float* __restrict__ pm, float* __restrict__ ps,
    float* __restrict__ partial)
{
  int chunk = blockIdx.x, bh = blockIdx.y, t = threadIdx.x;
  __shared__ float qs[40][64];
  __shared__ float S[40][256];
  if (t < 160) {
    int u = t >> 2, p = (t & 3) * 16;
    int r = M_top[bh * Uu + u];
    const float4* src = (const float4*)(q + ((size_t)bh * Nn + r) * Dd + p);
    *(float4*)&qs[u][p + 0]  = src[0];
    *(float4*)&qs[u][p + 4]  = src[1];
    *(float4*)&qs[u][p + 8]  = src[2];
    *(float4*)&qs[u][p + 12] = src[3];
  }
  __syncthreads();

  {
    int n = chunk * 256 + t;
    const float4* krow = (const float4*)(k + ((size_t)bh * Nn + n) * Dd);
    float acc[40];
    #pragma unroll
    for (int u = 0; u < 40; ++u) acc[u] = 0.f;
    #pragma unroll
    for (int d4 = 0; d4 < 16; ++d4) {
      float4 kv = krow[d4];
      #pragma unroll
      for (int u = 0; u < 40; ++u) {
        float4 qv = *(const float4*)&qs[u][d4 * 4];
        acc[u] += qv.x * kv.x + qv.y * kv.y + qv.z * kv.z + qv.w * kv.w;
      }
    }
    #pragma unroll
    for (int u = 0; u < 40; ++u) S[u][t] = acc[u] * 0.125f;
  }
  __syncthreads();

  int w = t >> 6, lane = t & 63;
  #pragma unroll
  for (int r = 0; r < 10; ++r) {
    int u = w * 10 + r;
    float v0 = S[u][lane], v1 = S[u][lane + 64], v2 = S[u][lane + 128], v3 = S[u][lane + 192];
    float m = fmaxf(fmaxf(v0, v1), fmaxf(v2, v3));
    #pragma unroll
    for (int o = 1; o < 64; o <<= 1) m = fmaxf(m, __shfl_xor(m, o));
    float e0 = expf(v0 - m), e1 = expf(v1 - m), e2 = expf(v2 - m), e3 = expf(v3 - m);
    S[u][lane] = e0; S[u][lane + 64] = e1; S[u][lane + 128] = e2; S[u][lane + 192] = e3;
    float sum = e0 + e1 + e2 + e3;
    #pragma unroll
    for (int o = 1; o < 64; o <<= 1) sum += __shfl_xor(sum, o);
    if (lane == 0) {
      pm[(bh * 8 + chunk) * Uu + u] = m;
      ps[(bh * 8 + chunk) * Uu + u] = sum;
    }
  }
  __syncthreads();

  float acc2[40];
  #pragma unroll
  for (int u = 0; u < 40; ++u) acc2[u] = 0.f;
  const float* vb = v + ((size_t)bh * Nn + chunk * 256 + w * 64) * Dd + lane;
  for (int i = 0; i < 64; ++i) {
    float vv = vb[(size_t)i * Dd];
    #pragma unroll
    for (int u = 0; u < 40; ++u) acc2[u] = fmaf(S[u][w * 64 + i], vv, acc2[u]);
  }
  float* pp = partial + ((size_t)bh * Uu * 32 + chunk * 4 + w) * Dd + lane;
  #pragma unroll
  for (int u = 0; u < 40; ++u) pp[(size_t)u * 2048] = acc2[u];
}

// ---------- combine partials -> dvF (zero-padded bf16 hi/lo) + map ----------
// 1 wave per bhu. lane = d.
__global__ __launch_bounds__(64) void combine_lite(
    const float* __restrict__ pm, const float* __restrict__ ps,
    const float* __restrict__ partial, const float* __restrict__ vmean,
    const int* __restrict__ M_top,
    unsigned short* __restrict__ dvh, unsigned short* __restrict__ dvl,
    int* __restrict__ map)
{
  int bhu = blockIdx.x;
  int bh = bhu / Uu, u = bhu % Uu, h = bh & 7;
  int lane = threadIdx.x;

  float pmv[8], psv[8];
  #pragma unroll
  for (int c = 0; c < 8; ++c) {
    pmv[c] = pm[(bh * 8 + c) * Uu + u];
    psv[c] = ps[(bh * 8 + c) * Uu + u];
  }
  float m = pmv[0];
  #pragma unroll
  for (int c = 1; c < 8; ++c) m = fmaxf(m, pmv[c]);
  float w8[8], Z = 0.f;
  #pragma unroll
  for (int c = 0; c < 8; ++c) { w8[c] = expf(pmv[c] - m); Z += w8[c] * psv[c]; }

  const float* pb = partial + (size_t)bhu * 2048;
  float s = 0.f;
  #pragma unroll
  for (int cw = 0; cw < 32; ++cw)
    s = fmaf(pb[cw * 64 + lane], w8[cw >> 2], s);

  float dv = s / Z - vmean[bh * Dd + lane];
  unsigned short hbits = f2bf(dv);
  unsigned short lbits = f2bf(dv - bf2f(hbits));

  #pragma unroll
  for (int cc = 0; cc < 8; ++cc) {
    int c = cc * 64 + lane;
    bool mine = (cc == h);
    dvh[(size_t)bhu * 512 + c] = mine ? hbits : (unsigned short)0;
    dvl[(size_t)bhu * 512 + c] = mine ? lbits : (unsigned short)0;
  }
  if (lane == 0) map[bh * Nn + M_top[bhu]] = bhu;
}

// ---------- base[b][c] = vmean_b @ Wo + bo ----------
__global__ __launch_bounds__(256) void base_kernel(
    const float* __restrict__ vmean, const float* __restrict__ Wo,
    const float* __restrict__ bo, float* __restrict__ base)
{
  int b = blockIdx.x, t = threadIdx.x;
  __shared__ float vm[512];
  vm[t] = vmean[b * 512 + t];
  vm[t + 256] = vmean[b * 512 + t + 256];
  __syncthreads();
  for (int c = t; c < 512; c += 256) {
    float s = bo[c];
    for (int k2 = 0; k2 < 512; ++k2)
      s = fmaf(vm[k2], Wo[(size_t)k2 * 512 + c], s);
    base[b * 512 + c] = s;
  }
}

// ---------- assemble out rows ----------
__global__ __launch_bounds__(256) void assemble_kernel(
    const float* __restrict__ base, const int* __restrict__ map,
    const float* __restrict__ dout, float* __restrict__ out)
{
  int t = threadIdx.x;
  int row = blockIdx.x * 4 + (t >> 6);
  int lane = t & 63;
  int b = row >> 11, n = row & 2047;
  float4 a0 = *(const float4*)(base + b * 512 + lane * 4);
  float4 a1 = *(const float4*)(base + b * 512 + 256 + lane * 4);
  for (int h = 0; h < 8; ++h) {
    int mi = map[(b * Hh + h) * Nn + n];
    if (mi >= 0) {
      const float* dp = dout + (size_t)mi * 512;
      float4 d0 = *(const float4*)(dp + lane * 4);
      float4 d1 = *(const float4*)(dp + 256 + lane * 4);
      a0.x += d0.x; a0.y += d0.y; a0.z += d0.z; a0.w += d0.w;
      a1.x += d1.x; a1.y += d1.y; a1.z += d1.z; a1.w += d1.w;
    }
  }
  *(float4*)(out + (size_t)row * 512 + lane * 4) = a0;
  *(float4*)(out + (size_t)row * 512 + 256 + lane * 4) = a1;
}

} // namespace

extern "C" void kernel_launch(void* const* d_in, const int* in_sizes, int n_in,
                              void* d_out, int out_size, void* d_ws, size_t ws_size,
                              hipStream_t stream) {
  const float* x  = (const float*)d_in[0];
  const float* Wq = (const float*)d_in[1];
  const float* bq = (const float*)d_in[2];
  const float* Wk = (const float*)d_in[3];
  const float* bk = (const float*)d_in[4];
  const float* Wv = (const float*)d_in[5];
  const float* bv = (const float*)d_in[6];
  const float* Wo = (const float*)d_in[7];
  const float* bo = (const float*)d_in[8];
  const int* idx  = (const int*)d_in[9];
  float* out = (float*)d_out;

  float* ws = (float*)d_ws;
  float* q      = ws;                       // 4,194,304 f
  float* kbuf   = ws + 4194304;
  float* vbuf   = ws + 8388608;
  float* Mbuf   = ws + 12582912;            // 65,536 f
  float* vmean  = ws + 12648448;            // 2,048 f
  float* pm     = ws + 12650496;            // 10,240 f
  float* ps     = ws + 12660736;            // 10,240 f
  float* dout   = ws + 12670976;            // 655,360 f [1280][512]
  float* base   = ws + 13326336;            // 2,048 f
  int*   M_top  = (int*)(ws + 13328384);    // 1,280
  int*   map    = (int*)(ws + 13329664);    // 65,536
  unsigned short* dvh = (unsigned short*)(ws + 13395200); // 655,360 u16
  unsigned short* dvl = (unsigned short*)(ws + 13722880);
  unsigned short* xh  = (unsigned short*)(ws + 14050560); // 4,194,304 u16
  unsigned short* xl  = (unsigned short*)(ws + 16147712);
  unsigned short* WTh = (unsigned short*)(ws + 18244864); // 2048*512 u16
  unsigned short* WTl = (unsigned short*)(ws + 18769152);
  float* partial = ws + 14050560;           // overlays xh/xl after gemm_qkv

  convert_all<<<4096 + 2048, 256, 0, stream>>>(x, Wq, Wk, Wv, Wo, xh, xl, WTh, WTl);

  gemm_split<0><<<dim3(64, 12), 256, 0, stream>>>(
      xh, xl, WTh, WTl, bq, bk, bv, q, kbuf, vbuf);

  sampled_qk_kernel<<<2048, 256, 0, stream>>>(q, kbuf, idx, Mbuf);
  topk_kernel<<<BH, 64, 0, stream>>>(Mbuf, M_top);
  vmean_kernel<<<BH, 256, 0, stream>>>(vbuf, vmean);

  fused_attn_kernel<<<dim3(8, BH), 256, 0, stream>>>(q, kbuf, vbuf, M_top, pm, ps, partial);

  hipMemsetAsync(map, 0xFF, BH * Nn * sizeof(int), stream);
  combine_lite<<<BH * Uu, 64, 0, stream>>>(pm, ps, partial, vmean, M_top, dvh, dvl, map);

  gemm_split<1><<<dim3(10, 4), 256, 0, stream>>>(
      dvh, dvl, WTh + (size_t)1536 * 512, WTl + (size_t)1536 * 512,
      nullptr, nullptr, nullptr, dout, nullptr, nullptr);

  base_kernel<<<Bb, 256, 0, stream>>>(vmean, Wo, bo, base);
  assemble_kernel<<<M_ROWS / 4, 256, 0, stream>>>(base, map, dout, out);
}

// Round 8
// 261.239 us; speedup vs baseline: 2.2091x; 1.0157x over previous
//
#include <hip/hip_runtime.h>
#include <math.h>

namespace {

constexpr int Bb = 4, Nn = 2048, Cc = 512, Hh = 8, Dd = 64, Ss = 40, Uu = 40;
constexpr int M_ROWS = Bb * Nn; // 8192
constexpr int BH = Bb * Hh;     // 32

typedef __attribute__((ext_vector_type(8))) short short8;
typedef __attribute__((ext_vector_type(4))) float f32x4;

__device__ inline unsigned short f2bf(float f) {
  union { float f; unsigned u; } v; v.f = f;
  unsigned r = (v.u + 0x7fffu + ((v.u >> 16) & 1u)) >> 16;
  return (unsigned short)r;
}
__device__ inline float bf2f(unsigned short h) {
  union { unsigned u; float f; } v; v.u = ((unsigned)h) << 16;
  return v.f;
}

// ---------- split x into bf16 hi/lo AND build transposed split weights ----------
// W rows 0..511: Wq^T, 512..1023: Wk^T, 1024..1535: Wv^T, 1536..2047: Wo^T
__global__ __launch_bounds__(256) void convert_all(
    const float* __restrict__ x, const float* __restrict__ Wq,
    const float* __restrict__ Wk, const float* __restrict__ Wv,
    const float* __restrict__ Wo,
    unsigned short* __restrict__ xh, unsigned short* __restrict__ xl,
    unsigned short* __restrict__ WTh, unsigned short* __restrict__ WTl)
{
  if (blockIdx.x < 4096) {
    size_t i = ((size_t)blockIdx.x * 256 + threadIdx.x) * 4;
    float4 v = *(const float4*)(x + i);
    ushort4 h, l;
    h.x = f2bf(v.x); l.x = f2bf(v.x - bf2f(h.x));
    h.y = f2bf(v.y); l.y = f2bf(v.y - bf2f(h.y));
    h.z = f2bf(v.z); l.z = f2bf(v.z - bf2f(h.z));
    h.w = f2bf(v.w); l.w = f2bf(v.w - bf2f(h.w));
    *(ushort4*)(xh + i) = h;
    *(ushort4*)(xl + i) = l;
  } else {
    int nrow = blockIdx.x - 4096;
    int which = nrow >> 9, col = nrow & 511;
    const float* Wsrc = which == 0 ? Wq : (which == 1 ? Wk : (which == 2 ? Wv : Wo));
    for (int kk = threadIdx.x; kk < 512; kk += 256) {
      float v = Wsrc[(size_t)kk * 512 + col];
      unsigned short h = f2bf(v);
      WTh[(size_t)nrow * 512 + kk] = h;
      WTl[(size_t)nrow * 512 + kk] = f2bf(v - bf2f(h));
    }
  }
}

// ---------- bf16 split-precision MFMA GEMM, 2-phase double-buffered ----------
// Swizzle: LDS[row][p] holds global chunk p ^ ((row>>1)&3)  (granule-exact,
// 2 lanes/granule on ds_read_b128 -> conflict-free). Source pre-swizzled.
// One barrier per K-step; stage of tile t+1 overlaps MFMA of tile t.
template<int MODE>
__global__ __launch_bounds__(256) void gemm_split(
    const unsigned short* __restrict__ xh, const unsigned short* __restrict__ xl,
    const unsigned short* __restrict__ WThp, const unsigned short* __restrict__ WTlp,
    const float* __restrict__ bq, const float* __restrict__ bk, const float* __restrict__ bv,
    float* __restrict__ o0, float* __restrict__ o1, float* __restrict__ o2)
{
  __shared__ __align__(16) unsigned short Ah[2][128 * 32];
  __shared__ __align__(16) unsigned short Al[2][128 * 32];
  __shared__ __align__(16) unsigned short Bh[2][128 * 32];
  __shared__ __align__(16) unsigned short Bl[2][128 * 32];
  int tid = threadIdx.x;
  int lane = tid & 63, w = tid >> 6;
  int bm = blockIdx.x * 128, bn = blockIdx.y * 128;

  f32x4 acc[4][4];
  #pragma unroll
  for (int i = 0; i < 4; ++i)
    #pragma unroll
    for (int j = 0; j < 4; ++j)
      #pragma unroll
      for (int r = 0; r < 4; ++r) acc[i][j][r] = 0.f;

  int wm = (w >> 1) * 64, wn = (w & 1) * 64;
  int lm = lane & 15, lg = lane >> 4;

  int srow = lane >> 2;
  int row0 = w * 16 + srow;
  int row1 = row0 + 64;
  int cs0 = (lane & 3) ^ ((row0 >> 1) & 3);
  int cs1 = (lane & 3) ^ ((row1 >> 1) & 3);
  size_t a0 = (size_t)(bm + row0) * 512 + cs0 * 8;
  size_t a1 = (size_t)(bm + row1) * 512 + cs1 * 8;
  size_t b0 = (size_t)(bn + row0) * 512 + cs0 * 8;
  size_t b1 = (size_t)(bn + row1) * 512 + cs1 * 8;
  unsigned d0 = w * 1024;

#define GLDS(gp, lp) __builtin_amdgcn_global_load_lds( \
    (const __attribute__((address_space(1))) void*)(gp), \
    (__attribute__((address_space(3))) void*)(lp), 16, 0, 0)

#define STAGE(bi, k0) do { \
    GLDS(xh   + a0 + (k0), (char*)Ah + (bi) * 8192 + d0); \
    GLDS(xh   + a1 + (k0), (char*)Ah + (bi) * 8192 + 4096 + d0); \
    GLDS(xl   + a0 + (k0), (char*)Al + (bi) * 8192 + d0); \
    GLDS(xl   + a1 + (k0), (char*)Al + (bi) * 8192 + 4096 + d0); \
    GLDS(WThp + b0 + (k0), (char*)Bh + (bi) * 8192 + d0); \
    GLDS(WThp + b1 + (k0), (char*)Bh + (bi) * 8192 + 4096 + d0); \
    GLDS(WTlp + b0 + (k0), (char*)Bl + (bi) * 8192 + d0); \
    GLDS(WTlp + b1 + (k0), (char*)Bl + (bi) * 8192 + 4096 + d0); \
  } while (0)

  STAGE(0, 0);
  __syncthreads();
  int buf = 0;

  for (int kt = 0; kt < 16; ++kt) {
    if (kt < 15) STAGE(buf ^ 1, (kt + 1) * 32);

    const unsigned short* Ahb = Ah[buf];
    const unsigned short* Alb = Al[buf];
    const unsigned short* Bhb = Bh[buf];
    const unsigned short* Blb = Bl[buf];

    short8 afh[4], bgh[4], afl[4], bgl[4];
    #pragma unroll
    for (int i = 0; i < 4; ++i) {
      int R = wm + i * 16 + lm;
      afh[i] = *(const short8*)(Ahb + R * 32 + ((lg ^ ((R >> 1) & 3)) * 8));
    }
    #pragma unroll
    for (int j = 0; j < 4; ++j) {
      int R = wn + j * 16 + lm;
      bgh[j] = *(const short8*)(Bhb + R * 32 + ((lg ^ ((R >> 1) & 3)) * 8));
    }
    #pragma unroll
    for (int i = 0; i < 4; ++i)
      #pragma unroll
      for (int j = 0; j < 4; ++j)
        acc[i][j] = __builtin_amdgcn_mfma_f32_16x16x32_bf16(afh[i], bgh[j], acc[i][j], 0, 0, 0);

    #pragma unroll
    for (int i = 0; i < 4; ++i) {
      int R = wm + i * 16 + lm;
      afl[i] = *(const short8*)(Alb + R * 32 + ((lg ^ ((R >> 1) & 3)) * 8));
    }
    #pragma unroll
    for (int i = 0; i < 4; ++i)
      #pragma unroll
      for (int j = 0; j < 4; ++j)
        acc[i][j] = __builtin_amdgcn_mfma_f32_16x16x32_bf16(afl[i], bgh[j], acc[i][j], 0, 0, 0);

    #pragma unroll
    for (int j = 0; j < 4; ++j) {
      int R = wn + j * 16 + lm;
      bgl[j] = *(const short8*)(Blb + R * 32 + ((lg ^ ((R >> 1) & 3)) * 8));
    }
    #pragma unroll
    for (int i = 0; i < 4; ++i)
      #pragma unroll
      for (int j = 0; j < 4; ++j)
        acc[i][j] = __builtin_amdgcn_mfma_f32_16x16x32_bf16(afh[i], bgl[j], acc[i][j], 0, 0, 0);

    __syncthreads();
    buf ^= 1;
  }
#undef STAGE
#undef GLDS

  if (MODE == 0) {
    #pragma unroll
    for (int j = 0; j < 4; ++j) {
      int n = bn + wn + j * 16 + lm;
      float bias = n < 512 ? bq[n] : (n < 1024 ? bk[n - 512] : bv[n - 1024]);
      int tensor = n >> 9, h = (n >> 6) & 7, d = n & 63;
      float* op = tensor == 0 ? o0 : (tensor == 1 ? o1 : o2);
      #pragma unroll
      for (int i = 0; i < 4; ++i) {
        #pragma unroll
        for (int r = 0; r < 4; ++r) {
          int m = bm + wm + i * 16 + lg * 4 + r;
          int b = m >> 11, nn = m & 2047;
          op[((size_t)(b * Hh + h) * Nn + nn) * Dd + d] = acc[i][j][r] + bias;
        }
      }
    }
  } else {
    #pragma unroll
    for (int j = 0; j < 4; ++j) {
      int n = bn + wn + j * 16 + lm;
      #pragma unroll
      for (int i = 0; i < 4; ++i) {
        #pragma unroll
        for (int r = 0; r < 4; ++r) {
          int m = bm + wm + i * 16 + lg * 4 + r;
          o0[(size_t)m * 512 + n] = acc[i][j][r];
        }
      }
    }
  }
}

// ---------- sampled QK^T -> M, bh-pinned to XCDs, high occupancy ----------
__global__ __launch_bounds__(256) void sampled_qk_kernel(
    const float* __restrict__ q, const float* __restrict__ k,
    const int* __restrict__ idx, float* __restrict__ Mout)
{
  int p = blockIdx.x;
  int xcd = p & 7, j = p >> 3;
  int chunk = j & 63;
  int bh = (j >> 6) * 8 + xcd;
  int t = threadIdx.x;
  int w = t >> 6, lane = t & 63;
  int g = lane >> 2, dq = lane & 3;

  const float* kb = k + (size_t)bh * Nn * Dd;

  for (int li = 0; li < 8; ++li) {
    int l = chunk * 32 + w * 8 + li;
    const float* qrow = q + ((size_t)bh * Nn + l) * Dd + dq * 4;
    float4 qv[4];
    #pragma unroll
    for (int i = 0; i < 4; ++i) qv[i] = *(const float4*)(qrow + i * 16);
    float mx = -INFINITY, sm = 0.f;
    #pragma unroll
    for (int pass = 0; pass < 3; ++pass) {
      int s = pass * 16 + g;
      bool valid = (s < Ss);
      float dot = 0.f;
      if (valid) {
        int kr = idx[l * Ss + s];
        const float* krow = kb + (size_t)kr * Dd + dq * 4;
        #pragma unroll
        for (int i = 0; i < 4; ++i) {
          float4 kv = *(const float4*)(krow + i * 16);
          dot += kv.x * qv[i].x + kv.y * qv[i].y + kv.z * qv[i].z + kv.w * qv[i].w;
        }
      }
      dot += __shfl_xor(dot, 1);
      dot += __shfl_xor(dot, 2);
      if (valid) { mx = fmaxf(mx, dot); sm += dot; }
    }
    #pragma unroll
    for (int o = 4; o < 64; o <<= 1) {
      mx = fmaxf(mx, __shfl_xor(mx, o));
      sm += __shfl_xor(sm, o);
    }
    if (lane == 0) Mout[(size_t)bh * Nn + l] = mx - sm * (1.f / (float)Nn);
  }
}

// ---------- top-40 per (b,h): single wave, register-resident ----------
__global__ __launch_bounds__(64) void topk_kernel(
    const float* __restrict__ Min, int* __restrict__ M_top)
{
  int bh = blockIdx.x, lane = threadIdx.x;
  const float* row = Min + (size_t)bh * Nn;
  float v[32];
  #pragma unroll
  for (int j = 0; j < 32; ++j) v[j] = row[j * 64 + lane];
  unsigned mask = 0;
  for (int it = 0; it < Uu; ++it) {
    float best = -INFINITY; int bidx = 0x7FFFFFFF;
    #pragma unroll
    for (int j = 0; j < 32; ++j) {
      if (!((mask >> j) & 1u) && v[j] > best) { best = v[j]; bidx = j * 64 + lane; }
    }
    #pragma unroll
    for (int o = 32; o; o >>= 1) {
      float ov = __shfl_xor(best, o);
      int oi = __shfl_xor(bidx, o);
      if (ov > best || (ov == best && oi < bidx)) { best = ov; bidx = oi; }
    }
    if ((bidx & 63) == lane) mask |= 1u << (bidx >> 6);
    if (lane == 0) M_top[bh * Uu + it] = bidx;
  }
}

// ---------- mean of V over N per (b,h,d) ----------
__global__ __launch_bounds__(256) void vmean_kernel(
    const float* __restrict__ v, float* __restrict__ vmean)
{
  int bh = blockIdx.x, t = threadIdx.x;
  int d = t & 63, chunk = t >> 6;
  const float* base = v + (size_t)bh * Nn * Dd;
  float s = 0.f;
  for (int n = chunk * 512; n < (chunk + 1) * 512; ++n) s += base[(size_t)n * Dd + d];
  __shared__ float part[4][64];
  part[chunk][d] = s;
  __syncthreads();
  if (t < 64)
    vmean[bh * Dd + t] = (part[0][t] + part[1][t] + part[2][t] + part[3][t]) * (1.f / (float)Nn);
}

// ---------- fused scores+softmax+PV partials, per (64-col chunk, bh) ----------
// Grid (32, 32) = 1024 blocks (4/CU). Wave w owns u-group w*10..w*10+9.
// partial layout [bh][u][32][64]; pm/ps [bh][32][40].
__global__ __launch_bounds__(256) void fused_attn_kernel(
    const float* __restrict__ q, const float* __restrict__ k, const float* __restrict__ v,
    const int* __restrict__ M_top, float* __restrict__ pm, float* __restrict__ ps,
    float* __restrict__ partial)
{
  int chunk = blockIdx.x, bh = blockIdx.y, t = threadIdx.x;
  __shared__ float qs[40][64];
  __shared__ float S[40][64];
  if (t < 160) {
    int u = t >> 2, p = (t & 3) * 16;
    int r = M_top[bh * Uu + u];
    const float4* src = (const float4*)(q + ((size_t)bh * Nn + r) * Dd + p);
    *(float4*)&qs[u][p + 0]  = src[0];
    *(float4*)&qs[u][p + 4]  = src[1];
    *(float4*)&qs[u][p + 8]  = src[2];
    *(float4*)&qs[u][p + 12] = src[3];
  }
  __syncthreads();

  int nl = t & 63, w = t >> 6;   // wave w handles u in [w*10, w*10+10)
  {
    int n = chunk * 64 + nl;
    const float4* krow = (const float4*)(k + ((size_t)bh * Nn + n) * Dd);
    float acc[10];
    #pragma unroll
    for (int uu = 0; uu < 10; ++uu) acc[uu] = 0.f;
    #pragma unroll
    for (int d4 = 0; d4 < 16; ++d4) {
      float4 kv = krow[d4];
      #pragma unroll
      for (int uu = 0; uu < 10; ++uu) {
        float4 qv = *(const float4*)&qs[w * 10 + uu][d4 * 4];
        acc[uu] += qv.x * kv.x + qv.y * kv.y + qv.z * kv.z + qv.w * kv.w;
      }
    }
    #pragma unroll
    for (int uu = 0; uu < 10; ++uu) S[w * 10 + uu][nl] = acc[uu] * 0.125f;
  }
  // no barrier: each wave softmaxes + PVs its own u rows (wave-coherent LDS)

  #pragma unroll
  for (int r = 0; r < 10; ++r) {
    int u = w * 10 + r;
    float v0 = S[u][nl];
    float m = v0;
    #pragma unroll
    for (int o = 1; o < 64; o <<= 1) m = fmaxf(m, __shfl_xor(m, o));
    float e0 = expf(v0 - m);
    S[u][nl] = e0;
    float sum = e0;
    #pragma unroll
    for (int o = 1; o < 64; o <<= 1) sum += __shfl_xor(sum, o);
    if (nl == 0) {
      pm[(bh * 32 + chunk) * Uu + u] = m;
      ps[(bh * 32 + chunk) * Uu + u] = sum;
    }
  }

  float acc2[10];
  #pragma unroll
  for (int uu = 0; uu < 10; ++uu) acc2[uu] = 0.f;
  const float* vb = v + ((size_t)bh * Nn + chunk * 64) * Dd + nl;
  for (int i = 0; i < 64; ++i) {
    float vv = vb[(size_t)i * Dd];
    #pragma unroll
    for (int uu = 0; uu < 10; ++uu) acc2[uu] = fmaf(S[w * 10 + uu][i], vv, acc2[uu]);
  }
  #pragma unroll
  for (int uu = 0; uu < 10; ++uu) {
    int u = w * 10 + uu;
    partial[(((size_t)bh * Uu + u) * 32 + chunk) * 64 + nl] = acc2[uu];
  }
}

// ---------- combine partials -> dvF (zero-padded bf16 hi/lo) + map ----------
__global__ __launch_bounds__(64) void combine_lite(
    const float* __restrict__ pm, const float* __restrict__ ps,
    const float* __restrict__ partial, const float* __restrict__ vmean,
    const int* __restrict__ M_top,
    unsigned short* __restrict__ dvh, unsigned short* __restrict__ dvl,
    int* __restrict__ map)
{
  int bhu = blockIdx.x;
  int bh = bhu / Uu, u = bhu % Uu, h = bh & 7;
  int lane = threadIdx.x;

  float pmv[32];
  float m = -INFINITY;
  #pragma unroll
  for (int c = 0; c < 32; ++c) {
    pmv[c] = pm[(bh * 32 + c) * Uu + u];
    m = fmaxf(m, pmv[c]);
  }
  float w32[32], Z = 0.f;
  #pragma unroll
  for (int c = 0; c < 32; ++c) {
    w32[c] = expf(pmv[c] - m);
    Z += w32[c] * ps[(bh * 32 + c) * Uu + u];
  }

  const float* pb = partial + (size_t)bhu * 2048;
  float s = 0.f;
  #pragma unroll
  for (int c = 0; c < 32; ++c)
    s = fmaf(pb[c * 64 + lane], w32[c], s);

  float dv = s / Z - vmean[bh * Dd + lane];
  unsigned short hbits = f2bf(dv);
  unsigned short lbits = f2bf(dv - bf2f(hbits));

  #pragma unroll
  for (int cc = 0; cc < 8; ++cc) {
    int c = cc * 64 + lane;
    bool mine = (cc == h);
    dvh[(size_t)bhu * 512 + c] = mine ? hbits : (unsigned short)0;
    dvl[(size_t)bhu * 512 + c] = mine ? lbits : (unsigned short)0;
  }
  if (lane == 0) map[bh * Nn + M_top[bhu]] = bhu;
}

// ---------- base[b][c] = vmean_b @ Wo + bo ----------
__global__ __launch_bounds__(256) void base_kernel(
    const float* __restrict__ vmean, const float* __restrict__ Wo,
    const float* __restrict__ bo, float* __restrict__ base)
{
  int b = blockIdx.x, t = threadIdx.x;
  __shared__ float vm[512];
  vm[t] = vmean[b * 512 + t];
  vm[t + 256] = vmean[b * 512 + t + 256];
  __syncthreads();
  for (int c = t; c < 512; c += 256) {
    float s = bo[c];
    for (int k2 = 0; k2 < 512; ++k2)
      s = fmaf(vm[k2], Wo[(size_t)k2 * 512 + c], s);
    base[b * 512 + c] = s;
  }
}

// ---------- assemble out rows ----------
__global__ __launch_bounds__(256) void assemble_kernel(
    const float* __restrict__ base, const int* __restrict__ map,
    const float* __restrict__ dout, float* __restrict__ out)
{
  int t = threadIdx.x;
  int row = blockIdx.x * 4 + (t >> 6);
  int lane = t & 63;
  int b = row >> 11, n = row & 2047;
  float4 a0 = *(const float4*)(base + b * 512 + lane * 4);
  float4 a1 = *(const float4*)(base + b * 512 + 256 + lane * 4);
  for (int h = 0; h < 8; ++h) {
    int mi = map[(b * Hh + h) * Nn + n];
    if (mi >= 0) {
      const float* dp = dout + (size_t)mi * 512;
      float4 d0 = *(const float4*)(dp + lane * 4);
      float4 d1 = *(const float4*)(dp + 256 + lane * 4);
      a0.x += d0.x; a0.y += d0.y; a0.z += d0.z; a0.w += d0.w;
      a1.x += d1.x; a1.y += d1.y; a1.z += d1.z; a1.w += d1.w;
    }
  }
  *(float4*)(out + (size_t)row * 512 + lane * 4) = a0;
  *(float4*)(out + (size_t)row * 512 + 256 + lane * 4) = a1;
}

} // namespace

extern "C" void kernel_launch(void* const* d_in, const int* in_sizes, int n_in,
                              void* d_out, int out_size, void* d_ws, size_t ws_size,
                              hipStream_t stream) {
  const float* x  = (const float*)d_in[0];
  const float* Wq = (const float*)d_in[1];
  const float* bq = (const float*)d_in[2];
  const float* Wk = (const float*)d_in[3];
  const float* bk = (const float*)d_in[4];
  const float* Wv = (const float*)d_in[5];
  const float* bv = (const float*)d_in[6];
  const float* Wo = (const float*)d_in[7];
  const float* bo = (const float*)d_in[8];
  const int* idx  = (const int*)d_in[9];
  float* out = (float*)d_out;

  float* ws = (float*)d_ws;
  float* q      = ws;                       // 4,194,304 f
  float* kbuf   = ws + 4194304;
  float* vbuf   = ws + 8388608;
  float* Mbuf   = ws + 12582912;            // 65,536 f
  float* vmean  = ws + 12648448;            // 2,048 f
  float* pm     = ws + 12650496;            // 40,960 f [32][32][40]
  float* ps     = ws + 12691456;            // 40,960 f
  float* dout   = ws + 12732416;            // 655,360 f [1280][512]
  float* base   = ws + 13387776;            // 2,048 f
  int*   M_top  = (int*)(ws + 13389824);    // 1,280
  int*   map    = (int*)(ws + 13391104);    // 65,536
  unsigned short* dvh = (unsigned short*)(ws + 13456640); // 655,360 u16
  unsigned short* dvl = (unsigned short*)(ws + 13784320);
  unsigned short* xh  = (unsigned short*)(ws + 14112000); // 4,194,304 u16
  unsigned short* xl  = (unsigned short*)(ws + 16209152);
  unsigned short* WTh = (unsigned short*)(ws + 18306304); // 2048*512 u16
  unsigned short* WTl = (unsigned short*)(ws + 18830592); // ends 19,354,880 f
  float* partial = ws + 14112000;           // overlays xh/xl after gemm<0> (2,621,440 f)

  convert_all<<<4096 + 2048, 256, 0, stream>>>(x, Wq, Wk, Wv, Wo, xh, xl, WTh, WTl);

  gemm_split<0><<<dim3(64, 12), 256, 0, stream>>>(
      xh, xl, WTh, WTl, bq, bk, bv, q, kbuf, vbuf);

  sampled_qk_kernel<<<2048, 256, 0, stream>>>(q, kbuf, idx, Mbuf);
  topk_kernel<<<BH, 64, 0, stream>>>(Mbuf, M_top);
  vmean_kernel<<<BH, 256, 0, stream>>>(vbuf, vmean);

  fused_attn_kernel<<<dim3(32, BH), 256, 0, stream>>>(q, kbuf, vbuf, M_top, pm, ps, partial);

  hipMemsetAsync(map, 0xFF, BH * Nn * sizeof(int), stream);
  combine_lite<<<BH * Uu, 64, 0, stream>>>(pm, ps, partial, vmean, M_top, dvh, dvl, map);

  gemm_split<1><<<dim3(10, 4), 256, 0, stream>>>(
      dvh, dvl, WTh + (size_t)1536 * 512, WTl + (size_t)1536 * 512,
      nullptr, nullptr, nullptr, dout, nullptr, nullptr);

  base_kernel<<<Bb, 256, 0, stream>>>(vmean, Wo, bo, base);
  assemble_kernel<<<M_ROWS / 4, 256, 0, stream>>>(base, map, dout, out);
}

// Round 9
// 224.086 us; speedup vs baseline: 2.5753x; 1.1658x over previous
//
#include <hip/hip_runtime.h>
#include <math.h>

namespace {

constexpr int Bb = 4, Nn = 2048, Cc = 512, Hh = 8, Dd = 64, Ss = 40, Uu = 40;
constexpr int M_ROWS = Bb * Nn; // 8192
constexpr int BH = Bb * Hh;     // 32

typedef __attribute__((ext_vector_type(8))) short short8;
typedef __attribute__((ext_vector_type(4))) float f32x4;

__device__ inline unsigned short f2bf(float f) {
  union { float f; unsigned u; } v; v.f = f;
  unsigned r = (v.u + 0x7fffu + ((v.u >> 16) & 1u)) >> 16;
  return (unsigned short)r;
}
__device__ inline float bf2f(unsigned short h) {
  union { unsigned u; float f; } v; v.u = ((unsigned)h) << 16;
  return v.f;
}

// ---------- split x into bf16 hi/lo AND build transposed split weights ----------
// Blocks 0..4095: x split. Blocks 4096..4351: W transpose via LDS 64x64 tiles.
// WT rows 0..511: Wq^T, 512..1023: Wk^T, 1024..1535: Wv^T, 1536..2047: Wo^T.
__global__ __launch_bounds__(256) void convert_all(
    const float* __restrict__ x, const float* __restrict__ Wq,
    const float* __restrict__ Wk, const float* __restrict__ Wv,
    const float* __restrict__ Wo,
    unsigned short* __restrict__ xh, unsigned short* __restrict__ xl,
    unsigned short* __restrict__ WTh, unsigned short* __restrict__ WTl)
{
  if (blockIdx.x < 4096) {
    size_t i = ((size_t)blockIdx.x * 256 + threadIdx.x) * 4;
    float4 v = *(const float4*)(x + i);
    ushort4 h, l;
    h.x = f2bf(v.x); l.x = f2bf(v.x - bf2f(h.x));
    h.y = f2bf(v.y); l.y = f2bf(v.y - bf2f(h.y));
    h.z = f2bf(v.z); l.z = f2bf(v.z - bf2f(h.z));
    h.w = f2bf(v.w); l.w = f2bf(v.w - bf2f(h.w));
    *(ushort4*)(xh + i) = h;
    *(ushort4*)(xl + i) = l;
  } else {
    int wb = blockIdx.x - 4096;       // 0..255
    int which = wb >> 6;
    int tile = wb & 63;
    int tr = tile >> 3, tc = tile & 7; // 8x8 tiles of 64x64
    const float* Wsrc = which == 0 ? Wq : (which == 1 ? Wk : (which == 2 ? Wv : Wo));
    __shared__ float tileS[64][65];
    int t = threadIdx.x;
    int r0 = t >> 4;           // 0..15
    int c0 = (t & 15) * 4;     // 0..60
    #pragma unroll
    for (int i = 0; i < 4; ++i) {
      int r = r0 + i * 16;
      float4 v = *(const float4*)(Wsrc + (size_t)(tr * 64 + r) * 512 + tc * 64 + c0);
      tileS[r][c0] = v.x; tileS[r][c0 + 1] = v.y;
      tileS[r][c0 + 2] = v.z; tileS[r][c0 + 3] = v.w;
    }
    __syncthreads();
    #pragma unroll
    for (int i = 0; i < 4; ++i) {
      int c = r0 + i * 16;  // col of W = row of WT (local)
      float4 v = make_float4(tileS[c0][c], tileS[c0 + 1][c],
                             tileS[c0 + 2][c], tileS[c0 + 3][c]);
      ushort4 hh, ll;
      hh.x = f2bf(v.x); ll.x = f2bf(v.x - bf2f(hh.x));
      hh.y = f2bf(v.y); ll.y = f2bf(v.y - bf2f(hh.y));
      hh.z = f2bf(v.z); ll.z = f2bf(v.z - bf2f(hh.z));
      hh.w = f2bf(v.w); ll.w = f2bf(v.w - bf2f(hh.w));
      size_t off = (size_t)(which * 512 + tc * 64 + c) * 512 + tr * 64 + c0;
      *(ushort4*)(WTh + off) = hh;
      *(ushort4*)(WTl + off) = ll;
    }
  }
}

// ---------- bf16 split-precision MFMA GEMM, 1-phase, conflict-free swizzle ----------
// LDS[row][p] holds global chunk p ^ ((row>>1)&3); read with same XOR (rule #21).
// MODE 0: QKV projection, grid (64,12); MODE 1: plain C[M][512], grid (M/128,4).
template<int MODE>
__global__ __launch_bounds__(256) void gemm_split(
    const unsigned short* __restrict__ xh, const unsigned short* __restrict__ xl,
    const unsigned short* __restrict__ WThp, const unsigned short* __restrict__ WTlp,
    const float* __restrict__ bq, const float* __restrict__ bk, const float* __restrict__ bv,
    float* __restrict__ o0, float* __restrict__ o1, float* __restrict__ o2)
{
  __shared__ __align__(16) unsigned short Ah[128 * 32];
  __shared__ __align__(16) unsigned short Al[128 * 32];
  __shared__ __align__(16) unsigned short Bh[128 * 32];
  __shared__ __align__(16) unsigned short Bl[128 * 32];
  int tid = threadIdx.x;
  int lane = tid & 63, w = tid >> 6;
  int bm = blockIdx.x * 128, bn = blockIdx.y * 128;

  f32x4 acc[4][4];
  #pragma unroll
  for (int i = 0; i < 4; ++i)
    #pragma unroll
    for (int j = 0; j < 4; ++j)
      #pragma unroll
      for (int r = 0; r < 4; ++r) acc[i][j][r] = 0.f;

  int wm = (w >> 1) * 64, wn = (w & 1) * 64;
  int lm = lane & 15, lg = lane >> 4;

  int srow = lane >> 2;
  int row0 = w * 16 + srow;
  int row1 = row0 + 64;
  int cs0 = (lane & 3) ^ ((row0 >> 1) & 3);
  int cs1 = (lane & 3) ^ ((row1 >> 1) & 3);
  size_t a0 = (size_t)(bm + row0) * 512 + cs0 * 8;
  size_t a1 = (size_t)(bm + row1) * 512 + cs1 * 8;
  size_t b0 = (size_t)(bn + row0) * 512 + cs0 * 8;
  size_t b1 = (size_t)(bn + row1) * 512 + cs1 * 8;
  unsigned d0 = w * 1024;

#define GLDS(gp, lp) __builtin_amdgcn_global_load_lds( \
    (const __attribute__((address_space(1))) void*)(gp), \
    (__attribute__((address_space(3))) void*)(lp), 16, 0, 0)

  for (int kt = 0; kt < 16; ++kt) {
    int k0 = kt * 32;
    GLDS(xh   + a0 + k0, (char*)Ah + d0);
    GLDS(xh   + a1 + k0, (char*)Ah + 4096 + d0);
    GLDS(xl   + a0 + k0, (char*)Al + d0);
    GLDS(xl   + a1 + k0, (char*)Al + 4096 + d0);
    GLDS(WThp + b0 + k0, (char*)Bh + d0);
    GLDS(WThp + b1 + k0, (char*)Bh + 4096 + d0);
    GLDS(WTlp + b0 + k0, (char*)Bl + d0);
    GLDS(WTlp + b1 + k0, (char*)Bl + 4096 + d0);
    __syncthreads();

    short8 afh[4], bgh[4], afl[4], bgl[4];
    #pragma unroll
    for (int i = 0; i < 4; ++i) {
      int R = wm + i * 16 + lm;
      afh[i] = *(const short8*)(Ah + R * 32 + ((lg ^ ((R >> 1) & 3)) * 8));
    }
    #pragma unroll
    for (int j = 0; j < 4; ++j) {
      int R = wn + j * 16 + lm;
      bgh[j] = *(const short8*)(Bh + R * 32 + ((lg ^ ((R >> 1) & 3)) * 8));
    }
    #pragma unroll
    for (int i = 0; i < 4; ++i)
      #pragma unroll
      for (int j = 0; j < 4; ++j)
        acc[i][j] = __builtin_amdgcn_mfma_f32_16x16x32_bf16(afh[i], bgh[j], acc[i][j], 0, 0, 0);

    #pragma unroll
    for (int i = 0; i < 4; ++i) {
      int R = wm + i * 16 + lm;
      afl[i] = *(const short8*)(Al + R * 32 + ((lg ^ ((R >> 1) & 3)) * 8));
    }
    #pragma unroll
    for (int i = 0; i < 4; ++i)
      #pragma unroll
      for (int j = 0; j < 4; ++j)
        acc[i][j] = __builtin_amdgcn_mfma_f32_16x16x32_bf16(afl[i], bgh[j], acc[i][j], 0, 0, 0);

    #pragma unroll
    for (int j = 0; j < 4; ++j) {
      int R = wn + j * 16 + lm;
      bgl[j] = *(const short8*)(Bl + R * 32 + ((lg ^ ((R >> 1) & 3)) * 8));
    }
    #pragma unroll
    for (int i = 0; i < 4; ++i)
      #pragma unroll
      for (int j = 0; j < 4; ++j)
        acc[i][j] = __builtin_amdgcn_mfma_f32_16x16x32_bf16(afh[i], bgl[j], acc[i][j], 0, 0, 0);

    __syncthreads();
  }
#undef GLDS

  if (MODE == 0) {
    #pragma unroll
    for (int j = 0; j < 4; ++j) {
      int n = bn + wn + j * 16 + lm;
      float bias = n < 512 ? bq[n] : (n < 1024 ? bk[n - 512] : bv[n - 1024]);
      int tensor = n >> 9, h = (n >> 6) & 7, d = n & 63;
      float* op = tensor == 0 ? o0 : (tensor == 1 ? o1 : o2);
      #pragma unroll
      for (int i = 0; i < 4; ++i) {
        #pragma unroll
        for (int r = 0; r < 4; ++r) {
          int m = bm + wm + i * 16 + lg * 4 + r;
          int b = m >> 11, nn = m & 2047;
          op[((size_t)(b * Hh + h) * Nn + nn) * Dd + d] = acc[i][j][r] + bias;
        }
      }
    }
  } else {
    #pragma unroll
    for (int j = 0; j < 4; ++j) {
      int n = bn + wn + j * 16 + lm;
      #pragma unroll
      for (int i = 0; i < 4; ++i) {
        #pragma unroll
        for (int r = 0; r < 4; ++r) {
          int m = bm + wm + i * 16 + lg * 4 + r;
          o0[(size_t)m * 512 + n] = acc[i][j][r];
        }
      }
    }
  }
}

// ---------- sampled QK^T -> M, bh-pinned to XCDs, high occupancy ----------
__global__ __launch_bounds__(256) void sampled_qk_kernel(
    const float* __restrict__ q, const float* __restrict__ k,
    const int* __restrict__ idx, float* __restrict__ Mout)
{
  int p = blockIdx.x;
  int xcd = p & 7, j = p >> 3;
  int chunk = j & 63;
  int bh = (j >> 6) * 8 + xcd;
  int t = threadIdx.x;
  int w = t >> 6, lane = t & 63;
  int g = lane >> 2, dq = lane & 3;

  const float* kb = k + (size_t)bh * Nn * Dd;

  for (int li = 0; li < 8; ++li) {
    int l = chunk * 32 + w * 8 + li;
    const float* qrow = q + ((size_t)bh * Nn + l) * Dd + dq * 4;
    float4 qv[4];
    #pragma unroll
    for (int i = 0; i < 4; ++i) qv[i] = *(const float4*)(qrow + i * 16);
    float mx = -INFINITY, sm = 0.f;
    #pragma unroll
    for (int pass = 0; pass < 3; ++pass) {
      int s = pass * 16 + g;
      bool valid = (s < Ss);
      float dot = 0.f;
      if (valid) {
        int kr = idx[l * Ss + s];
        const float* krow = kb + (size_t)kr * Dd + dq * 4;
        #pragma unroll
        for (int i = 0; i < 4; ++i) {
          float4 kv = *(const float4*)(krow + i * 16);
          dot += kv.x * qv[i].x + kv.y * qv[i].y + kv.z * qv[i].z + kv.w * qv[i].w;
        }
      }
      dot += __shfl_xor(dot, 1);
      dot += __shfl_xor(dot, 2);
      if (valid) { mx = fmaxf(mx, dot); sm += dot; }
    }
    #pragma unroll
    for (int o = 4; o < 64; o <<= 1) {
      mx = fmaxf(mx, __shfl_xor(mx, o));
      sm += __shfl_xor(sm, o);
    }
    if (lane == 0) Mout[(size_t)bh * Nn + l] = mx - sm * (1.f / (float)Nn);
  }
}

// ---------- top-40 per (b,h): single wave, register-resident ----------
__global__ __launch_bounds__(64) void topk_kernel(
    const float* __restrict__ Min, int* __restrict__ M_top)
{
  int bh = blockIdx.x, lane = threadIdx.x;
  const float* row = Min + (size_t)bh * Nn;
  float v[32];
  #pragma unroll
  for (int j = 0; j < 32; ++j) v[j] = row[j * 64 + lane];
  unsigned mask = 0;
  for (int it = 0; it < Uu; ++it) {
    float best = -INFINITY; int bidx = 0x7FFFFFFF;
    #pragma unroll
    for (int j = 0; j < 32; ++j) {
      if (!((mask >> j) & 1u) && v[j] > best) { best = v[j]; bidx = j * 64 + lane; }
    }
    #pragma unroll
    for (int o = 32; o; o >>= 1) {
      float ov = __shfl_xor(best, o);
      int oi = __shfl_xor(bidx, o);
      if (ov > best || (ov == best && oi < bidx)) { best = ov; bidx = oi; }
    }
    if ((bidx & 63) == lane) mask |= 1u << (bidx >> 6);
    if (lane == 0) M_top[bh * Uu + it] = bidx;
  }
}

// ---------- mean of V over N per (b,h,d); also init map to -1 ----------
__global__ __launch_bounds__(256) void vmean_kernel(
    const float* __restrict__ v, float* __restrict__ vmean, int* __restrict__ map)
{
  int bh = blockIdx.x, t = threadIdx.x;
  for (int i = t; i < Nn; i += 256) map[bh * Nn + i] = -1;
  int d = t & 63, chunk = t >> 6;
  const float* base = v + (size_t)bh * Nn * Dd;
  float s = 0.f;
  for (int n = chunk * 512; n < (chunk + 1) * 512; ++n) s += base[(size_t)n * Dd + d];
  __shared__ float part[4][64];
  part[chunk][d] = s;
  __syncthreads();
  if (t < 64)
    vmean[bh * Dd + t] = (part[0][t] + part[1][t] + part[2][t] + part[3][t]) * (1.f / (float)Nn);
}

// ---------- fused scores+softmax+PV partials, per (64-col chunk, bh) ----------
__global__ __launch_bounds__(256) void fused_attn_kernel(
    const float* __restrict__ q, const float* __restrict__ k, const float* __restrict__ v,
    const int* __restrict__ M_top, float* __restrict__ pm, float* __restrict__ ps,
    float* __restrict__ partial)
{
  int chunk = blockIdx.x, bh = blockIdx.y, t = threadIdx.x;
  __shared__ float qs[40][64];
  __shared__ float S[40][64];
  if (t < 160) {
    int u = t >> 2, p = (t & 3) * 16;
    int r = M_top[bh * Uu + u];
    const float4* src = (const float4*)(q + ((size_t)bh * Nn + r) * Dd + p);
    *(float4*)&qs[u][p + 0]  = src[0];
    *(float4*)&qs[u][p + 4]  = src[1];
    *(float4*)&qs[u][p + 8]  = src[2];
    *(float4*)&qs[u][p + 12] = src[3];
  }
  __syncthreads();

  int nl = t & 63, w = t >> 6;
  {
    int n = chunk * 64 + nl;
    const float4* krow = (const float4*)(k + ((size_t)bh * Nn + n) * Dd);
    float acc[10];
    #pragma unroll
    for (int uu = 0; uu < 10; ++uu) acc[uu] = 0.f;
    #pragma unroll
    for (int d4 = 0; d4 < 16; ++d4) {
      float4 kv = krow[d4];
      #pragma unroll
      for (int uu = 0; uu < 10; ++uu) {
        float4 qv = *(const float4*)&qs[w * 10 + uu][d4 * 4];
        acc[uu] += qv.x * kv.x + qv.y * kv.y + qv.z * kv.z + qv.w * kv.w;
      }
    }
    #pragma unroll
    for (int uu = 0; uu < 10; ++uu) S[w * 10 + uu][nl] = acc[uu] * 0.125f;
  }

  #pragma unroll
  for (int r = 0; r < 10; ++r) {
    int u = w * 10 + r;
    float v0 = S[u][nl];
    float m = v0;
    #pragma unroll
    for (int o = 1; o < 64; o <<= 1) m = fmaxf(m, __shfl_xor(m, o));
    float e0 = expf(v0 - m);
    S[u][nl] = e0;
    float sum = e0;
    #pragma unroll
    for (int o = 1; o < 64; o <<= 1) sum += __shfl_xor(sum, o);
    if (nl == 0) {
      pm[(bh * 32 + chunk) * Uu + u] = m;
      ps[(bh * 32 + chunk) * Uu + u] = sum;
    }
  }

  float acc2[10];
  #pragma unroll
  for (int uu = 0; uu < 10; ++uu) acc2[uu] = 0.f;
  const float* vb = v + ((size_t)bh * Nn + chunk * 64) * Dd + nl;
  for (int i = 0; i < 64; ++i) {
    float vv = vb[(size_t)i * Dd];
    #pragma unroll
    for (int uu = 0; uu < 10; ++uu) acc2[uu] = fmaf(S[w * 10 + uu][i], vv, acc2[uu]);
  }
  #pragma unroll
  for (int uu = 0; uu < 10; ++uu) {
    int u = w * 10 + uu;
    partial[(((size_t)bh * Uu + u) * 32 + chunk) * 64 + nl] = acc2[uu];
  }
}

// ---------- combine partials -> dvF rows; blocks >=1280 emit vmean rows ----------
__global__ __launch_bounds__(64) void combine_lite(
    const float* __restrict__ pm, const float* __restrict__ ps,
    const float* __restrict__ partial, const float* __restrict__ vmean,
    const int* __restrict__ M_top,
    unsigned short* __restrict__ dvh, unsigned short* __restrict__ dvl,
    int* __restrict__ map)
{
  int bhu = blockIdx.x;
  int lane = threadIdx.x;

  if (bhu >= BH * Uu) {            // vmean rows for the fused base GEMM
    int b = bhu - BH * Uu;
    #pragma unroll
    for (int cc = 0; cc < 8; ++cc) {
      float v = vmean[(b * 8 + cc) * 64 + lane];
      unsigned short hb = f2bf(v);
      dvh[(size_t)bhu * 512 + cc * 64 + lane] = hb;
      dvl[(size_t)bhu * 512 + cc * 64 + lane] = f2bf(v - bf2f(hb));
    }
    return;
  }

  int bh = bhu / Uu, u = bhu % Uu, h = bh & 7;
  float pmv[32];
  float m = -INFINITY;
  #pragma unroll
  for (int c = 0; c < 32; ++c) {
    pmv[c] = pm[(bh * 32 + c) * Uu + u];
    m = fmaxf(m, pmv[c]);
  }
  float w32[32], Z = 0.f;
  #pragma unroll
  for (int c = 0; c < 32; ++c) {
    w32[c] = expf(pmv[c] - m);
    Z += w32[c] * ps[(bh * 32 + c) * Uu + u];
  }

  const float* pb = partial + (size_t)bhu * 2048;
  float s = 0.f;
  #pragma unroll
  for (int c = 0; c < 32; ++c)
    s = fmaf(pb[c * 64 + lane], w32[c], s);

  float dv = s / Z - vmean[bh * Dd + lane];
  unsigned short hbits = f2bf(dv);
  unsigned short lbits = f2bf(dv - bf2f(hbits));

  #pragma unroll
  for (int cc = 0; cc < 8; ++cc) {
    int c = cc * 64 + lane;
    bool mine = (cc == h);
    dvh[(size_t)bhu * 512 + c] = mine ? hbits : (unsigned short)0;
    dvl[(size_t)bhu * 512 + c] = mine ? lbits : (unsigned short)0;
  }
  if (lane == 0) map[bh * Nn + M_top[bhu]] = bhu;
}

// ---------- assemble out rows (base = dout row 1280+b, + bo) ----------
__global__ __launch_bounds__(256) void assemble_kernel(
    const int* __restrict__ map, const float* __restrict__ dout,
    const float* __restrict__ bo, float* __restrict__ out)
{
  int t = threadIdx.x;
  int row = blockIdx.x * 4 + (t >> 6);
  int lane = t & 63;
  int b = row >> 11, n = row & 2047;
  const float* bp = dout + (size_t)(BH * Uu + b) * 512;
  float4 a0 = *(const float4*)(bp + lane * 4);
  float4 a1 = *(const float4*)(bp + 256 + lane * 4);
  float4 o0 = *(const float4*)(bo + lane * 4);
  float4 o1 = *(const float4*)(bo + 256 + lane * 4);
  a0.x += o0.x; a0.y += o0.y; a0.z += o0.z; a0.w += o0.w;
  a1.x += o1.x; a1.y += o1.y; a1.z += o1.z; a1.w += o1.w;
  for (int h = 0; h < 8; ++h) {
    int mi = map[(b * Hh + h) * Nn + n];
    if (mi >= 0) {
      const float* dp = dout + (size_t)mi * 512;
      float4 d0 = *(const float4*)(dp + lane * 4);
      float4 d1 = *(const float4*)(dp + 256 + lane * 4);
      a0.x += d0.x; a0.y += d0.y; a0.z += d0.z; a0.w += d0.w;
      a1.x += d1.x; a1.y += d1.y; a1.z += d1.z; a1.w += d1.w;
    }
  }
  *(float4*)(out + (size_t)row * 512 + lane * 4) = a0;
  *(float4*)(out + (size_t)row * 512 + 256 + lane * 4) = a1;
}

} // namespace

extern "C" void kernel_launch(void* const* d_in, const int* in_sizes, int n_in,
                              void* d_out, int out_size, void* d_ws, size_t ws_size,
                              hipStream_t stream) {
  const float* x  = (const float*)d_in[0];
  const float* Wq = (const float*)d_in[1];
  const float* bq = (const float*)d_in[2];
  const float* Wk = (const float*)d_in[3];
  const float* bk = (const float*)d_in[4];
  const float* Wv = (const float*)d_in[5];
  const float* bv = (const float*)d_in[6];
  const float* Wo = (const float*)d_in[7];
  const float* bo = (const float*)d_in[8];
  const int* idx  = (const int*)d_in[9];
  float* out = (float*)d_out;

  // dv/dout rows: 1280 attn rows + 4 vmean rows, padded to 1408 (= 11*128)
  constexpr int DV_ROWS = 1408;

  float* ws = (float*)d_ws;
  float* q      = ws;                       // 4,194,304 f
  float* kbuf   = ws + 4194304;
  float* vbuf   = ws + 8388608;
  float* Mbuf   = ws + 12582912;            // 65,536 f
  float* vmean  = ws + 12648448;            // 2,048 f
  float* pm     = ws + 12650496;            // 40,960 f [32][32][40]
  float* ps     = ws + 12691456;            // 40,960 f
  float* dout   = ws + 12732416;            // 720,896 f [1408][512]
  int*   M_top  = (int*)(ws + 13453312);    // 1,280
  int*   map    = (int*)(ws + 13454592);    // 65,536
  unsigned short* dvh = (unsigned short*)(ws + 13520128); // 1408*512 u16 (360,448 f)
  unsigned short* dvl = (unsigned short*)(ws + 13880576);
  unsigned short* xh  = (unsigned short*)(ws + 14241024); // 8192*512 u16
  unsigned short* xl  = (unsigned short*)(ws + 16338176);
  unsigned short* WTh = (unsigned short*)(ws + 18435328); // 2048*512 u16
  unsigned short* WTl = (unsigned short*)(ws + 18959616); // ends 19,483,904 f
  float* partial = ws + 14241024;           // overlays xh/xl after gemm<0> (2,621,440 f)

  convert_all<<<4096 + 256, 256, 0, stream>>>(x, Wq, Wk, Wv, Wo, xh, xl, WTh, WTl);

  gemm_split<0><<<dim3(64, 12), 256, 0, stream>>>(
      xh, xl, WTh, WTl, bq, bk, bv, q, kbuf, vbuf);

  sampled_qk_kernel<<<2048, 256, 0, stream>>>(q, kbuf, idx, Mbuf);
  topk_kernel<<<BH, 64, 0, stream>>>(Mbuf, M_top);
  vmean_kernel<<<BH, 256, 0, stream>>>(vbuf, vmean, map);

  fused_attn_kernel<<<dim3(32, BH), 256, 0, stream>>>(q, kbuf, vbuf, M_top, pm, ps, partial);

  combine_lite<<<BH * Uu + Bb, 64, 0, stream>>>(pm, ps, partial, vmean, M_top, dvh, dvl, map);

  gemm_split<1><<<dim3(DV_ROWS / 128, 4), 256, 0, stream>>>(
      dvh, dvl, WTh + (size_t)1536 * 512, WTl + (size_t)1536 * 512,
      nullptr, nullptr, nullptr, dout, nullptr, nullptr);

  assemble_kernel<<<M_ROWS / 4, 256, 0, stream>>>(map, dout, bo, out);
}

// Round 10
// 208.646 us; speedup vs baseline: 2.7659x; 1.0740x over previous
//
#include <hip/hip_runtime.h>
#include <math.h>

namespace {

constexpr int Bb = 4, Nn = 2048, Cc = 512, Hh = 8, Dd = 64, Ss = 40, Uu = 40;
constexpr int M_ROWS = Bb * Nn; // 8192
constexpr int BH = Bb * Hh;     // 32
constexpr int DV_ROWS = 1536;   // 1280 attn rows + 4 vmean rows, padded to 6*256

typedef __attribute__((ext_vector_type(8))) short short8;
typedef __attribute__((ext_vector_type(4))) float f32x4;

__device__ inline unsigned short f2bf(float f) {
  union { float f; unsigned u; } v; v.f = f;
  unsigned r = (v.u + 0x7fffu + ((v.u >> 16) & 1u)) >> 16;
  return (unsigned short)r;
}
__device__ inline float bf2f(unsigned short h) {
  union { unsigned u; float f; } v; v.u = ((unsigned)h) << 16;
  return v.f;
}

// ---------- split x into bf16 hi/lo AND build transposed split weights ----------
__global__ __launch_bounds__(256) void convert_all(
    const float* __restrict__ x, const float* __restrict__ Wq,
    const float* __restrict__ Wk, const float* __restrict__ Wv,
    const float* __restrict__ Wo,
    unsigned short* __restrict__ xh, unsigned short* __restrict__ xl,
    unsigned short* __restrict__ WTh, unsigned short* __restrict__ WTl)
{
  if (blockIdx.x < 4096) {
    size_t i = ((size_t)blockIdx.x * 256 + threadIdx.x) * 4;
    float4 v = *(const float4*)(x + i);
    ushort4 h, l;
    h.x = f2bf(v.x); l.x = f2bf(v.x - bf2f(h.x));
    h.y = f2bf(v.y); l.y = f2bf(v.y - bf2f(h.y));
    h.z = f2bf(v.z); l.z = f2bf(v.z - bf2f(h.z));
    h.w = f2bf(v.w); l.w = f2bf(v.w - bf2f(h.w));
    *(ushort4*)(xh + i) = h;
    *(ushort4*)(xl + i) = l;
  } else {
    int wb = blockIdx.x - 4096;       // 0..255
    int which = wb >> 6;
    int tile = wb & 63;
    int tr = tile >> 3, tc = tile & 7;
    const float* Wsrc = which == 0 ? Wq : (which == 1 ? Wk : (which == 2 ? Wv : Wo));
    __shared__ float tileS[64][65];
    int t = threadIdx.x;
    int r0 = t >> 4;
    int c0 = (t & 15) * 4;
    #pragma unroll
    for (int i = 0; i < 4; ++i) {
      int r = r0 + i * 16;
      float4 v = *(const float4*)(Wsrc + (size_t)(tr * 64 + r) * 512 + tc * 64 + c0);
      tileS[r][c0] = v.x; tileS[r][c0 + 1] = v.y;
      tileS[r][c0 + 2] = v.z; tileS[r][c0 + 3] = v.w;
    }
    __syncthreads();
    #pragma unroll
    for (int i = 0; i < 4; ++i) {
      int c = r0 + i * 16;
      float4 v = make_float4(tileS[c0][c], tileS[c0 + 1][c],
                             tileS[c0 + 2][c], tileS[c0 + 3][c]);
      ushort4 hh, ll;
      hh.x = f2bf(v.x); ll.x = f2bf(v.x - bf2f(hh.x));
      hh.y = f2bf(v.y); ll.y = f2bf(v.y - bf2f(hh.y));
      hh.z = f2bf(v.z); ll.z = f2bf(v.z - bf2f(hh.z));
      hh.w = f2bf(v.w); ll.w = f2bf(v.w - bf2f(hh.w));
      size_t off = (size_t)(which * 512 + tc * 64 + c) * 512 + tr * 64 + c0;
      *(ushort4*)(WTh + off) = hh;
      *(ushort4*)(WTl + off) = ll;
    }
  }
}

// ---------- bf16 split-precision MFMA GEMM, 256x128 tile, 512 threads ----------
// 8 waves in 4x2 grid; per wave 64x64 output (acc 4x4 f32x4). Per K-step (32):
// A (256x32) = 2 GLDS issues, B (128x32) = 1 each for Bh/Bl -> 6 issues.
// Swizzle: LDS slot p of row r holds global chunk p ^ ((r>>1)&3); note
// ((r+128)>>1)&3 == (r>>1)&3 so both A issues share one cs. Conflicts = 0 (R9).
// MODE 0: QKV projection, grid (32,12); MODE 1: plain C[1536][512], grid (6,4).
template<int MODE>
__global__ __launch_bounds__(512) void gemm_split(
    const unsigned short* __restrict__ xh, const unsigned short* __restrict__ xl,
    const unsigned short* __restrict__ WThp, const unsigned short* __restrict__ WTlp,
    const float* __restrict__ bq, const float* __restrict__ bk, const float* __restrict__ bv,
    float* __restrict__ o0, float* __restrict__ o1, float* __restrict__ o2)
{
  __shared__ __align__(16) unsigned short Ah[256 * 32];
  __shared__ __align__(16) unsigned short Al[256 * 32];
  __shared__ __align__(16) unsigned short Bh[128 * 32];
  __shared__ __align__(16) unsigned short Bl[128 * 32];
  int tid = threadIdx.x;
  int lane = tid & 63, w = tid >> 6;
  int bm = blockIdx.x * 256, bn = blockIdx.y * 128;

  f32x4 acc[4][4];
  #pragma unroll
  for (int i = 0; i < 4; ++i)
    #pragma unroll
    for (int j = 0; j < 4; ++j)
      #pragma unroll
      for (int r = 0; r < 4; ++r) acc[i][j][r] = 0.f;

  int wm = (w >> 1) * 64, wn = (w & 1) * 64;
  int lm = lane & 15, lg = lane >> 4;

  int srow = tid >> 2;                       // 0..127
  int cs = (tid & 3) ^ ((srow >> 1) & 3);    // pre-swizzled source chunk
  size_t a0 = (size_t)(bm + srow) * 512 + cs * 8;
  size_t a1 = a0 + (size_t)128 * 512;
  size_t b0 = (size_t)(bn + srow) * 512 + cs * 8;
  unsigned d0 = w * 1024;

#define GLDS(gp, lp) __builtin_amdgcn_global_load_lds( \
    (const __attribute__((address_space(1))) void*)(gp), \
    (__attribute__((address_space(3))) void*)(lp), 16, 0, 0)

  for (int kt = 0; kt < 16; ++kt) {
    int k0 = kt * 32;
    GLDS(xh   + a0 + k0, (char*)Ah + d0);
    GLDS(xh   + a1 + k0, (char*)Ah + 8192 + d0);
    GLDS(xl   + a0 + k0, (char*)Al + d0);
    GLDS(xl   + a1 + k0, (char*)Al + 8192 + d0);
    GLDS(WThp + b0 + k0, (char*)Bh + d0);
    GLDS(WTlp + b0 + k0, (char*)Bl + d0);
    __syncthreads();

    short8 afh[4], bgh[4], afl[4], bgl[4];
    #pragma unroll
    for (int i = 0; i < 4; ++i) {
      int R = wm + i * 16 + lm;
      afh[i] = *(const short8*)(Ah + R * 32 + ((lg ^ ((R >> 1) & 3)) * 8));
    }
    #pragma unroll
    for (int j = 0; j < 4; ++j) {
      int R = wn + j * 16 + lm;
      bgh[j] = *(const short8*)(Bh + R * 32 + ((lg ^ ((R >> 1) & 3)) * 8));
    }
    #pragma unroll
    for (int i = 0; i < 4; ++i)
      #pragma unroll
      for (int j = 0; j < 4; ++j)
        acc[i][j] = __builtin_amdgcn_mfma_f32_16x16x32_bf16(afh[i], bgh[j], acc[i][j], 0, 0, 0);

    #pragma unroll
    for (int i = 0; i < 4; ++i) {
      int R = wm + i * 16 + lm;
      afl[i] = *(const short8*)(Al + R * 32 + ((lg ^ ((R >> 1) & 3)) * 8));
    }
    #pragma unroll
    for (int i = 0; i < 4; ++i)
      #pragma unroll
      for (int j = 0; j < 4; ++j)
        acc[i][j] = __builtin_amdgcn_mfma_f32_16x16x32_bf16(afl[i], bgh[j], acc[i][j], 0, 0, 0);

    #pragma unroll
    for (int j = 0; j < 4; ++j) {
      int R = wn + j * 16 + lm;
      bgl[j] = *(const short8*)(Bl + R * 32 + ((lg ^ ((R >> 1) & 3)) * 8));
    }
    #pragma unroll
    for (int i = 0; i < 4; ++i)
      #pragma unroll
      for (int j = 0; j < 4; ++j)
        acc[i][j] = __builtin_amdgcn_mfma_f32_16x16x32_bf16(afh[i], bgl[j], acc[i][j], 0, 0, 0);

    __syncthreads();
  }
#undef GLDS

  if (MODE == 0) {
    #pragma unroll
    for (int j = 0; j < 4; ++j) {
      int n = bn + wn + j * 16 + lm;
      float bias = n < 512 ? bq[n] : (n < 1024 ? bk[n - 512] : bv[n - 1024]);
      int tensor = n >> 9, h = (n >> 6) & 7, d = n & 63;
      float* op = tensor == 0 ? o0 : (tensor == 1 ? o1 : o2);
      #pragma unroll
      for (int i = 0; i < 4; ++i) {
        #pragma unroll
        for (int r = 0; r < 4; ++r) {
          int m = bm + wm + i * 16 + lg * 4 + r;
          int b = m >> 11, nn = m & 2047;
          op[((size_t)(b * Hh + h) * Nn + nn) * Dd + d] = acc[i][j][r] + bias;
        }
      }
    }
  } else {
    #pragma unroll
    for (int j = 0; j < 4; ++j) {
      int n = bn + wn + j * 16 + lm;
      #pragma unroll
      for (int i = 0; i < 4; ++i) {
        #pragma unroll
        for (int r = 0; r < 4; ++r) {
          int m = bm + wm + i * 16 + lg * 4 + r;
          o0[(size_t)m * 512 + n] = acc[i][j][r];
        }
      }
    }
  }
}

// ---------- sampled QK^T -> M (blocks 0..2047) + vmean/map-init (2048..2079) ----------
__global__ __launch_bounds__(256) void sampled_vmean_kernel(
    const float* __restrict__ q, const float* __restrict__ k,
    const int* __restrict__ idx, float* __restrict__ Mout,
    const float* __restrict__ v, float* __restrict__ vmean, int* __restrict__ map)
{
  int p = blockIdx.x;
  int t = threadIdx.x;
  if (p >= 2048) {
    // vmean for bh = p - 2048, plus map init
    int bh = p - 2048;
    for (int i = t; i < Nn; i += 256) map[bh * Nn + i] = -1;
    int d = t & 63, chunk = t >> 6;
    const float* base = v + (size_t)bh * Nn * Dd;
    float s = 0.f;
    for (int n = chunk * 512; n < (chunk + 1) * 512; ++n) s += base[(size_t)n * Dd + d];
    __shared__ float part[4][64];
    part[chunk][d] = s;
    __syncthreads();
    if (t < 64)
      vmean[bh * Dd + t] = (part[0][t] + part[1][t] + part[2][t] + part[3][t]) * (1.f / (float)Nn);
    return;
  }
  int xcd = p & 7, j = p >> 3;
  int chunk = j & 63;
  int bh = (j >> 6) * 8 + xcd;
  int w = t >> 6, lane = t & 63;
  int g = lane >> 2, dq = lane & 3;

  const float* kb = k + (size_t)bh * Nn * Dd;

  for (int li = 0; li < 8; ++li) {
    int l = chunk * 32 + w * 8 + li;
    const float* qrow = q + ((size_t)bh * Nn + l) * Dd + dq * 4;
    float4 qv[4];
    #pragma unroll
    for (int i = 0; i < 4; ++i) qv[i] = *(const float4*)(qrow + i * 16);
    float mx = -INFINITY, sm = 0.f;
    #pragma unroll
    for (int pass = 0; pass < 3; ++pass) {
      int s = pass * 16 + g;
      bool valid = (s < Ss);
      float dot = 0.f;
      if (valid) {
        int kr = idx[l * Ss + s];
        const float* krow = kb + (size_t)kr * Dd + dq * 4;
        #pragma unroll
        for (int i = 0; i < 4; ++i) {
          float4 kv = *(const float4*)(krow + i * 16);
          dot += kv.x * qv[i].x + kv.y * qv[i].y + kv.z * qv[i].z + kv.w * qv[i].w;
        }
      }
      dot += __shfl_xor(dot, 1);
      dot += __shfl_xor(dot, 2);
      if (valid) { mx = fmaxf(mx, dot); sm += dot; }
    }
    #pragma unroll
    for (int o = 4; o < 64; o <<= 1) {
      mx = fmaxf(mx, __shfl_xor(mx, o));
      sm += __shfl_xor(sm, o);
    }
    if (lane == 0) Mout[(size_t)bh * Nn + l] = mx - sm * (1.f / (float)Nn);
  }
}

// ---------- top-40 per (b,h): single wave, register-resident ----------
__global__ __launch_bounds__(64) void topk_kernel(
    const float* __restrict__ Min, int* __restrict__ M_top)
{
  int bh = blockIdx.x, lane = threadIdx.x;
  const float* row = Min + (size_t)bh * Nn;
  float v[32];
  #pragma unroll
  for (int j = 0; j < 32; ++j) v[j] = row[j * 64 + lane];
  unsigned mask = 0;
  for (int it = 0; it < Uu; ++it) {
    float best = -INFINITY; int bidx = 0x7FFFFFFF;
    #pragma unroll
    for (int j = 0; j < 32; ++j) {
      if (!((mask >> j) & 1u) && v[j] > best) { best = v[j]; bidx = j * 64 + lane; }
    }
    #pragma unroll
    for (int o = 32; o; o >>= 1) {
      float ov = __shfl_xor(best, o);
      int oi = __shfl_xor(bidx, o);
      if (ov > best || (ov == best && oi < bidx)) { best = ov; bidx = oi; }
    }
    if ((bidx & 63) == lane) mask |= 1u << (bidx >> 6);
    if (lane == 0) M_top[bh * Uu + it] = bidx;
  }
}

// ---------- fused scores+softmax+PV partials, per (64-col chunk, bh) ----------
__global__ __launch_bounds__(256) void fused_attn_kernel(
    const float* __restrict__ q, const float* __restrict__ k, const float* __restrict__ v,
    const int* __restrict__ M_top, float* __restrict__ pm, float* __restrict__ ps,
    float* __restrict__ partial)
{
  int chunk = blockIdx.x, bh = blockIdx.y, t = threadIdx.x;
  __shared__ float qs[40][64];
  __shared__ float S[40][64];
  if (t < 160) {
    int u = t >> 2, p = (t & 3) * 16;
    int r = M_top[bh * Uu + u];
    const float4* src = (const float4*)(q + ((size_t)bh * Nn + r) * Dd + p);
    *(float4*)&qs[u][p + 0]  = src[0];
    *(float4*)&qs[u][p + 4]  = src[1];
    *(float4*)&qs[u][p + 8]  = src[2];
    *(float4*)&qs[u][p + 12] = src[3];
  }
  __syncthreads();

  int nl = t & 63, w = t >> 6;
  {
    int n = chunk * 64 + nl;
    const float4* krow = (const float4*)(k + ((size_t)bh * Nn + n) * Dd);
    float acc[10];
    #pragma unroll
    for (int uu = 0; uu < 10; ++uu) acc[uu] = 0.f;
    #pragma unroll
    for (int d4 = 0; d4 < 16; ++d4) {
      float4 kv = krow[d4];
      #pragma unroll
      for (int uu = 0; uu < 10; ++uu) {
        float4 qv = *(const float4*)&qs[w * 10 + uu][d4 * 4];
        acc[uu] += qv.x * kv.x + qv.y * kv.y + qv.z * kv.z + qv.w * kv.w;
      }
    }
    #pragma unroll
    for (int uu = 0; uu < 10; ++uu) S[w * 10 + uu][nl] = acc[uu] * 0.125f;
  }

  #pragma unroll
  for (int r = 0; r < 10; ++r) {
    int u = w * 10 + r;
    float v0 = S[u][nl];
    float m = v0;
    #pragma unroll
    for (int o = 1; o < 64; o <<= 1) m = fmaxf(m, __shfl_xor(m, o));
    float e0 = expf(v0 - m);
    S[u][nl] = e0;
    float sum = e0;
    #pragma unroll
    for (int o = 1; o < 64; o <<= 1) sum += __shfl_xor(sum, o);
    if (nl == 0) {
      pm[(bh * 32 + chunk) * Uu + u] = m;
      ps[(bh * 32 + chunk) * Uu + u] = sum;
    }
  }

  float acc2[10];
  #pragma unroll
  for (int uu = 0; uu < 10; ++uu) acc2[uu] = 0.f;
  const float* vb = v + ((size_t)bh * Nn + chunk * 64) * Dd + nl;
  for (int i = 0; i < 64; ++i) {
    float vv = vb[(size_t)i * Dd];
    #pragma unroll
    for (int uu = 0; uu < 10; ++uu) acc2[uu] = fmaf(S[w * 10 + uu][i], vv, acc2[uu]);
  }
  #pragma unroll
  for (int uu = 0; uu < 10; ++uu) {
    int u = w * 10 + uu;
    partial[(((size_t)bh * Uu + u) * 32 + chunk) * 64 + nl] = acc2[uu];
  }
}

// ---------- combine partials -> dvF rows; blocks >=1280 emit vmean rows ----------
__global__ __launch_bounds__(64) void combine_lite(
    const float* __restrict__ pm, const float* __restrict__ ps,
    const float* __restrict__ partial, const float* __restrict__ vmean,
    const int* __restrict__ M_top,
    unsigned short* __restrict__ dvh, unsigned short* __restrict__ dvl,
    int* __restrict__ map)
{
  int bhu = blockIdx.x;
  int lane = threadIdx.x;

  if (bhu >= BH * Uu) {            // vmean rows for the fused base GEMM
    int b = bhu - BH * Uu;
    #pragma unroll
    for (int cc = 0; cc < 8; ++cc) {
      float v = vmean[(b * 8 + cc) * 64 + lane];
      unsigned short hb = f2bf(v);
      dvh[(size_t)bhu * 512 + cc * 64 + lane] = hb;
      dvl[(size_t)bhu * 512 + cc * 64 + lane] = f2bf(v - bf2f(hb));
    }
    return;
  }

  int bh = bhu / Uu, u = bhu % Uu, h = bh & 7;
  float pmv[32];
  float m = -INFINITY;
  #pragma unroll
  for (int c = 0; c < 32; ++c) {
    pmv[c] = pm[(bh * 32 + c) * Uu + u];
    m = fmaxf(m, pmv[c]);
  }
  float w32[32], Z = 0.f;
  #pragma unroll
  for (int c = 0; c < 32; ++c) {
    w32[c] = expf(pmv[c] - m);
    Z += w32[c] * ps[(bh * 32 + c) * Uu + u];
  }

  const float* pb = partial + (size_t)bhu * 2048;
  float s = 0.f;
  #pragma unroll
  for (int c = 0; c < 32; ++c)
    s = fmaf(pb[c * 64 + lane], w32[c], s);

  float dv = s / Z - vmean[bh * Dd + lane];
  unsigned short hbits = f2bf(dv);
  unsigned short lbits = f2bf(dv - bf2f(hbits));

  #pragma unroll
  for (int cc = 0; cc < 8; ++cc) {
    int c = cc * 64 + lane;
    bool mine = (cc == h);
    dvh[(size_t)bhu * 512 + c] = mine ? hbits : (unsigned short)0;
    dvl[(size_t)bhu * 512 + c] = mine ? lbits : (unsigned short)0;
  }
  if (lane == 0) map[bh * Nn + M_top[bhu]] = bhu;
}

// ---------- assemble out rows (base = dout row 1280+b, + bo) ----------
__global__ __launch_bounds__(256) void assemble_kernel(
    const int* __restrict__ map, const float* __restrict__ dout,
    const float* __restrict__ bo, float* __restrict__ out)
{
  int t = threadIdx.x;
  int row = blockIdx.x * 4 + (t >> 6);
  int lane = t & 63;
  int b = row >> 11, n = row & 2047;
  const float* bp = dout + (size_t)(BH * Uu + b) * 512;
  float4 a0 = *(const float4*)(bp + lane * 4);
  float4 a1 = *(const float4*)(bp + 256 + lane * 4);
  float4 o0 = *(const float4*)(bo + lane * 4);
  float4 o1 = *(const float4*)(bo + 256 + lane * 4);
  a0.x += o0.x; a0.y += o0.y; a0.z += o0.z; a0.w += o0.w;
  a1.x += o1.x; a1.y += o1.y; a1.z += o1.z; a1.w += o1.w;
  for (int h = 0; h < 8; ++h) {
    int mi = map[(b * Hh + h) * Nn + n];
    if (mi >= 0) {
      const float* dp = dout + (size_t)mi * 512;
      float4 d0 = *(const float4*)(dp + lane * 4);
      float4 d1 = *(const float4*)(dp + 256 + lane * 4);
      a0.x += d0.x; a0.y += d0.y; a0.z += d0.z; a0.w += d0.w;
      a1.x += d1.x; a1.y += d1.y; a1.z += d1.z; a1.w += d1.w;
    }
  }
  *(float4*)(out + (size_t)row * 512 + lane * 4) = a0;
  *(float4*)(out + (size_t)row * 512 + 256 + lane * 4) = a1;
}

} // namespace

extern "C" void kernel_launch(void* const* d_in, const int* in_sizes, int n_in,
                              void* d_out, int out_size, void* d_ws, size_t ws_size,
                              hipStream_t stream) {
  const float* x  = (const float*)d_in[0];
  const float* Wq = (const float*)d_in[1];
  const float* bq = (const float*)d_in[2];
  const float* Wk = (const float*)d_in[3];
  const float* bk = (const float*)d_in[4];
  const float* Wv = (const float*)d_in[5];
  const float* bv = (const float*)d_in[6];
  const float* Wo = (const float*)d_in[7];
  const float* bo = (const float*)d_in[8];
  const int* idx  = (const int*)d_in[9];
  float* out = (float*)d_out;

  float* ws = (float*)d_ws;
  float* q      = ws;                       // 4,194,304 f
  float* kbuf   = ws + 4194304;
  float* vbuf   = ws + 8388608;
  float* Mbuf   = ws + 12582912;            // 65,536 f
  float* vmean  = ws + 12648448;            // 2,048 f
  float* pm     = ws + 12650496;            // 40,960 f [32][32][40]
  float* ps     = ws + 12691456;            // 40,960 f
  float* dout   = ws + 12732416;            // 786,432 f [1536][512]
  int*   M_top  = (int*)(ws + 13518848);    // 1,280
  int*   map    = (int*)(ws + 13520128);    // 65,536
  unsigned short* dvh = (unsigned short*)(ws + 13585664); // 1536*512 u16 (393,216 f)
  unsigned short* dvl = (unsigned short*)(ws + 13978880); // ends 14,372,096
  unsigned short* xh  = (unsigned short*)(ws + 14372096); // 8192*512 u16
  unsigned short* xl  = (unsigned short*)(ws + 16469248);
  unsigned short* WTh = (unsigned short*)(ws + 18566400); // 2048*512 u16
  unsigned short* WTl = (unsigned short*)(ws + 19090688); // ends 19,614,976 f
  float* partial = ws + 14372096;           // overlays xh/xl after gemm<0> (2,621,440 f)

  convert_all<<<4096 + 256, 256, 0, stream>>>(x, Wq, Wk, Wv, Wo, xh, xl, WTh, WTl);

  gemm_split<0><<<dim3(32, 12), 512, 0, stream>>>(
      xh, xl, WTh, WTl, bq, bk, bv, q, kbuf, vbuf);

  sampled_vmean_kernel<<<2048 + 32, 256, 0, stream>>>(
      q, kbuf, idx, Mbuf, vbuf, vmean, map);

  topk_kernel<<<BH, 64, 0, stream>>>(Mbuf, M_top);

  fused_attn_kernel<<<dim3(32, BH), 256, 0, stream>>>(q, kbuf, vbuf, M_top, pm, ps, partial);

  combine_lite<<<BH * Uu + Bb, 64, 0, stream>>>(pm, ps, partial, vmean, M_top, dvh, dvl, map);

  gemm_split<1><<<dim3(DV_ROWS / 256, 4), 512, 0, stream>>>(
      dvh, dvl, WTh + (size_t)1536 * 512, WTl + (size_t)1536 * 512,
      nullptr, nullptr, nullptr, dout, nullptr, nullptr);

  assemble_kernel<<<M_ROWS / 4, 256, 0, stream>>>(map, dout, bo, out);
}